// Round 2
// baseline (3357.441 us; speedup 1.0000x reference)
//
#include <hip/hip_runtime.h>
#include <math.h>

// twoB=8, L=4096 (H=W=64), C=256, d_inner=512, nh_m=8, hd=64, D_STATE=64,
// conv_dim=640, zx width=1160, CHUNK=256 (16 chunks/batch), WS=8, SS=4, NH=8, Dh=32.

#define DEVI static __device__ __forceinline__
typedef unsigned short u16;
typedef unsigned int   u32;

DEVI float sigm_(float x){ return 1.f/(1.f+expf(-x)); }
DEVI float silu_(float x){ return x/(1.f+expf(-x)); }
DEVI float wsum_(float v){
#pragma unroll
  for (int o=32;o>0;o>>=1) v += __shfl_xor(v,o,64);
  return v;
}

// ---- bf16 helpers (raw u16 storage, fp32 compute) ----
DEVI float b2f(u16 u){ union{u32 i; float f;} v; v.i = ((u32)u)<<16; return v.f; }
DEVI u16 f2b(float f){ union{float f; u32 i;} v; v.f=f; u32 r = v.i + 0x7fffu + ((v.i>>16)&1u); return (u16)(r>>16); }
DEVI float4 ld4(const float* p){ return *(const float4*)p; }
DEVI float4 ld4(const u16* p){
  uint2 r = *(const uint2*)p;
  return make_float4(b2f((u16)(r.x&0xffff)), b2f((u16)(r.x>>16)),
                     b2f((u16)(r.y&0xffff)), b2f((u16)(r.y>>16)));
}
DEVI void st4(u16* p, float a, float b, float c, float d){
  uint2 r; r.x = (u32)f2b(a) | ((u32)f2b(b)<<16); r.y = (u32)f2b(c) | ((u32)f2b(d)<<16);
  *(uint2*)p = r;
}
DEVI void ld8(const u16* p, float* f){
  uint4 r = *(const uint4*)p;
  f[0]=b2f((u16)(r.x&0xffff)); f[1]=b2f((u16)(r.x>>16));
  f[2]=b2f((u16)(r.y&0xffff)); f[3]=b2f((u16)(r.y>>16));
  f[4]=b2f((u16)(r.z&0xffff)); f[5]=b2f((u16)(r.z>>16));
  f[6]=b2f((u16)(r.w&0xffff)); f[7]=b2f((u16)(r.w>>16));
}
DEVI void st8(u16* p, const float* f){
  uint4 r;
  r.x=(u32)f2b(f[0])|((u32)f2b(f[1])<<16); r.y=(u32)f2b(f[2])|((u32)f2b(f[3])<<16);
  r.z=(u32)f2b(f[4])|((u32)f2b(f[5])<<16); r.w=(u32)f2b(f[6])|((u32)f2b(f[7])<<16);
  *(uint4*)p = r;
}
DEVI float tof(float v){ return v; }
DEVI float tof(u16 v){ return b2f(v); }
DEVI void sto(float* p, float v){ *p = v; }
DEVI void sto(u16* p, float v){ *p = f2b(v); }

// ---------------- fused LN(x)->xn, LN(xn)->xns (bf16 outs) -----------------
__global__ __launch_bounds__(256) void ln2x_k(
    const float* __restrict__ x, const float* __restrict__ w1, const float* __restrict__ b1,
    const float* __restrict__ w2, const float* __restrict__ b2,
    u16* __restrict__ xn, u16* __restrict__ xns)
{
  int tok = blockIdx.x*4 + (threadIdx.x>>6);
  int lane = threadIdx.x & 63;
  size_t base = (size_t)tok*256 + lane*4;
  float4 v = *(const float4*)(x + base);
  float mu = wsum_(v.x+v.y+v.z+v.w) * (1.f/256.f);
  float ax=v.x-mu, ay=v.y-mu, az=v.z-mu, aw=v.w-mu;
  float var = wsum_(ax*ax+ay*ay+az*az+aw*aw) * (1.f/256.f);
  float r = rsqrtf(var+1e-5f);
  float4 wv = *(const float4*)(w1+lane*4);
  float4 bv = *(const float4*)(b1+lane*4);
  float ox=ax*r*wv.x+bv.x, oy=ay*r*wv.y+bv.y, oz=az*r*wv.z+bv.z, ow=aw*r*wv.w+bv.w;
  st4(xn + base, ox, oy, oz, ow);
  float mu2 = wsum_(ox+oy+oz+ow)*(1.f/256.f);
  float bx=ox-mu2, by=oy-mu2, bz=oz-mu2, bw=ow-mu2;
  float var2 = wsum_(bx*bx+by*by+bz*bz+bw*bw)*(1.f/256.f);
  float r2 = rsqrtf(var2+1e-5f);
  float4 w2v = *(const float4*)(w2+lane*4);
  float4 b2v = *(const float4*)(b2+lane*4);
  st4(xns + base, bx*r2*w2v.x+b2v.x, by*r2*w2v.y+b2v.y, bz*r2*w2v.z+b2v.z, bw*r2*w2v.w+b2v.w);
}

// ---------------- generic LayerNorm (C=256), bf16 out, in-place safe -------
template<typename IT>
__global__ __launch_bounds__(256) void ln_k(
    const IT* __restrict__ in, const float* __restrict__ w, const float* __restrict__ b,
    u16* __restrict__ outp)
{
  int tok = blockIdx.x*4 + (threadIdx.x>>6);
  int lane = threadIdx.x & 63;
  size_t base = (size_t)tok*256 + lane*4;
  float4 v = ld4(in + base);
  float mu = wsum_(v.x+v.y+v.z+v.w) * (1.f/256.f);
  float ax=v.x-mu, ay=v.y-mu, az=v.z-mu, aw=v.w-mu;
  float var = wsum_(ax*ax+ay*ay+az*az+aw*aw) * (1.f/256.f);
  float r = rsqrtf(var+1e-5f);
  float4 wv = *(const float4*)(w+lane*4);
  float4 bv = *(const float4*)(b+lane*4);
  st4(outp + base, ax*r*wv.x+bv.x, ay*r*wv.y+bv.y, az*r*wv.z+bv.z, aw*r*wv.w+bv.w);
}

// -------- GEMM: out[M,N] = epi(cat(A1,A2)[M,K] @ W[K,:][n0..] + bias) ------
// A is bf16; W,bias fp32 with row stride ldw; other: OT; out: CT.
enum { EPI_NONE=0, EPI_SILU=1, EPI_GELU=2, EPI_SIGMUL=3, EPI_ADD=4, EPI_RELU=5, EPI_SIGMOID=6 };

template<int EPI, typename OT, typename CT>
__global__ __launch_bounds__(256) void gemm_k(
    const u16* __restrict__ A1, const u16* __restrict__ A2, int K1, int K2,
    const float* __restrict__ W, int ldw, const float* __restrict__ bias,
    const OT* other, CT* outp, int M, int N)
{
  __shared__ float as[16][68];
  __shared__ float bs[16][64];
  int m0 = blockIdx.y*64, n0 = blockIdx.x*64;
  int t = threadIdx.x;
  int ty = t>>4, tx = t&15;
  float acc[4][4] = {{0.f}};
  int K = K1 + K2;
  int arow = t>>2, ac4 = (t&3)<<2;
  int bkr = t>>4, bnc = (t&15)<<2;
  for (int k0=0; k0<K; k0+=16){
    int gk = k0 + ac4;
    float4 av;
    if (gk < K1) av = ld4(A1 + (size_t)(m0+arow)*K1 + gk);
    else         av = ld4(A2 + (size_t)(m0+arow)*K2 + (gk-K1));
    as[ac4+0][arow]=av.x; as[ac4+1][arow]=av.y; as[ac4+2][arow]=av.z; as[ac4+3][arow]=av.w;
    int gn = n0 + bnc;
    const float* wp = W + (size_t)(k0+bkr)*ldw;
    if (gn+3 < N) {
      *(float4*)&bs[bkr][bnc] = *(const float4*)(wp + gn);
    } else {
#pragma unroll
      for (int j=0;j<4;j++) bs[bkr][bnc+j] = (gn+j<N) ? wp[gn+j] : 0.f;
    }
    __syncthreads();
#pragma unroll
    for (int kk=0; kk<16; kk++){
      float4 a4 = *(const float4*)&as[kk][ty*4];
      float4 b4 = *(const float4*)&bs[kk][tx*4];
      acc[0][0]+=a4.x*b4.x; acc[0][1]+=a4.x*b4.y; acc[0][2]+=a4.x*b4.z; acc[0][3]+=a4.x*b4.w;
      acc[1][0]+=a4.y*b4.x; acc[1][1]+=a4.y*b4.y; acc[1][2]+=a4.y*b4.z; acc[1][3]+=a4.y*b4.w;
      acc[2][0]+=a4.z*b4.x; acc[2][1]+=a4.z*b4.y; acc[2][2]+=a4.z*b4.z; acc[2][3]+=a4.z*b4.w;
      acc[3][0]+=a4.w*b4.x; acc[3][1]+=a4.w*b4.y; acc[3][2]+=a4.w*b4.z; acc[3][3]+=a4.w*b4.w;
    }
    __syncthreads();
  }
#pragma unroll
  for (int i=0;i<4;i++){
    int gm = m0 + ty*4 + i;
#pragma unroll
    for (int j=0;j<4;j++){
      int gn = n0 + tx*4 + j;
      if (gn >= N) continue;
      float v = acc[i][j] + (bias ? bias[gn] : 0.f);
      size_t off = (size_t)gm*N + gn;
      if (EPI==EPI_SILU)        v = silu_(v);
      else if (EPI==EPI_GELU)   v = 0.5f*v*(1.f+erff(v*0.70710678118654752f));
      else if (EPI==EPI_SIGMUL) v = tof(other[off])*sigm_(v);
      else if (EPI==EPI_ADD)    v = v + tof(other[off]);
      else if (EPI==EPI_RELU)   v = fmaxf(v,0.f);
      else if (EPI==EPI_SIGMOID)v = sigm_(v);
      sto(outp + off, v);
    }
  }
}

// ---------------- causal conv (D_CONV=4) + SiLU, per-batch (4096 rows) -----
__global__ __launch_bounds__(256) void conv_k(
    const u16* __restrict__ XBC, const float* __restrict__ cw, const float* __restrict__ cb,
    u16* __restrict__ XC)
{
  int gid = blockIdx.x*256 + threadIdx.x;     // l*160 + c4grp, l in [0,4096)
  int l = gid / 160;
  int c4 = (gid - l*160)*4;
  float a0=cb[c4+0], a1=cb[c4+1], a2=cb[c4+2], a3=cb[c4+3];
#pragma unroll
  for (int k=0;k<4;k++){
    int ls = l - 3 + k;
    if (ls < 0) continue;
    float4 v = ld4(XBC + (size_t)ls*640 + c4);
    a0 += v.x * cw[(c4+0)*4 + k];
    a1 += v.y * cw[(c4+1)*4 + k];
    a2 += v.z * cw[(c4+2)*4 + k];
    a3 += v.w * cw[(c4+3)*4 + k];
  }
  st4(XC + (size_t)l*640 + c4, silu_(a0), silu_(a1), silu_(a2), silu_(a3));
}

// ---------------- dt: softplus(dtraw+bias); a = -dt*exp(a_log) (full) ------
__global__ __launch_bounds__(256) void dtk_k(
    const float* __restrict__ DTRAW, const float* __restrict__ dtb, const float* __restrict__ alog,
    float* __restrict__ DT_, float* __restrict__ AA_)
{
  int gid = blockIdx.x*256 + threadIdx.x;     // tok*8 + h
  int h = gid & 7;
  float xv = DTRAW[gid] + dtb[h];
  float sp = (xv > 20.f) ? xv : log1pf(expf(xv));
  DT_[gid] = sp;
  AA_[gid] = -sp * expf(alog[h]);
}

// ---------------- per-chunk inclusive cumsum of a (full) -------------------
__global__ __launch_bounds__(256) void acs_k(const float* __restrict__ AA_, float* __restrict__ ACS_)
{
  int wid = (blockIdx.x<<2) + (threadIdx.x>>6);   // 0..1023 = (b*8+h)*16+c
  int lane = threadIdx.x & 63;
  int c  = wid & 15;
  int bh = wid >> 4;
  int b  = bh >> 3, h = bh & 7;
  size_t tok0 = (size_t)b*4096 + c*256 + lane*4;
  float v0 = AA_[(tok0+0)*8 + h];
  float v1 = AA_[(tok0+1)*8 + h];
  float v2 = AA_[(tok0+2)*8 + h];
  float v3 = AA_[(tok0+3)*8 + h];
  v1 += v0; v2 += v1; v3 += v2;
  float tot = v3, s = tot;
#pragma unroll
  for (int o=1;o<64;o<<=1){
    float u = __shfl_up(s, o, 64);
    if (lane >= o) s += u;
  }
  float excl = s - tot;
  float* dst = ACS_ + (size_t)bh*4096 + c*256 + lane*4;
  dst[0]=excl+v0; dst[1]=excl+v1; dst[2]=excl+v2; dst[3]=excl+v3;
}

// ---------------- chunk end-states (per batch): ST[(c*8+h)][p][n] ----------
__global__ __launch_bounds__(256) void states_k(
    const u16* __restrict__ XC, const float* __restrict__ DTb, const float* __restrict__ ACSb,
    float* __restrict__ ST)
{
  int bid = blockIdx.x;                  // c*8 + h
  int h = bid & 7, c = bid>>3;
  __shared__ float bsh[16][64];
  __shared__ float xsh[16][64];
  int t = threadIdx.x, ty=t>>4, tx=t&15;
  const float* acs = ACSb + (size_t)h*4096 + c*256;
  float aL = acs[255];
  size_t tok0 = (size_t)c*256;
  float acc[4][4] = {{0.f}};
  int sr = t>>4, nc = (t&15)<<2;
  for (int s0=0; s0<256; s0+=16){
    size_t grow = tok0 + s0 + sr;
    float w = expf(aL - acs[s0+sr]);
    float4 bv = ld4(XC + grow*640 + 512 + nc);
    bsh[sr][nc+0]=bv.x*w; bsh[sr][nc+1]=bv.y*w; bsh[sr][nc+2]=bv.z*w; bsh[sr][nc+3]=bv.w*w;
    float dtv = DTb[grow*8 + h];
    float4 xv = ld4(XC + grow*640 + h*64 + nc);
    xsh[sr][nc+0]=xv.x*dtv; xsh[sr][nc+1]=xv.y*dtv; xsh[sr][nc+2]=xv.z*dtv; xsh[sr][nc+3]=xv.w*dtv;
    __syncthreads();
#pragma unroll
    for (int kk=0;kk<16;kk++){
      float4 p4 = *(const float4*)&xsh[kk][ty*4];
      float4 n4 = *(const float4*)&bsh[kk][tx*4];
      acc[0][0]+=p4.x*n4.x; acc[0][1]+=p4.x*n4.y; acc[0][2]+=p4.x*n4.z; acc[0][3]+=p4.x*n4.w;
      acc[1][0]+=p4.y*n4.x; acc[1][1]+=p4.y*n4.y; acc[1][2]+=p4.y*n4.z; acc[1][3]+=p4.y*n4.w;
      acc[2][0]+=p4.z*n4.x; acc[2][1]+=p4.z*n4.y; acc[2][2]+=p4.z*n4.z; acc[2][3]+=p4.z*n4.w;
      acc[3][0]+=p4.w*n4.x; acc[3][1]+=p4.w*n4.y; acc[3][2]+=p4.w*n4.z; acc[3][3]+=p4.w*n4.w;
    }
    __syncthreads();
  }
  float* dst = ST + (size_t)bid*4096;
#pragma unroll
  for (int i=0;i<4;i++)
#pragma unroll
    for (int j=0;j<4;j++)
      dst[(ty*4+i)*64 + tx*4+j] = acc[i][j];
}

// ---------------- sequential inter-chunk scan (per batch, grid=8 heads) ----
__global__ __launch_bounds__(256) void scan_k(
    const float* __restrict__ ST, const float* __restrict__ ACSb, float* __restrict__ STIN)
{
  int h = blockIdx.x;
  int t = threadIdx.x;
  float hr[16];
#pragma unroll
  for (int e=0;e<16;e++) hr[e]=0.f;
  for (int c=0;c<16;c++){
    float dec = expf(ACSb[(size_t)h*4096 + c*256 + 255]);
    size_t base = (size_t)(c*8+h)*4096;
#pragma unroll
    for (int e=0;e<16;e++){
      size_t idx = base + e*256 + t;
      float st = ST[idx];
      STIN[idx] = hr[e];
      hr[e] = hr[e]*dec + st;
    }
  }
}

// ---------------- Y = Yd + Yo + d_skip*xs (per batch) ----------------------
__global__ __launch_bounds__(256) void ydy_k(
    const u16* __restrict__ XC, const float* __restrict__ DTb,
    const float* __restrict__ ACSb, const float* __restrict__ STIN,
    const float* __restrict__ dskip, u16* __restrict__ Y)
{
  int bid = blockIdx.x;                      // (c*8+h)*4 + lt
  int lt = bid & 3, h = (bid>>2)&7, c = bid>>5;
  int l0 = lt*64;
  __shared__ float smem[10624];
  float (*qT)[68]  = (float(*)[68])smem;            // [n][l]
  float (*kT)[33]  = (float(*)[33])(smem+4352);     // [n][s]
  float (*vsh)[64] = (float(*)[64])(smem+6464);     // [s][p]
  float (*ssh)[33] = (float(*)[33])(smem+8512);     // [l][s]
  float (*sT)[68]  = (float(*)[68])(smem+4352);     // [n][p] overlays
  int t = threadIdx.x, ty=t>>4, tx=t&15;
  const float* acs = ACSb + (size_t)h*4096 + c*256;
  size_t tok0 = (size_t)c*256;
#pragma unroll
  for (int it=0; it<4; it++){
    int idx = t + it*256;
    int r = idx>>4, c4 = (idx&15)<<2;
    float4 v = ld4(XC + (tok0 + l0 + r)*640 + 576 + c4);
    qT[c4+0][r]=v.x; qT[c4+1][r]=v.y; qT[c4+2][r]=v.z; qT[c4+3][r]=v.w;
  }
  float acsl[4];
#pragma unroll
  for (int i=0;i<4;i++) acsl[i] = acs[l0 + ty*4 + i];
  float acc[4][4] = {{0.f}};
  for (int s0=0; s0 < l0+64; s0+=32){
#pragma unroll
    for (int it=0; it<2; it++){
      int idx = t + it*256;
      int r = idx>>4, c4 = (idx&15)<<2;
      size_t grow = tok0 + s0 + r;
      float4 bv = ld4(XC + grow*640 + 512 + c4);
      kT[c4+0][r]=bv.x; kT[c4+1][r]=bv.y; kT[c4+2][r]=bv.z; kT[c4+3][r]=bv.w;
      float dtv = DTb[grow*8 + h];
      float4 xv = ld4(XC + grow*640 + h*64 + c4);
      vsh[r][c4+0]=xv.x*dtv; vsh[r][c4+1]=xv.y*dtv; vsh[r][c4+2]=xv.z*dtv; vsh[r][c4+3]=xv.w*dtv;
    }
    __syncthreads();
    float sc[4][2] = {{0.f}};
#pragma unroll
    for (int n=0;n<64;n++){
      float4 q4 = *(const float4*)&qT[n][ty*4];
      float k0v = kT[n][tx*2+0];
      float k1v = kT[n][tx*2+1];
      sc[0][0]+=q4.x*k0v; sc[0][1]+=q4.x*k1v;
      sc[1][0]+=q4.y*k0v; sc[1][1]+=q4.y*k1v;
      sc[2][0]+=q4.z*k0v; sc[2][1]+=q4.z*k1v;
      sc[3][0]+=q4.w*k0v; sc[3][1]+=q4.w*k1v;
    }
    float acss[2];
    acss[0] = acs[s0 + tx*2+0];
    acss[1] = acs[s0 + tx*2+1];
#pragma unroll
    for (int i=0;i<4;i++){
      int li = l0 + ty*4 + i;
#pragma unroll
      for (int j=0;j<2;j++){
        int sj = s0 + tx*2 + j;
        float w = (sj <= li) ? expf(acsl[i] - acss[j]) : 0.f;
        ssh[ty*4+i][tx*2+j] = sc[i][j]*w;
      }
    }
    __syncthreads();
#pragma unroll
    for (int s=0;s<32;s++){
      float s0v=ssh[ty*4+0][s], s1v=ssh[ty*4+1][s], s2v=ssh[ty*4+2][s], s3v=ssh[ty*4+3][s];
      float4 v4 = *(const float4*)&vsh[s][tx*4];
      acc[0][0]+=s0v*v4.x; acc[0][1]+=s0v*v4.y; acc[0][2]+=s0v*v4.z; acc[0][3]+=s0v*v4.w;
      acc[1][0]+=s1v*v4.x; acc[1][1]+=s1v*v4.y; acc[1][2]+=s1v*v4.z; acc[1][3]+=s1v*v4.w;
      acc[2][0]+=s2v*v4.x; acc[2][1]+=s2v*v4.y; acc[2][2]+=s2v*v4.z; acc[2][3]+=s2v*v4.w;
      acc[3][0]+=s3v*v4.x; acc[3][1]+=s3v*v4.y; acc[3][2]+=s3v*v4.z; acc[3][3]+=s3v*v4.w;
    }
    __syncthreads();
  }
  const float* stin = STIN + (size_t)(c*8+h)*4096;
#pragma unroll
  for (int it=0; it<4; it++){
    int idx = t + it*256;
    int r = idx>>4, c4 = (idx&15)<<2;
    float4 v = *(const float4*)(stin + r*64 + c4);
    sT[c4+0][r]=v.x; sT[c4+1][r]=v.y; sT[c4+2][r]=v.z; sT[c4+3][r]=v.w;
  }
  __syncthreads();
  float osc[4][4] = {{0.f}};
#pragma unroll
  for (int n=0;n<64;n++){
    float4 q4 = *(const float4*)&qT[n][ty*4];
    float4 p4 = *(const float4*)&sT[n][tx*4];
    osc[0][0]+=q4.x*p4.x; osc[0][1]+=q4.x*p4.y; osc[0][2]+=q4.x*p4.z; osc[0][3]+=q4.x*p4.w;
    osc[1][0]+=q4.y*p4.x; osc[1][1]+=q4.y*p4.y; osc[1][2]+=q4.y*p4.z; osc[1][3]+=q4.y*p4.w;
    osc[2][0]+=q4.z*p4.x; osc[2][1]+=q4.z*p4.y; osc[2][2]+=q4.z*p4.z; osc[2][3]+=q4.z*p4.w;
    osc[3][0]+=q4.w*p4.x; osc[3][1]+=q4.w*p4.y; osc[3][2]+=q4.w*p4.z; osc[3][3]+=q4.w*p4.w;
  }
  float dsk = dskip[h];
#pragma unroll
  for (int i=0;i<4;i++){
    float el = expf(acsl[i]);
    size_t grow = tok0 + l0 + ty*4 + i;
    float4 xs = ld4(XC + grow*640 + h*64 + tx*4);
    st4(Y + grow*512 + h*64 + tx*4,
        acc[i][0] + el*osc[i][0] + dsk*xs.x,
        acc[i][1] + el*osc[i][1] + dsk*xs.y,
        acc[i][2] + el*osc[i][2] + dsk*xs.z,
        acc[i][3] + el*osc[i][3] + dsk*xs.w);
  }
}

// ---------------- u = y*silu(z); RMSNorm*w over 512 (per batch, in place) --
__global__ __launch_bounds__(256) void urms_k(
    u16* Y, const u16* __restrict__ Z, const float* __restrict__ nw)
{
  int tok = blockIdx.x*4 + (threadIdx.x>>6);
  int lane = threadIdx.x & 63;
  size_t base = (size_t)tok*512 + lane*8;
  float y[8], z[8], u[8];
  ld8(Y+base, y); ld8(Z+base, z);
  float ss=0.f;
#pragma unroll
  for (int e=0;e<8;e++){ u[e] = y[e]*silu_(z[e]); ss += u[e]*u[e]; }
  ss = wsum_(ss);
  float r = rsqrtf(ss*(1.f/512.f) + 1e-5f);
  float4 w0 = *(const float4*)(nw + lane*8);
  float4 w1 = *(const float4*)(nw + lane*8 + 4);
  float o[8];
  o[0]=u[0]*r*w0.x; o[1]=u[1]*r*w0.y; o[2]=u[2]*r*w0.z; o[3]=u[3]*r*w0.w;
  o[4]=u[4]*r*w1.x; o[5]=u[5]*r*w1.y; o[6]=u[6]*r*w1.z; o[7]=u[7]*r*w1.w;
  st8(Y+base, o);
}

// ---------------- window gather / scatter (roll by 4, 8x8 windows) ---------
DEVI int winmap_tok(int r){
  int win = r>>6, tk = r&63;
  int b = win>>6, wid = win&63;
  int h2 = ((wid>>3)<<3) + (tk>>3);
  int w2 = ((wid&7)<<3) + (tk&7);
  int hh = (h2+4)&63, wwp = (w2+4)&63;
  return b*4096 + hh*64 + wwp;
}
__global__ __launch_bounds__(256) void gather_k(const u16* __restrict__ XN, u16* __restrict__ XW)
{
  int gid = blockIdx.x*256 + threadIdx.x;
  int r = gid>>6, c4 = (gid&63)<<2;
  int tok = winmap_tok(r);
  *(uint2*)(XW + (size_t)r*256 + c4) = *(const uint2*)(XN + (size_t)tok*256 + c4);
}
__global__ __launch_bounds__(256) void scatter_k(const u16* __restrict__ XAW, u16* __restrict__ XA, int r0)
{
  int gid = blockIdx.x*256 + threadIdx.x;
  int r = gid>>6, c4 = (gid&63)<<2;
  int tok = winmap_tok(r0 + r);
  *(uint2*)(XA + (size_t)tok*256 + c4) = *(const uint2*)(XAW + (size_t)r*256 + c4);
}

// ---------------- window attention per (window, head), per batch -----------
__global__ __launch_bounds__(256) void attn_k(
    const u16* __restrict__ QKV, const float* __restrict__ rpb, u16* __restrict__ OW)
{
  int win = blockIdx.x;     // local window 0..63
  int head = blockIdx.y;
  __shared__ float qs[64][36], ks[64][36], vs[64][36];
  __shared__ float ssm[64][65];
  __shared__ int rid[64];
  int t = threadIdx.x;
  const float scale = 0.17677669529663687f;  // 32^-0.5
#pragma unroll
  for (int it=0; it<2; it++){
    int idx = t + it*256;
    int r = idx>>3, c4 = (idx&7)<<2;
    const u16* base = QKV + ((size_t)win*64 + r)*768 + head*32 + c4;
    float4 q4 = ld4(base);
    float4 k4 = ld4(base + 256);
    float4 v4 = ld4(base + 512);
    qs[r][c4+0]=q4.x*scale; qs[r][c4+1]=q4.y*scale; qs[r][c4+2]=q4.z*scale; qs[r][c4+3]=q4.w*scale;
    *(float4*)&ks[r][c4] = k4;
    *(float4*)&vs[r][c4] = v4;
  }
  if (t < 64){
    int h2 = ((win>>3)<<3) + (t>>3);
    int w2 = ((win&7)<<3) + (t&7);
    int rh = (h2<56)?0:((h2<60)?1:2);
    int rw = (w2<56)?0:((w2<60)?1:2);
    rid[t] = rh*3 + rw;
  }
  __syncthreads();
  int i = t>>2, jb = t&3;
#pragma unroll
  for (int jj=0; jj<16; jj++){
    int j = jb*16 + jj;
    float s = 0.f;
#pragma unroll
    for (int d4=0; d4<8; d4++){
      float4 q4 = *(const float4*)&qs[i][d4*4];
      float4 k4 = *(const float4*)&ks[j][d4*4];
      s += q4.x*k4.x + q4.y*k4.y + q4.z*k4.z + q4.w*k4.w;
    }
    int di = (i>>3) - (j>>3);
    int dj = (i&7) - (j&7);
    s += rpb[((di+7)*15 + (dj+7))*8 + head];
    if (rid[i] != rid[j]) s -= 100.f;
    ssm[i][j] = s;
  }
  __syncthreads();
  if (t < 64){
    float mx = -1e30f;
#pragma unroll
    for (int j=0;j<64;j++) mx = fmaxf(mx, ssm[t][j]);
    float sum = 0.f;
#pragma unroll
    for (int j=0;j<64;j++){ float e = expf(ssm[t][j]-mx); ssm[t][j]=e; sum+=e; }
    float inv = 1.f/sum;
#pragma unroll
    for (int j=0;j<64;j++) ssm[t][j] *= inv;
  }
  __syncthreads();
  int d0 = (t&3)*8;
  float o[8] = {0.f,0.f,0.f,0.f,0.f,0.f,0.f,0.f};
#pragma unroll
  for (int j=0;j<64;j++){
    float pv = ssm[i][j];
    float4 va = *(const float4*)&vs[j][d0];
    float4 vb = *(const float4*)&vs[j][d0+4];
    o[0]+=pv*va.x; o[1]+=pv*va.y; o[2]+=pv*va.z; o[3]+=pv*va.w;
    o[4]+=pv*vb.x; o[5]+=pv*vb.y; o[6]+=pv*vb.z; o[7]+=pv*vb.w;
  }
  st8(OW + ((size_t)win*64 + i)*256 + head*32 + d0, o);
}

// ---------------- xm *= gm ; xa *= ga (bf16) -------------------------------
__global__ __launch_bounds__(256) void mul2_k(
    u16* XM, const u16* __restrict__ GM, u16* XA, const u16* __restrict__ GA)
{
  size_t i = ((size_t)blockIdx.x*256 + threadIdx.x)*4;
  float4 m = ld4(XM+i), g = ld4(GM+i);
  st4(XM+i, m.x*g.x, m.y*g.y, m.z*g.z, m.w*g.w);
  float4 a = ld4(XA+i), g2 = ld4(GA+i);
  st4(XA+i, a.x*g2.x, a.y*g2.y, a.z*g2.z, a.w*g2.w);
}

// ---------------- host ------------------------------------------------------
extern "C" void kernel_launch(void* const* d_in, const int* in_sizes, int n_in,
                              void* d_out, int out_size, void* d_ws, size_t ws_size,
                              hipStream_t stream)
{
  (void)in_sizes; (void)n_in; (void)out_size;
  // byte offsets into d_ws (total need: 81,788,928 B ~ 78 MB)
  const size_t OFF_XN   = 0;               // bf16 32768x256 (later XA)
  const size_t OFF_XNS  = 16777216;        // bf16 32768x256 (later XM)
  const size_t OFF_SP   = 33554432;        // bf16 32768x256 (later GM)
  const size_t OFF_DTRAW= 50331648;        // f32 32768x8
  const size_t OFF_DT   = 51380224;
  const size_t OFF_AA   = 52428800;
  const size_t OFF_ACS  = 53477376;
  const size_t U7       = 54525952;        // phase-shared scratch arena (27,262,976 B)
  const size_t NEED     = 81788928;
  if (ws_size < NEED) return;

  const float* x       = (const float*)d_in[0];
  const float* ln1_w   = (const float*)d_in[1];
  const float* ln1_b   = (const float*)d_in[2];
  const float* ns_w    = (const float*)d_in[3];
  const float* ns_b    = (const float*)d_in[4];
  const float* m_win   = (const float*)d_in[5];
  const float* m_conv_w= (const float*)d_in[6];
  const float* m_conv_b= (const float*)d_in[7];
  const float* m_dt_b  = (const float*)d_in[8];
  const float* m_a_log = (const float*)d_in[9];
  const float* m_d     = (const float*)d_in[10];
  const float* m_norm_w= (const float*)d_in[11];
  const float* m_wout  = (const float*)d_in[12];
  const float* tm_w1   = (const float*)d_in[13];
  const float* tm_b1   = (const float*)d_in[14];
  const float* tm_w2   = (const float*)d_in[15];
  const float* tm_b2   = (const float*)d_in[16];
  const float* nt_w    = (const float*)d_in[17];
  const float* nt_b    = (const float*)d_in[18];
  const float* qkv_w   = (const float*)d_in[19];
  const float* qkv_b   = (const float*)d_in[20];
  const float* rpb     = (const float*)d_in[21];
  const float* gate_w  = (const float*)d_in[22];
  const float* gate_b  = (const float*)d_in[23];
  const float* proj_w  = (const float*)d_in[24];
  const float* proj_b  = (const float*)d_in[25];
  const float* cg_w1a  = (const float*)d_in[26];
  const float* cg_b1a  = (const float*)d_in[27];
  const float* cg_w2a  = (const float*)d_in[28];
  const float* cg_b2a  = (const float*)d_in[29];
  const float* cg_w1m  = (const float*)d_in[30];
  const float* cg_b1m  = (const float*)d_in[31];
  const float* cg_w2m  = (const float*)d_in[32];
  const float* cg_b2m  = (const float*)d_in[33];
  const float* cg_wf   = (const float*)d_in[34];
  const float* cg_bf   = (const float*)d_in[35];
  const float* ln2_w   = (const float*)d_in[36];
  const float* ln2_b   = (const float*)d_in[37];
  const float* mlp_w1  = (const float*)d_in[38];
  const float* mlp_b1  = (const float*)d_in[39];
  const float* mlp_w2  = (const float*)d_in[40];
  const float* mlp_b2  = (const float*)d_in[41];
  float* dout = (float*)d_out;
  char* ws = (char*)d_ws;

  u16*  XN   = (u16*)(ws + OFF_XN);
  u16*  XNS  = (u16*)(ws + OFF_XNS);
  u16*  SP   = (u16*)(ws + OFF_SP);
  float* DTRAW = (float*)(ws + OFF_DTRAW);
  float* DT  = (float*)(ws + OFF_DT);
  float* AA  = (float*)(ws + OFF_AA);
  float* ACS = (float*)(ws + OFF_ACS);
  // per-batch B..F transients
  u16*  XBCc = (u16*)(ws + U7);
  u16*  XCc  = (u16*)(ws + U7 + 5242880);
  float* ST  = (float*)(ws + U7 + 10485760);
  float* STIN= (float*)(ws + U7 + 12582912);
  u16*  Yc   = (u16*)(ws + U7 + 14680064);
  u16*  Zc   = (u16*)(ws + U7 + 18874368);
  // G
  u16*  TBUF = (u16*)(ws + U7);
  u16*  XM   = XNS;                 // XNS dead after batch loop
  // H
  u16*  XW   = (u16*)(ws + U7);
  u16*  QKVc = (u16*)(ws + U7 + 16777216);
  u16*  OWc  = (u16*)(ws + U7 + 23068672);
  u16*  XAWc = (u16*)(ws + U7 + 25165824);
  u16*  XA   = XN;                  // XN dead after gather
  // I
  u16*  CGH  = (u16*)(ws + U7);
  u16*  GA   = (u16*)(ws + U7 + 4194304);
  u16*  GM   = SP;                  // SP dead after G
  // J
  u16*  LNc  = (u16*)(ws + U7);
  u16*  MHc  = (u16*)(ws + U7 + 4194304);

  const size_t TB = 4096*256;   // tokens-per-batch * C (elements)
  const size_t H2 = 16384*256;  // half of SP/XM

  // Phase A: xn = LN(x); xns = LN(xn)
  ln2x_k<<<8192,256,0,stream>>>(x, ln1_w, ln1_b, ns_w, ns_b, XN, XNS);
  // dt path (full): dtraw = xns @ Win[:,1152:1160]
  gemm_k<EPI_NONE,float,float><<<dim3(1,512),256,0,stream>>>(XNS,nullptr,256,0, m_win+1152,1160, nullptr, nullptr, DTRAW, 32768,8);
  dtk_k<<<1024,256,0,stream>>>(DTRAW, m_dt_b, m_a_log, DT, AA);
  acs_k<<<256,256,0,stream>>>(AA, ACS);

  // Phases B..F per batch
  for (int b=0; b<8; b++){
    const u16* XNSb = XNS + (size_t)b*TB;
    const float* DTb = DT + (size_t)b*32768;
    const float* ACSb = ACS + (size_t)b*32768;
    gemm_k<EPI_NONE,float,u16><<<dim3(10,64),256,0,stream>>>(XNSb,nullptr,256,0, m_win+512,1160, nullptr, nullptr, XBCc, 4096,640);
    conv_k<<<2560,256,0,stream>>>(XBCc, m_conv_w, m_conv_b, XCc);
    states_k<<<128,256,0,stream>>>(XCc, DTb, ACSb, ST);
    scan_k<<<8,256,0,stream>>>(ST, ACSb, STIN);
    ydy_k<<<512,256,0,stream>>>(XCc, DTb, ACSb, STIN, m_d, Yc);
    gemm_k<EPI_NONE,float,u16><<<dim3(8,64),256,0,stream>>>(XNSb,nullptr,256,0, m_win,1160, nullptr, nullptr, Zc, 4096,512);
    urms_k<<<1024,256,0,stream>>>(Yc, Zc, m_norm_w);
    gemm_k<EPI_ADD,u16,u16><<<dim3(4,64),256,0,stream>>>(Yc,nullptr,512,0, m_wout,256, nullptr, XN + (size_t)b*TB, SP + (size_t)b*TB, 4096,256);
  }

  // Phase G: tmix (sequential f0 then f1)
  gemm_k<EPI_SILU,float,u16><<<dim3(4,256),256,0,stream>>>(SP, SP+H2, 256,256, tm_w1,256, tm_b1, nullptr, TBUF, 16384,256);
  gemm_k<EPI_ADD,u16,u16><<<dim3(4,256),256,0,stream>>>(TBUF,nullptr,256,0, tm_w2,256, tm_b2, SP, XM, 16384,256);
  ln_k<u16><<<4096,256,0,stream>>>(XM, nt_w, nt_b, XM);
  gemm_k<EPI_SILU,float,u16><<<dim3(4,256),256,0,stream>>>(SP+H2, XM, 256,256, tm_w1,256, tm_b1, nullptr, TBUF, 16384,256);
  gemm_k<EPI_ADD,u16,u16><<<dim3(4,256),256,0,stream>>>(TBUF,nullptr,256,0, tm_w2,256, tm_b2, SP+H2, XM+H2, 16384,256);
  ln_k<u16><<<4096,256,0,stream>>>(XM+H2, nt_w, nt_b, XM+H2);

  // Phase H: window attention on xn (per batch)
  gather_k<<<8192,256,0,stream>>>(XN, XW);
  for (int b=0; b<8; b++){
    const u16* XWb = XW + (size_t)b*TB;
    gemm_k<EPI_NONE,float,u16><<<dim3(12,64),256,0,stream>>>(XWb,nullptr,256,0, qkv_w,768, qkv_b, nullptr, QKVc, 4096,768);
    attn_k<<<dim3(64,8),256,0,stream>>>(QKVc, rpb, OWc);
    gemm_k<EPI_SIGMUL,u16,u16><<<dim3(4,64),256,0,stream>>>(XWb,nullptr,256,0, gate_w,256, gate_b, OWc, OWc, 4096,256);
    gemm_k<EPI_NONE,float,u16><<<dim3(4,64),256,0,stream>>>(OWc,nullptr,256,0, proj_w,256, proj_b, nullptr, XAWc, 4096,256);
    scatter_k<<<1024,256,0,stream>>>(XAWc, XA, b*4096);
  }

  // Phase I: cross gates; xo = x + cat(xm*gm, xa*ga)@cg_wf + cg_bf -> d_out
  gemm_k<EPI_RELU,float,u16><<<dim3(1,512),256,0,stream>>>(XA,nullptr,256,0, cg_w1a,64, cg_b1a, nullptr, CGH, 32768,64);
  gemm_k<EPI_SIGMOID,float,u16><<<dim3(4,512),256,0,stream>>>(CGH,nullptr,64,0, cg_w2a,256, cg_b2a, nullptr, GM, 32768,256);
  gemm_k<EPI_RELU,float,u16><<<dim3(1,512),256,0,stream>>>(XM,nullptr,256,0, cg_w1m,64, cg_b1m, nullptr, CGH, 32768,64);
  gemm_k<EPI_SIGMOID,float,u16><<<dim3(4,512),256,0,stream>>>(CGH,nullptr,64,0, cg_w2m,256, cg_b2m, nullptr, GA, 32768,256);
  mul2_k<<<8192,256,0,stream>>>(XM, GM, XA, GA);
  gemm_k<EPI_ADD,float,float><<<dim3(4,512),256,0,stream>>>(XM, XA, 256,256, cg_wf,256, cg_bf, x, dout, 32768,256);

  // Phase J: MLP, per 8192-row slab; out = xo + gelu(ln(xo)@w1+b1)@w2+b2 (in-place on d_out)
  for (int q=0; q<4; q++){
    float* XOq = dout + (size_t)q*8192*256;
    ln_k<float><<<2048,256,0,stream>>>(XOq, ln2_w, ln2_b, LNc);
    gemm_k<EPI_GELU,float,u16><<<dim3(16,128),256,0,stream>>>(LNc,nullptr,256,0, mlp_w1,1024, mlp_b1, nullptr, MHc, 8192,1024);
    gemm_k<EPI_ADD,float,float><<<dim3(4,128),256,0,stream>>>(MHc,nullptr,1024,0, mlp_w2,256, mlp_b2, XOq, XOq, 8192,256);
  }
}

// Round 3
// 2026.765 us; speedup vs baseline: 1.6566x; 1.6566x over previous
//
#include <hip/hip_runtime.h>
#include <math.h>

// twoB=8, L=4096 (H=W=64), C=256, d_inner=512, nh_m=8, hd=64, D_STATE=64,
// conv_dim=640, zx width=1160, CHUNK=256 (16 chunks/batch), WS=8, SS=4, NH=8, Dh=32.

#define DEVI static __device__ __forceinline__
typedef unsigned short u16;
typedef unsigned int   u32;
typedef __attribute__((ext_vector_type(8))) short s16x8;
typedef __attribute__((ext_vector_type(4))) float f32x4;

DEVI float sigm_(float x){ return 1.f/(1.f+expf(-x)); }
DEVI float silu_(float x){ return x/(1.f+expf(-x)); }
DEVI float wsum_(float v){
#pragma unroll
  for (int o=32;o>0;o>>=1) v += __shfl_xor(v,o,64);
  return v;
}

// ---- bf16 helpers (raw u16 storage, fp32 compute) ----
DEVI float b2f(u16 u){ union{u32 i; float f;} v; v.i = ((u32)u)<<16; return v.f; }
DEVI u16 f2b(float f){ union{float f; u32 i;} v; v.f=f; u32 r = v.i + 0x7fffu + ((v.i>>16)&1u); return (u16)(r>>16); }
DEVI float4 ld4(const float* p){ return *(const float4*)p; }
DEVI float4 ld4(const u16* p){
  uint2 r = *(const uint2*)p;
  return make_float4(b2f((u16)(r.x&0xffff)), b2f((u16)(r.x>>16)),
                     b2f((u16)(r.y&0xffff)), b2f((u16)(r.y>>16)));
}
DEVI void st4(u16* p, float a, float b, float c, float d){
  uint2 r; r.x = (u32)f2b(a) | ((u32)f2b(b)<<16); r.y = (u32)f2b(c) | ((u32)f2b(d)<<16);
  *(uint2*)p = r;
}
DEVI void ld8(const u16* p, float* f){
  uint4 r = *(const uint4*)p;
  f[0]=b2f((u16)(r.x&0xffff)); f[1]=b2f((u16)(r.x>>16));
  f[2]=b2f((u16)(r.y&0xffff)); f[3]=b2f((u16)(r.y>>16));
  f[4]=b2f((u16)(r.z&0xffff)); f[5]=b2f((u16)(r.z>>16));
  f[6]=b2f((u16)(r.w&0xffff)); f[7]=b2f((u16)(r.w>>16));
}
DEVI void st8(u16* p, const float* f){
  uint4 r;
  r.x=(u32)f2b(f[0])|((u32)f2b(f[1])<<16); r.y=(u32)f2b(f[2])|((u32)f2b(f[3])<<16);
  r.z=(u32)f2b(f[4])|((u32)f2b(f[5])<<16); r.w=(u32)f2b(f[6])|((u32)f2b(f[7])<<16);
  *(uint4*)p = r;
}
DEVI float tof(float v){ return v; }
DEVI float tof(u16 v){ return b2f(v); }
DEVI void sto(float* p, float v){ *p = v; }
DEVI void sto(u16* p, float v){ *p = f2b(v); }

// window row -> token map (roll by -4, 8x8 windows over 64x64, per batch)
DEVI int winmap_tok(int r){
  int win = r>>6, tk = r&63;
  int b = win>>6, wid = win&63;
  int h2 = ((wid>>3)<<3) + (tk>>3);
  int w2 = ((wid&7)<<3) + (tk&7);
  int hh = (h2+4)&63, wwp = (w2+4)&63;
  return b*4096 + hh*64 + wwp;
}

// ---------------- fused LN(x)->xn, LN(xn)->xns (bf16 outs) -----------------
__global__ __launch_bounds__(256) void ln2x_k(
    const float* __restrict__ x, const float* __restrict__ w1, const float* __restrict__ b1,
    const float* __restrict__ w2, const float* __restrict__ b2,
    u16* __restrict__ xn, u16* __restrict__ xns)
{
  int tok = blockIdx.x*4 + (threadIdx.x>>6);
  int lane = threadIdx.x & 63;
  size_t base = (size_t)tok*256 + lane*4;
  float4 v = *(const float4*)(x + base);
  float mu = wsum_(v.x+v.y+v.z+v.w) * (1.f/256.f);
  float ax=v.x-mu, ay=v.y-mu, az=v.z-mu, aw=v.w-mu;
  float var = wsum_(ax*ax+ay*ay+az*az+aw*aw) * (1.f/256.f);
  float r = rsqrtf(var+1e-5f);
  float4 wv = *(const float4*)(w1+lane*4);
  float4 bv = *(const float4*)(b1+lane*4);
  float ox=ax*r*wv.x+bv.x, oy=ay*r*wv.y+bv.y, oz=az*r*wv.z+bv.z, ow=aw*r*wv.w+bv.w;
  st4(xn + base, ox, oy, oz, ow);
  float mu2 = wsum_(ox+oy+oz+ow)*(1.f/256.f);
  float bx=ox-mu2, by=oy-mu2, bz=oz-mu2, bw=ow-mu2;
  float var2 = wsum_(bx*bx+by*by+bz*bz+bw*bw)*(1.f/256.f);
  float r2 = rsqrtf(var2+1e-5f);
  float4 w2v = *(const float4*)(w2+lane*4);
  float4 b2v = *(const float4*)(b2+lane*4);
  st4(xns + base, bx*r2*w2v.x+b2v.x, by*r2*w2v.y+b2v.y, bz*r2*w2v.z+b2v.z, bw*r2*w2v.w+b2v.w);
}

// ---------------- generic LayerNorm (C=256), bf16 out ----------------------
template<typename IT>
__global__ __launch_bounds__(256) void ln_k(
    const IT* __restrict__ in, const float* __restrict__ w, const float* __restrict__ b,
    u16* __restrict__ outp)
{
  int tok = blockIdx.x*4 + (threadIdx.x>>6);
  int lane = threadIdx.x & 63;
  size_t base = (size_t)tok*256 + lane*4;
  float4 v = ld4(in + base);
  float mu = wsum_(v.x+v.y+v.z+v.w) * (1.f/256.f);
  float ax=v.x-mu, ay=v.y-mu, az=v.z-mu, aw=v.w-mu;
  float var = wsum_(ax*ax+ay*ay+az*az+aw*aw) * (1.f/256.f);
  float r = rsqrtf(var+1e-5f);
  float4 wv = *(const float4*)(w+lane*4);
  float4 bv = *(const float4*)(b+lane*4);
  st4(outp + base, ax*r*wv.x+bv.x, ay*r*wv.y+bv.y, az*r*wv.z+bv.z, aw*r*wv.w+bv.w);
}

// ---------------- weight fp32[K][N](ldw) -> bf16 Wt[N][K] ------------------
__global__ __launch_bounds__(256) void wt_k(
    const float* __restrict__ W, int ldw, int K, u16* __restrict__ Wt)
{
  __shared__ float tl[32][33];
  int k0 = blockIdx.x*32, n0 = blockIdx.y*32;
  int t = threadIdx.x; int ty=t>>5, tx=t&31;
#pragma unroll
  for (int i=0;i<4;i++){
    int k = ty + i*8;
    tl[k][tx] = W[(size_t)(k0+k)*ldw + n0+tx];
  }
  __syncthreads();
#pragma unroll
  for (int i=0;i<4;i++){
    int n = ty + i*8;
    Wt[(size_t)(n0+n)*K + k0 + tx] = f2b(tl[tx][n]);
  }
}

enum { EPI_NONE=0, EPI_SILU=1, EPI_GELU=2, EPI_SIGMUL=3, EPI_ADD=4, EPI_RELU=5, EPI_SIGMOID=6 };

// -------- MFMA GEMM: out[M,N] = epi(cat(A1,A2)[M,K] @ Wt[N,K]^T + bias) ----
// BN=128 fixed, BK=32, 4 waves (2x2), A bf16 rows, Wt bf16 [N][K].
template<int BM, int EPI, bool WIN, typename OT, typename CT>
__global__ __launch_bounds__(256) void mgemm_k(
    const u16* __restrict__ A1, const u16* __restrict__ A2, int K1, int K2,
    const u16* __restrict__ Wt, const float* __restrict__ bias,
    const OT* other, CT* outp, int N, int r0)
{
  constexpr int MW = BM/32;            // 16-row frags per wave
  constexpr int LA = BM/64;            // A staging loads per thread
  __shared__ u16 As[BM][40];
  __shared__ u16 Bs[128][40];
  int m0 = blockIdx.y*BM, n0 = blockIdx.x*128;
  int t = threadIdx.x;
  int lane = t&63, w = t>>6;
  int wr = w>>1, wc = w&1;
  int K = K1 + K2;
  f32x4 acc[MW][4];
#pragma unroll
  for (int mi=0;mi<MW;mi++)
#pragma unroll
    for (int ni=0;ni<4;ni++) acc[mi][ni] = (f32x4){0.f,0.f,0.f,0.f};
  int lrow = t>>2, lc8 = (t&3)*8;
  size_t aoff1[LA], aoff2[LA];
#pragma unroll
  for (int i=0;i<LA;i++){
    int gr = m0 + lrow + i*64;
    if (WIN) aoff1[i] = (size_t)winmap_tok(r0+gr)*K1;
    else { aoff1[i] = (size_t)gr*K1; aoff2[i] = (size_t)gr*K2; }
  }
  for (int k0=0; k0<K; k0+=32){
    int gk = k0 + lc8;
#pragma unroll
    for (int i=0;i<LA;i++){
      const u16* ap = (WIN || gk < K1) ? A1 + aoff1[i] + gk : A2 + aoff2[i] + (gk-K1);
      *(uint4*)&As[lrow + i*64][lc8] = *(const uint4*)ap;
    }
#pragma unroll
    for (int i=0;i<2;i++){
      int row = lrow + i*64;
      *(uint4*)&Bs[row][lc8] = *(const uint4*)(Wt + (size_t)(n0+row)*K + gk);
    }
    __syncthreads();
    int lg = lane>>4, li = lane&15;
    s16x8 afr[MW], bfr[4];
#pragma unroll
    for (int mi=0;mi<MW;mi++)
      afr[mi] = *(const s16x8*)&As[wr*(BM/2)+mi*16+li][lg*8];
#pragma unroll
    for (int ni=0;ni<4;ni++)
      bfr[ni] = *(const s16x8*)&Bs[wc*64+ni*16+li][lg*8];
#pragma unroll
    for (int mi=0;mi<MW;mi++)
#pragma unroll
      for (int ni=0;ni<4;ni++)
        acc[mi][ni] = __builtin_amdgcn_mfma_f32_16x16x32_bf16(afr[mi], bfr[ni], acc[mi][ni], 0,0,0);
    __syncthreads();
  }
  int lg = lane>>4, li = lane&15;
#pragma unroll
  for (int mi=0;mi<MW;mi++){
#pragma unroll
    for (int ni=0;ni<4;ni++){
      int gn = n0 + wc*64 + ni*16 + li;
      float bv = bias ? bias[gn] : 0.f;
#pragma unroll
      for (int r=0;r<4;r++){
        int gm = m0 + wr*(BM/2) + mi*16 + lg*4 + r;
        float v = acc[mi][ni][r] + bv;
        size_t off = (size_t)gm*N + gn;
        if (EPI==EPI_SILU)        v = silu_(v);
        else if (EPI==EPI_GELU)   v = 0.5f*v*(1.f+erff(v*0.70710678118654752f));
        else if (EPI==EPI_SIGMUL) v = tof(other[off])*sigm_(v);
        else if (EPI==EPI_ADD)    v = v + tof(other[off]);
        else if (EPI==EPI_SIGMOID)v = sigm_(v);
        sto(outp + off, v);
      }
    }
  }
}

// -------- fp32 fallback GEMM (small N): out = epi(A[M,K]@W[K,N]+bias) ------
template<int EPI, typename OT, typename CT>
__global__ __launch_bounds__(256) void gemm_k(
    const u16* __restrict__ A1, const u16* __restrict__ A2, int K1, int K2,
    const float* __restrict__ W, int ldw, const float* __restrict__ bias,
    const OT* other, CT* outp, int M, int N)
{
  __shared__ float as[16][68];
  __shared__ float bs[16][64];
  int m0 = blockIdx.y*64, n0 = blockIdx.x*64;
  int t = threadIdx.x;
  int ty = t>>4, tx = t&15;
  float acc[4][4] = {{0.f}};
  int K = K1 + K2;
  int arow = t>>2, ac4 = (t&3)<<2;
  int bkr = t>>4, bnc = (t&15)<<2;
  for (int k0=0; k0<K; k0+=16){
    int gk = k0 + ac4;
    float4 av;
    if (gk < K1) av = ld4(A1 + (size_t)(m0+arow)*K1 + gk);
    else         av = ld4(A2 + (size_t)(m0+arow)*K2 + (gk-K1));
    as[ac4+0][arow]=av.x; as[ac4+1][arow]=av.y; as[ac4+2][arow]=av.z; as[ac4+3][arow]=av.w;
    int gn = n0 + bnc;
    const float* wp = W + (size_t)(k0+bkr)*ldw;
    if (gn+3 < N) {
      *(float4*)&bs[bkr][bnc] = *(const float4*)(wp + gn);
    } else {
#pragma unroll
      for (int j=0;j<4;j++) bs[bkr][bnc+j] = (gn+j<N) ? wp[gn+j] : 0.f;
    }
    __syncthreads();
#pragma unroll
    for (int kk=0; kk<16; kk++){
      float4 a4 = *(const float4*)&as[kk][ty*4];
      float4 b4 = *(const float4*)&bs[kk][tx*4];
      acc[0][0]+=a4.x*b4.x; acc[0][1]+=a4.x*b4.y; acc[0][2]+=a4.x*b4.z; acc[0][3]+=a4.x*b4.w;
      acc[1][0]+=a4.y*b4.x; acc[1][1]+=a4.y*b4.y; acc[1][2]+=a4.y*b4.z; acc[1][3]+=a4.y*b4.w;
      acc[2][0]+=a4.z*b4.x; acc[2][1]+=a4.z*b4.y; acc[2][2]+=a4.z*b4.z; acc[2][3]+=a4.z*b4.w;
      acc[3][0]+=a4.w*b4.x; acc[3][1]+=a4.w*b4.y; acc[3][2]+=a4.w*b4.z; acc[3][3]+=a4.w*b4.w;
    }
    __syncthreads();
  }
#pragma unroll
  for (int i=0;i<4;i++){
    int gm = m0 + ty*4 + i;
#pragma unroll
    for (int j=0;j<4;j++){
      int gn = n0 + tx*4 + j;
      if (gn >= N) continue;
      float v = acc[i][j] + (bias ? bias[gn] : 0.f);
      size_t off = (size_t)gm*N + gn;
      if (EPI==EPI_SILU)        v = silu_(v);
      else if (EPI==EPI_GELU)   v = 0.5f*v*(1.f+erff(v*0.70710678118654752f));
      else if (EPI==EPI_SIGMUL) v = tof(other[off])*sigm_(v);
      else if (EPI==EPI_ADD)    v = v + tof(other[off]);
      else if (EPI==EPI_RELU)   v = fmaxf(v,0.f);
      else if (EPI==EPI_SIGMOID)v = sigm_(v);
      sto(outp + off, v);
    }
  }
}

// ---------------- causal conv (D_CONV=4) + SiLU, per-batch (4096 rows) -----
__global__ __launch_bounds__(256) void conv_k(
    const u16* __restrict__ XBC, const float* __restrict__ cw, const float* __restrict__ cb,
    u16* __restrict__ XC)
{
  int gid = blockIdx.x*256 + threadIdx.x;     // l*160 + c4grp
  int l = gid / 160;
  int c4 = (gid - l*160)*4;
  float a0=cb[c4+0], a1=cb[c4+1], a2=cb[c4+2], a3=cb[c4+3];
#pragma unroll
  for (int k=0;k<4;k++){
    int ls = l - 3 + k;
    if (ls < 0) continue;
    float4 v = ld4(XBC + (size_t)ls*640 + c4);
    a0 += v.x * cw[(c4+0)*4 + k];
    a1 += v.y * cw[(c4+1)*4 + k];
    a2 += v.z * cw[(c4+2)*4 + k];
    a3 += v.w * cw[(c4+3)*4 + k];
  }
  st4(XC + (size_t)l*640 + c4, silu_(a0), silu_(a1), silu_(a2), silu_(a3));
}

// ---------------- dt: softplus(dtraw+bias); a = -dt*exp(a_log) (full) ------
__global__ __launch_bounds__(256) void dtk_k(
    const float* __restrict__ DTRAW, const float* __restrict__ dtb, const float* __restrict__ alog,
    float* __restrict__ DT_, float* __restrict__ AA_)
{
  int gid = blockIdx.x*256 + threadIdx.x;     // tok*8 + h
  int h = gid & 7;
  float xv = DTRAW[gid] + dtb[h];
  float sp = (xv > 20.f) ? xv : log1pf(expf(xv));
  DT_[gid] = sp;
  AA_[gid] = -sp * expf(alog[h]);
}

// ---------------- per-chunk inclusive cumsum of a (full) -------------------
__global__ __launch_bounds__(256) void acs_k(const float* __restrict__ AA_, float* __restrict__ ACS_)
{
  int wid = (blockIdx.x<<2) + (threadIdx.x>>6);   // 0..1023 = (b*8+h)*16+c
  int lane = threadIdx.x & 63;
  int c  = wid & 15;
  int bh = wid >> 4;
  int b  = bh >> 3, h = bh & 7;
  size_t tok0 = (size_t)b*4096 + c*256 + lane*4;
  float v0 = AA_[(tok0+0)*8 + h];
  float v1 = AA_[(tok0+1)*8 + h];
  float v2 = AA_[(tok0+2)*8 + h];
  float v3 = AA_[(tok0+3)*8 + h];
  v1 += v0; v2 += v1; v3 += v2;
  float tot = v3, s = tot;
#pragma unroll
  for (int o=1;o<64;o<<=1){
    float u = __shfl_up(s, o, 64);
    if (lane >= o) s += u;
  }
  float excl = s - tot;
  float* dst = ACS_ + (size_t)bh*4096 + c*256 + lane*4;
  dst[0]=excl+v0; dst[1]=excl+v1; dst[2]=excl+v2; dst[3]=excl+v3;
}

// ---------------- chunk end-states (per batch): ST[(c*8+h)][p][n] ----------
__global__ __launch_bounds__(256) void states_k(
    const u16* __restrict__ XC, const float* __restrict__ DTb, const float* __restrict__ ACSb,
    float* __restrict__ ST)
{
  int bid = blockIdx.x;                  // c*8 + h
  int h = bid & 7, c = bid>>3;
  __shared__ float bsh[16][64];
  __shared__ float xsh[16][64];
  int t = threadIdx.x, ty=t>>4, tx=t&15;
  const float* acs = ACSb + (size_t)h*4096 + c*256;
  float aL = acs[255];
  size_t tok0 = (size_t)c*256;
  float acc[4][4] = {{0.f}};
  int sr = t>>4, nc = (t&15)<<2;
  for (int s0=0; s0<256; s0+=16){
    size_t grow = tok0 + s0 + sr;
    float w = expf(aL - acs[s0+sr]);
    float4 bv = ld4(XC + grow*640 + 512 + nc);
    bsh[sr][nc+0]=bv.x*w; bsh[sr][nc+1]=bv.y*w; bsh[sr][nc+2]=bv.z*w; bsh[sr][nc+3]=bv.w*w;
    float dtv = DTb[grow*8 + h];
    float4 xv = ld4(XC + grow*640 + h*64 + nc);
    xsh[sr][nc+0]=xv.x*dtv; xsh[sr][nc+1]=xv.y*dtv; xsh[sr][nc+2]=xv.z*dtv; xsh[sr][nc+3]=xv.w*dtv;
    __syncthreads();
#pragma unroll
    for (int kk=0;kk<16;kk++){
      float4 p4 = *(const float4*)&xsh[kk][ty*4];
      float4 n4 = *(const float4*)&bsh[kk][tx*4];
      acc[0][0]+=p4.x*n4.x; acc[0][1]+=p4.x*n4.y; acc[0][2]+=p4.x*n4.z; acc[0][3]+=p4.x*n4.w;
      acc[1][0]+=p4.y*n4.x; acc[1][1]+=p4.y*n4.y; acc[1][2]+=p4.y*n4.z; acc[1][3]+=p4.y*n4.w;
      acc[2][0]+=p4.z*n4.x; acc[2][1]+=p4.z*n4.y; acc[2][2]+=p4.z*n4.z; acc[2][3]+=p4.z*n4.w;
      acc[3][0]+=p4.w*n4.x; acc[3][1]+=p4.w*n4.y; acc[3][2]+=p4.w*n4.z; acc[3][3]+=p4.w*n4.w;
    }
    __syncthreads();
  }
  float* dst = ST + (size_t)bid*4096;
#pragma unroll
  for (int i=0;i<4;i++)
#pragma unroll
    for (int j=0;j<4;j++)
      dst[(ty*4+i)*64 + tx*4+j] = acc[i][j];
}

// ---------------- sequential inter-chunk scan (per batch, grid=8 heads) ----
__global__ __launch_bounds__(256) void scan_k(
    const float* __restrict__ ST, const float* __restrict__ ACSb, float* __restrict__ STIN)
{
  int h = blockIdx.x;
  int t = threadIdx.x;
  float hr[16];
#pragma unroll
  for (int e=0;e<16;e++) hr[e]=0.f;
  for (int c=0;c<16;c++){
    float dec = expf(ACSb[(size_t)h*4096 + c*256 + 255]);
    size_t base = (size_t)(c*8+h)*4096;
#pragma unroll
    for (int e=0;e<16;e++){
      size_t idx = base + e*256 + t;
      float st = ST[idx];
      STIN[idx] = hr[e];
      hr[e] = hr[e]*dec + st;
    }
  }
}

// ---------------- Y = Yd + Yo + d_skip*xs (per batch) ----------------------
__global__ __launch_bounds__(256) void ydy_k(
    const u16* __restrict__ XC, const float* __restrict__ DTb,
    const float* __restrict__ ACSb, const float* __restrict__ STIN,
    const float* __restrict__ dskip, u16* __restrict__ Y)
{
  int bid = blockIdx.x;                      // (c*8+h)*4 + lt
  int lt = bid & 3, h = (bid>>2)&7, c = bid>>5;
  int l0 = lt*64;
  __shared__ float smem[10624];
  float (*qT)[68]  = (float(*)[68])smem;            // [n][l]
  float (*kT)[33]  = (float(*)[33])(smem+4352);     // [n][s]
  float (*vsh)[64] = (float(*)[64])(smem+6464);     // [s][p]
  float (*ssh)[33] = (float(*)[33])(smem+8512);     // [l][s]
  float (*sT)[68]  = (float(*)[68])(smem+4352);     // [n][p] overlays
  int t = threadIdx.x, ty=t>>4, tx=t&15;
  const float* acs = ACSb + (size_t)h*4096 + c*256;
  size_t tok0 = (size_t)c*256;
#pragma unroll
  for (int it=0; it<4; it++){
    int idx = t + it*256;
    int r = idx>>4, c4 = (idx&15)<<2;
    float4 v = ld4(XC + (tok0 + l0 + r)*640 + 576 + c4);
    qT[c4+0][r]=v.x; qT[c4+1][r]=v.y; qT[c4+2][r]=v.z; qT[c4+3][r]=v.w;
  }
  float acsl[4];
#pragma unroll
  for (int i=0;i<4;i++) acsl[i] = acs[l0 + ty*4 + i];
  float acc[4][4] = {{0.f}};
  for (int s0=0; s0 < l0+64; s0+=32){
#pragma unroll
    for (int it=0; it<2; it++){
      int idx = t + it*256;
      int r = idx>>4, c4 = (idx&15)<<2;
      size_t grow = tok0 + s0 + r;
      float4 bv = ld4(XC + grow*640 + 512 + c4);
      kT[c4+0][r]=bv.x; kT[c4+1][r]=bv.y; kT[c4+2][r]=bv.z; kT[c4+3][r]=bv.w;
      float dtv = DTb[grow*8 + h];
      float4 xv = ld4(XC + grow*640 + h*64 + c4);
      vsh[r][c4+0]=xv.x*dtv; vsh[r][c4+1]=xv.y*dtv; vsh[r][c4+2]=xv.z*dtv; vsh[r][c4+3]=xv.w*dtv;
    }
    __syncthreads();
    float sc[4][2] = {{0.f}};
#pragma unroll
    for (int n=0;n<64;n++){
      float4 q4 = *(const float4*)&qT[n][ty*4];
      float k0v = kT[n][tx*2+0];
      float k1v = kT[n][tx*2+1];
      sc[0][0]+=q4.x*k0v; sc[0][1]+=q4.x*k1v;
      sc[1][0]+=q4.y*k0v; sc[1][1]+=q4.y*k1v;
      sc[2][0]+=q4.z*k0v; sc[2][1]+=q4.z*k1v;
      sc[3][0]+=q4.w*k0v; sc[3][1]+=q4.w*k1v;
    }
    float acss[2];
    acss[0] = acs[s0 + tx*2+0];
    acss[1] = acs[s0 + tx*2+1];
#pragma unroll
    for (int i=0;i<4;i++){
      int li = l0 + ty*4 + i;
#pragma unroll
      for (int j=0;j<2;j++){
        int sj = s0 + tx*2 + j;
        float w = (sj <= li) ? expf(acsl[i] - acss[j]) : 0.f;
        ssh[ty*4+i][tx*2+j] = sc[i][j]*w;
      }
    }
    __syncthreads();
#pragma unroll
    for (int s=0;s<32;s++){
      float s0v=ssh[ty*4+0][s], s1v=ssh[ty*4+1][s], s2v=ssh[ty*4+2][s], s3v=ssh[ty*4+3][s];
      float4 v4 = *(const float4*)&vsh[s][tx*4];
      acc[0][0]+=s0v*v4.x; acc[0][1]+=s0v*v4.y; acc[0][2]+=s0v*v4.z; acc[0][3]+=s0v*v4.w;
      acc[1][0]+=s1v*v4.x; acc[1][1]+=s1v*v4.y; acc[1][2]+=s1v*v4.z; acc[1][3]+=s1v*v4.w;
      acc[2][0]+=s2v*v4.x; acc[2][1]+=s2v*v4.y; acc[2][2]+=s2v*v4.z; acc[2][3]+=s2v*v4.w;
      acc[3][0]+=s3v*v4.x; acc[3][1]+=s3v*v4.y; acc[3][2]+=s3v*v4.z; acc[3][3]+=s3v*v4.w;
    }
    __syncthreads();
  }
  const float* stin = STIN + (size_t)(c*8+h)*4096;
#pragma unroll
  for (int it=0; it<4; it++){
    int idx = t + it*256;
    int r = idx>>4, c4 = (idx&15)<<2;
    float4 v = *(const float4*)(stin + r*64 + c4);
    sT[c4+0][r]=v.x; sT[c4+1][r]=v.y; sT[c4+2][r]=v.z; sT[c4+3][r]=v.w;
  }
  __syncthreads();
  float osc[4][4] = {{0.f}};
#pragma unroll
  for (int n=0;n<64;n++){
    float4 q4 = *(const float4*)&qT[n][ty*4];
    float4 p4 = *(const float4*)&sT[n][tx*4];
    osc[0][0]+=q4.x*p4.x; osc[0][1]+=q4.x*p4.y; osc[0][2]+=q4.x*p4.z; osc[0][3]+=q4.x*p4.w;
    osc[1][0]+=q4.y*p4.x; osc[1][1]+=q4.y*p4.y; osc[1][2]+=q4.y*p4.z; osc[1][3]+=q4.y*p4.w;
    osc[2][0]+=q4.z*p4.x; osc[2][1]+=q4.z*p4.y; osc[2][2]+=q4.z*p4.z; osc[2][3]+=q4.z*p4.w;
    osc[3][0]+=q4.w*p4.x; osc[3][1]+=q4.w*p4.y; osc[3][2]+=q4.w*p4.z; osc[3][3]+=q4.w*p4.w;
  }
  float dsk = dskip[h];
#pragma unroll
  for (int i=0;i<4;i++){
    float el = expf(acsl[i]);
    size_t grow = tok0 + l0 + ty*4 + i;
    float4 xs = ld4(XC + grow*640 + h*64 + tx*4);
    st4(Y + grow*512 + h*64 + tx*4,
        acc[i][0] + el*osc[i][0] + dsk*xs.x,
        acc[i][1] + el*osc[i][1] + dsk*xs.y,
        acc[i][2] + el*osc[i][2] + dsk*xs.z,
        acc[i][3] + el*osc[i][3] + dsk*xs.w);
  }
}

// ---------------- u = y*silu(z); RMSNorm*w over 512 (per batch, in place) --
__global__ __launch_bounds__(256) void urms_k(
    u16* Y, const u16* __restrict__ Z, const float* __restrict__ nw)
{
  int tok = blockIdx.x*4 + (threadIdx.x>>6);
  int lane = threadIdx.x & 63;
  size_t base = (size_t)tok*512 + lane*8;
  float y[8], z[8], u[8];
  ld8(Y+base, y); ld8(Z+base, z);
  float ss=0.f;
#pragma unroll
  for (int e=0;e<8;e++){ u[e] = y[e]*silu_(z[e]); ss += u[e]*u[e]; }
  ss = wsum_(ss);
  float r = rsqrtf(ss*(1.f/512.f) + 1e-5f);
  float4 w0 = *(const float4*)(nw + lane*8);
  float4 w1 = *(const float4*)(nw + lane*8 + 4);
  float o[8];
  o[0]=u[0]*r*w0.x; o[1]=u[1]*r*w0.y; o[2]=u[2]*r*w0.z; o[3]=u[3]*r*w0.w;
  o[4]=u[4]*r*w1.x; o[5]=u[5]*r*w1.y; o[6]=u[6]*r*w1.z; o[7]=u[7]*r*w1.w;
  st8(Y+base, o);
}

// ---------------- scatter (window rows of batch -> token layout) -----------
__global__ __launch_bounds__(256) void scatter_k(const u16* __restrict__ XAW, u16* __restrict__ XA, int r0)
{
  int gid = blockIdx.x*256 + threadIdx.x;
  int r = gid>>6, c4 = (gid&63)<<2;
  int tok = winmap_tok(r0 + r);
  *(uint2*)(XA + (size_t)tok*256 + c4) = *(const uint2*)(XAW + (size_t)r*256 + c4);
}

// ---------------- window attention per (window, head), per batch -----------
__global__ __launch_bounds__(256) void attn_k(
    const u16* __restrict__ QKV, const float* __restrict__ rpb, u16* __restrict__ OW)
{
  int win = blockIdx.x;     // local window 0..63
  int head = blockIdx.y;
  __shared__ float qs[64][36], ks[64][36], vs[64][36];
  __shared__ float ssm[64][65];
  __shared__ int rid[64];
  int t = threadIdx.x;
  const float scale = 0.17677669529663687f;  // 32^-0.5
#pragma unroll
  for (int it=0; it<2; it++){
    int idx = t + it*256;
    int r = idx>>3, c4 = (idx&7)<<2;
    const u16* base = QKV + ((size_t)win*64 + r)*768 + head*32 + c4;
    float4 q4 = ld4(base);
    float4 k4 = ld4(base + 256);
    float4 v4 = ld4(base + 512);
    qs[r][c4+0]=q4.x*scale; qs[r][c4+1]=q4.y*scale; qs[r][c4+2]=q4.z*scale; qs[r][c4+3]=q4.w*scale;
    *(float4*)&ks[r][c4] = k4;
    *(float4*)&vs[r][c4] = v4;
  }
  if (t < 64){
    int h2 = ((win>>3)<<3) + (t>>3);
    int w2 = ((win&7)<<3) + (t&7);
    int rh = (h2<56)?0:((h2<60)?1:2);
    int rw = (w2<56)?0:((w2<60)?1:2);
    rid[t] = rh*3 + rw;
  }
  __syncthreads();
  int i = t>>2, jb = t&3;
#pragma unroll
  for (int jj=0; jj<16; jj++){
    int j = jb*16 + jj;
    float s = 0.f;
#pragma unroll
    for (int d4=0; d4<8; d4++){
      float4 q4 = *(const float4*)&qs[i][d4*4];
      float4 k4 = *(const float4*)&ks[j][d4*4];
      s += q4.x*k4.x + q4.y*k4.y + q4.z*k4.z + q4.w*k4.w;
    }
    int di = (i>>3) - (j>>3);
    int dj = (i&7) - (j&7);
    s += rpb[((di+7)*15 + (dj+7))*8 + head];
    if (rid[i] != rid[j]) s -= 100.f;
    ssm[i][j] = s;
  }
  __syncthreads();
  if (t < 64){
    float mx = -1e30f;
#pragma unroll
    for (int j=0;j<64;j++) mx = fmaxf(mx, ssm[t][j]);
    float sum = 0.f;
#pragma unroll
    for (int j=0;j<64;j++){ float e = expf(ssm[t][j]-mx); ssm[t][j]=e; sum+=e; }
    float inv = 1.f/sum;
#pragma unroll
    for (int j=0;j<64;j++) ssm[t][j] *= inv;
  }
  __syncthreads();
  int d0 = (t&3)*8;
  float o[8] = {0.f,0.f,0.f,0.f,0.f,0.f,0.f,0.f};
#pragma unroll
  for (int j=0;j<64;j++){
    float pv = ssm[i][j];
    float4 va = *(const float4*)&vs[j][d0];
    float4 vb = *(const float4*)&vs[j][d0+4];
    o[0]+=pv*va.x; o[1]+=pv*va.y; o[2]+=pv*va.z; o[3]+=pv*va.w;
    o[4]+=pv*vb.x; o[5]+=pv*vb.y; o[6]+=pv*vb.z; o[7]+=pv*vb.w;
  }
  st8(OW + ((size_t)win*64 + i)*256 + head*32 + d0, o);
}

// ---------------- xm *= gm ; xa *= ga (bf16) -------------------------------
__global__ __launch_bounds__(256) void mul2_k(
    u16* XM, const u16* __restrict__ GM, u16* XA, const u16* __restrict__ GA)
{
  size_t i = ((size_t)blockIdx.x*256 + threadIdx.x)*4;
  float4 m = ld4(XM+i), g = ld4(GM+i);
  st4(XM+i, m.x*g.x, m.y*g.y, m.z*g.z, m.w*g.w);
  float4 a = ld4(XA+i), g2 = ld4(GA+i);
  st4(XA+i, a.x*g2.x, a.y*g2.y, a.z*g2.z, a.w*g2.w);
}

// ---------------- host ------------------------------------------------------
extern "C" void kernel_launch(void* const* d_in, const int* in_sizes, int n_in,
                              void* d_out, int out_size, void* d_ws, size_t ws_size,
                              hipStream_t stream)
{
  (void)in_sizes; (void)n_in; (void)out_size;
  const size_t OFF_XN   = 0;               // bf16 32768x256 (later XA)
  const size_t OFF_XNS  = 16777216;        // bf16 32768x256 (later XM)
  const size_t OFF_SP   = 33554432;        // bf16 32768x256 (later GM)
  const size_t OFF_DTRAW= 50331648;        // f32 32768x8
  const size_t OFF_DT   = 51380224;
  const size_t OFF_AA   = 52428800;
  const size_t OFF_ACS  = 53477376;
  const size_t OFF_WTS  = 54525952;        // bf16 weights (3,276,800 B used)
  const size_t U7       = 58195968;        // phase arena (23,068,672 B)
  const size_t NEED     = 81264640;
  if (ws_size < NEED) return;

  const float* x       = (const float*)d_in[0];
  const float* ln1_w   = (const float*)d_in[1];
  const float* ln1_b   = (const float*)d_in[2];
  const float* ns_w    = (const float*)d_in[3];
  const float* ns_b    = (const float*)d_in[4];
  const float* m_win   = (const float*)d_in[5];
  const float* m_conv_w= (const float*)d_in[6];
  const float* m_conv_b= (const float*)d_in[7];
  const float* m_dt_b  = (const float*)d_in[8];
  const float* m_a_log = (const float*)d_in[9];
  const float* m_d     = (const float*)d_in[10];
  const float* m_norm_w= (const float*)d_in[11];
  const float* m_wout  = (const float*)d_in[12];
  const float* tm_w1   = (const float*)d_in[13];
  const float* tm_b1   = (const float*)d_in[14];
  const float* tm_w2   = (const float*)d_in[15];
  const float* tm_b2   = (const float*)d_in[16];
  const float* nt_w    = (const float*)d_in[17];
  const float* nt_b    = (const float*)d_in[18];
  const float* qkv_w   = (const float*)d_in[19];
  const float* qkv_b   = (const float*)d_in[20];
  const float* rpb     = (const float*)d_in[21];
  const float* gate_w  = (const float*)d_in[22];
  const float* gate_b  = (const float*)d_in[23];
  const float* proj_w  = (const float*)d_in[24];
  const float* proj_b  = (const float*)d_in[25];
  const float* cg_w1a  = (const float*)d_in[26];
  const float* cg_b1a  = (const float*)d_in[27];
  const float* cg_w2a  = (const float*)d_in[28];
  const float* cg_b2a  = (const float*)d_in[29];
  const float* cg_w1m  = (const float*)d_in[30];
  const float* cg_b1m  = (const float*)d_in[31];
  const float* cg_w2m  = (const float*)d_in[32];
  const float* cg_b2m  = (const float*)d_in[33];
  const float* cg_wf   = (const float*)d_in[34];
  const float* cg_bf   = (const float*)d_in[35];
  const float* ln2_w   = (const float*)d_in[36];
  const float* ln2_b   = (const float*)d_in[37];
  const float* mlp_w1  = (const float*)d_in[38];
  const float* mlp_b1  = (const float*)d_in[39];
  const float* mlp_w2  = (const float*)d_in[40];
  const float* mlp_b2  = (const float*)d_in[41];
  float* dout = (float*)d_out;
  char* ws = (char*)d_ws;

  u16*  XN   = (u16*)(ws + OFF_XN);
  u16*  XNS  = (u16*)(ws + OFF_XNS);
  u16*  SP   = (u16*)(ws + OFF_SP);
  float* DTRAW = (float*)(ws + OFF_DTRAW);
  float* DT  = (float*)(ws + OFF_DT);
  float* AA  = (float*)(ws + OFF_AA);
  float* ACS = (float*)(ws + OFF_ACS);
  u16*  WTS  = (u16*)(ws + OFF_WTS);
  // bf16 transposed weights [N][K] (element offsets)
  u16* WT_XBC = WTS + 0;        // 640x256
  u16* WT_Z   = WTS + 163840;   // 512x256
  u16* WT_WOUT= WTS + 294912;   // 256x512
  u16* WT_TM1 = WTS + 425984;   // 256x512
  u16* WT_TM2 = WTS + 491520;   // 256x256
  u16* WT_QKV = WTS + 557056;   // 768x256
  u16* WT_GATE= WTS + 753664;   // 256x256
  u16* WT_PROJ= WTS + 819200;   // 256x256
  u16* WT_W2A = WTS + 884736;   // 256x64
  u16* WT_W2M = WTS + 901120;   // 256x64
  u16* WT_WF  = WTS + 917504;   // 256x512
  u16* WT_MLP1= WTS + 1048576;  // 1024x256
  u16* WT_MLP2= WTS + 1310720;  // 256x1024
  // arena
  u16*  XBCc = (u16*)(ws + U7);
  u16*  XCc  = (u16*)(ws + U7 + 5242880);
  float* ST  = (float*)(ws + U7 + 10485760);
  float* STIN= (float*)(ws + U7 + 12582912);
  u16*  Yc   = (u16*)(ws + U7 + 14680064);
  u16*  Zc   = (u16*)(ws + U7 + 18874368);
  u16*  TBUF = (u16*)(ws + U7);                 // G
  u16*  XM   = XNS;
  u16*  QKVc = (u16*)(ws + U7);                 // H
  u16*  OWc  = (u16*)(ws + U7 + 6291456);
  u16*  XAWc = (u16*)(ws + U7 + 8388608);
  u16*  XA   = XN;
  u16*  CGH  = (u16*)(ws + U7);                 // I
  u16*  GA   = (u16*)(ws + U7 + 4194304);
  u16*  GM   = SP;
  u16*  LNc  = (u16*)(ws + U7);                 // J
  u16*  MHc  = (u16*)(ws + U7 + 4194304);

  const size_t TB = 4096*256;
  const size_t H2 = 16384*256;

  // Phase 0: weight convert+transpose (fp32 [K][N] -> bf16 [N][K])
  wt_k<<<dim3(8,20),256,0,stream>>>(m_win+512,1160,256, WT_XBC);
  wt_k<<<dim3(8,16),256,0,stream>>>(m_win,    1160,256, WT_Z);
  wt_k<<<dim3(16,8),256,0,stream>>>(m_wout,    256,512, WT_WOUT);
  wt_k<<<dim3(16,8),256,0,stream>>>(tm_w1,     256,512, WT_TM1);
  wt_k<<<dim3(8,8), 256,0,stream>>>(tm_w2,     256,256, WT_TM2);
  wt_k<<<dim3(8,24),256,0,stream>>>(qkv_w,     768,256, WT_QKV);
  wt_k<<<dim3(8,8), 256,0,stream>>>(gate_w,    256,256, WT_GATE);
  wt_k<<<dim3(8,8), 256,0,stream>>>(proj_w,    256,256, WT_PROJ);
  wt_k<<<dim3(2,8), 256,0,stream>>>(cg_w2a,    256,64,  WT_W2A);
  wt_k<<<dim3(2,8), 256,0,stream>>>(cg_w2m,    256,64,  WT_W2M);
  wt_k<<<dim3(16,8),256,0,stream>>>(cg_wf,     256,512, WT_WF);
  wt_k<<<dim3(8,32),256,0,stream>>>(mlp_w1,   1024,256, WT_MLP1);
  wt_k<<<dim3(32,8),256,0,stream>>>(mlp_w2,    256,1024,WT_MLP2);

  // Phase A: xn = LN(x); xns = LN(xn); dt path
  ln2x_k<<<8192,256,0,stream>>>(x, ln1_w, ln1_b, ns_w, ns_b, XN, XNS);
  gemm_k<EPI_NONE,float,float><<<dim3(1,512),256,0,stream>>>(XNS,nullptr,256,0, m_win+1152,1160, nullptr, nullptr, DTRAW, 32768,8);
  dtk_k<<<1024,256,0,stream>>>(DTRAW, m_dt_b, m_a_log, DT, AA);
  acs_k<<<256,256,0,stream>>>(AA, ACS);

  // Phases B..F per batch
  for (int b=0; b<8; b++){
    const u16* XNSb = XNS + (size_t)b*TB;
    const float* DTb = DT + (size_t)b*32768;
    const float* ACSb = ACS + (size_t)b*32768;
    mgemm_k<64,EPI_NONE,false,float,u16><<<dim3(5,64),256,0,stream>>>(XNSb,nullptr,256,0, WT_XBC, nullptr, nullptr, XBCc, 640, 0);
    conv_k<<<2560,256,0,stream>>>(XBCc, m_conv_w, m_conv_b, XCc);
    states_k<<<128,256,0,stream>>>(XCc, DTb, ACSb, ST);
    scan_k<<<8,256,0,stream>>>(ST, ACSb, STIN);
    ydy_k<<<512,256,0,stream>>>(XCc, DTb, ACSb, STIN, m_d, Yc);
    mgemm_k<64,EPI_NONE,false,float,u16><<<dim3(4,64),256,0,stream>>>(XNSb,nullptr,256,0, WT_Z, nullptr, nullptr, Zc, 512, 0);
    urms_k<<<1024,256,0,stream>>>(Yc, Zc, m_norm_w);
    mgemm_k<64,EPI_ADD,false,u16,u16><<<dim3(2,64),256,0,stream>>>(Yc,nullptr,512,0, WT_WOUT, nullptr, XN + (size_t)b*TB, SP + (size_t)b*TB, 256, 0);
  }

  // Phase G: tmix (sequential f0 then f1)
  mgemm_k<128,EPI_SILU,false,float,u16><<<dim3(2,128),256,0,stream>>>(SP, SP+H2, 256,256, WT_TM1, tm_b1, nullptr, TBUF, 256, 0);
  mgemm_k<128,EPI_ADD,false,u16,u16><<<dim3(2,128),256,0,stream>>>(TBUF,nullptr,256,0, WT_TM2, tm_b2, SP, XM, 256, 0);
  ln_k<u16><<<4096,256,0,stream>>>(XM, nt_w, nt_b, XM);
  mgemm_k<128,EPI_SILU,false,float,u16><<<dim3(2,128),256,0,stream>>>(SP+H2, XM, 256,256, WT_TM1, tm_b1, nullptr, TBUF, 256, 0);
  mgemm_k<128,EPI_ADD,false,u16,u16><<<dim3(2,128),256,0,stream>>>(TBUF,nullptr,256,0, WT_TM2, tm_b2, SP+H2, XM+H2, 256, 0);
  ln_k<u16><<<4096,256,0,stream>>>(XM+H2, nt_w, nt_b, XM+H2);

  // Phase H: window attention on xn (per batch; gather fused into A-loads)
  for (int b=0; b<8; b++){
    int r0 = b*4096;
    mgemm_k<64,EPI_NONE,true,float,u16><<<dim3(6,64),256,0,stream>>>(XN,nullptr,256,0, WT_QKV, qkv_b, nullptr, QKVc, 768, r0);
    attn_k<<<dim3(64,8),256,0,stream>>>(QKVc, rpb, OWc);
    mgemm_k<64,EPI_SIGMUL,true,u16,u16><<<dim3(2,64),256,0,stream>>>(XN,nullptr,256,0, WT_GATE, gate_b, OWc, OWc, 256, r0);
    mgemm_k<64,EPI_NONE,false,float,u16><<<dim3(2,64),256,0,stream>>>(OWc,nullptr,256,0, WT_PROJ, proj_b, nullptr, XAWc, 256, 0);
    scatter_k<<<1024,256,0,stream>>>(XAWc, XA, r0);
  }

  // Phase I: cross gates; xo = x + cat(xm*gm, xa*ga)@cg_wf + cg_bf -> d_out
  gemm_k<EPI_RELU,float,u16><<<dim3(1,512),256,0,stream>>>(XA,nullptr,256,0, cg_w1a,64, cg_b1a, nullptr, CGH, 32768,64);
  mgemm_k<128,EPI_SIGMOID,false,float,u16><<<dim3(2,256),256,0,stream>>>(CGH,nullptr,64,0, WT_W2A, cg_b2a, nullptr, GM, 256, 0);
  gemm_k<EPI_RELU,float,u16><<<dim3(1,512),256,0,stream>>>(XM,nullptr,256,0, cg_w1m,64, cg_b1m, nullptr, CGH, 32768,64);
  mgemm_k<128,EPI_SIGMOID,false,float,u16><<<dim3(2,256),256,0,stream>>>(CGH,nullptr,64,0, WT_W2M, cg_b2m, nullptr, GA, 256, 0);
  mul2_k<<<8192,256,0,stream>>>(XM, GM, XA, GA);
  mgemm_k<128,EPI_ADD,false,float,float><<<dim3(2,256),256,0,stream>>>(XM, XA, 256,256, WT_WF, cg_bf, x, dout, 256, 0);

  // Phase J: MLP per 8192-row slab; out = xo + gelu(ln(xo)@w1+b1)@w2+b2
  for (int q=0; q<4; q++){
    float* XOq = dout + (size_t)q*8192*256;
    ln_k<float><<<2048,256,0,stream>>>(XOq, ln2_w, ln2_b, LNc);
    mgemm_k<128,EPI_GELU,false,float,u16><<<dim3(8,64),256,0,stream>>>(LNc,nullptr,256,0, WT_MLP1, mlp_b1, nullptr, MHc, 1024, 0);
    mgemm_k<64,EPI_ADD,false,float,float><<<dim3(2,128),256,0,stream>>>(MHc,nullptr,1024,0, WT_MLP2, mlp_b2, XOq, XOq, 256, 0);
  }
}

// Round 4
// 1123.538 us; speedup vs baseline: 2.9883x; 1.8039x over previous
//
#include <hip/hip_runtime.h>
#include <math.h>

// twoB=8, L=4096 (H=W=64), C=256, d_inner=512, nh_m=8, hd=64, D_STATE=64,
// conv_dim=640, zx width=1160, CHUNK=256 (16 chunks/batch), WS=8, SS=4, NH=8, Dh=32.

#define DEVI static __device__ __forceinline__
typedef unsigned short u16;
typedef unsigned int   u32;
typedef __attribute__((ext_vector_type(8))) short s16x8;
typedef __attribute__((ext_vector_type(4))) float f32x4;

DEVI float sigm_(float x){ return 1.f/(1.f+expf(-x)); }
DEVI float silu_(float x){ return x/(1.f+expf(-x)); }
DEVI float wsum_(float v){
#pragma unroll
  for (int o=32;o>0;o>>=1) v += __shfl_xor(v,o,64);
  return v;
}

DEVI float b2f(u16 u){ union{u32 i; float f;} v; v.i = ((u32)u)<<16; return v.f; }
DEVI u16 f2b(float f){ union{float f; u32 i;} v; v.f=f; u32 r = v.i + 0x7fffu + ((v.i>>16)&1u); return (u16)(r>>16); }
DEVI float4 ld4(const float* p){ return *(const float4*)p; }
DEVI float4 ld4(const u16* p){
  uint2 r = *(const uint2*)p;
  return make_float4(b2f((u16)(r.x&0xffff)), b2f((u16)(r.x>>16)),
                     b2f((u16)(r.y&0xffff)), b2f((u16)(r.y>>16)));
}
DEVI void st4(u16* p, float a, float b, float c, float d){
  uint2 r; r.x = (u32)f2b(a) | ((u32)f2b(b)<<16); r.y = (u32)f2b(c) | ((u32)f2b(d)<<16);
  *(uint2*)p = r;
}
DEVI void ld8(const u16* p, float* f){
  uint4 r = *(const uint4*)p;
  f[0]=b2f((u16)(r.x&0xffff)); f[1]=b2f((u16)(r.x>>16));
  f[2]=b2f((u16)(r.y&0xffff)); f[3]=b2f((u16)(r.y>>16));
  f[4]=b2f((u16)(r.z&0xffff)); f[5]=b2f((u16)(r.z>>16));
  f[6]=b2f((u16)(r.w&0xffff)); f[7]=b2f((u16)(r.w>>16));
}
DEVI void st8(u16* p, const float* f){
  uint4 r;
  r.x=(u32)f2b(f[0])|((u32)f2b(f[1])<<16); r.y=(u32)f2b(f[2])|((u32)f2b(f[3])<<16);
  r.z=(u32)f2b(f[4])|((u32)f2b(f[5])<<16); r.w=(u32)f2b(f[6])|((u32)f2b(f[7])<<16);
  *(uint4*)p = r;
}
DEVI float tof(float v){ return v; }
DEVI float tof(u16 v){ return b2f(v); }
DEVI void sto(float* p, float v){ *p = v; }
DEVI void sto(u16* p, float v){ *p = f2b(v); }

// window row -> token map (roll by -4, 8x8 windows over 64x64, per batch)
DEVI int winmap_tok(int r){
  int win = r>>6, tk = r&63;
  int b = win>>6, wid = win&63;
  int h2 = ((wid>>3)<<3) + (tk>>3);
  int w2 = ((wid&7)<<3) + (tk&7);
  int hh = (h2+4)&63, wwp = (w2+4)&63;
  return b*4096 + hh*64 + wwp;
}

// ---------------- fused LN(x)->xn, LN(xn)->xns (bf16 outs) -----------------
__global__ __launch_bounds__(256) void ln2x_k(
    const float* __restrict__ x, const float* __restrict__ w1, const float* __restrict__ b1,
    const float* __restrict__ w2, const float* __restrict__ b2,
    u16* __restrict__ xn, u16* __restrict__ xns)
{
  int tok = blockIdx.x*4 + (threadIdx.x>>6);
  int lane = threadIdx.x & 63;
  size_t base = (size_t)tok*256 + lane*4;
  float4 v = *(const float4*)(x + base);
  float mu = wsum_(v.x+v.y+v.z+v.w) * (1.f/256.f);
  float ax=v.x-mu, ay=v.y-mu, az=v.z-mu, aw=v.w-mu;
  float var = wsum_(ax*ax+ay*ay+az*az+aw*aw) * (1.f/256.f);
  float r = rsqrtf(var+1e-5f);
  float4 wv = *(const float4*)(w1+lane*4);
  float4 bv = *(const float4*)(b1+lane*4);
  float ox=ax*r*wv.x+bv.x, oy=ay*r*wv.y+bv.y, oz=az*r*wv.z+bv.z, ow=aw*r*wv.w+bv.w;
  st4(xn + base, ox, oy, oz, ow);
  float mu2 = wsum_(ox+oy+oz+ow)*(1.f/256.f);
  float bx=ox-mu2, by=oy-mu2, bz=oz-mu2, bw=ow-mu2;
  float var2 = wsum_(bx*bx+by*by+bz*bz+bw*bw)*(1.f/256.f);
  float r2 = rsqrtf(var2+1e-5f);
  float4 w2v = *(const float4*)(w2+lane*4);
  float4 b2v = *(const float4*)(b2+lane*4);
  st4(xns + base, bx*r2*w2v.x+b2v.x, by*r2*w2v.y+b2v.y, bz*r2*w2v.z+b2v.z, bw*r2*w2v.w+b2v.w);
}

// ---------------- generic LayerNorm (C=256), bf16 out ----------------------
template<typename IT>
__global__ __launch_bounds__(256) void ln_k(
    const IT* __restrict__ in, const float* __restrict__ w, const float* __restrict__ b,
    u16* __restrict__ outp)
{
  int tok = blockIdx.x*4 + (threadIdx.x>>6);
  int lane = threadIdx.x & 63;
  size_t base = (size_t)tok*256 + lane*4;
  float4 v = ld4(in + base);
  float mu = wsum_(v.x+v.y+v.z+v.w) * (1.f/256.f);
  float ax=v.x-mu, ay=v.y-mu, az=v.z-mu, aw=v.w-mu;
  float var = wsum_(ax*ax+ay*ay+az*az+aw*aw) * (1.f/256.f);
  float r = rsqrtf(var+1e-5f);
  float4 wv = *(const float4*)(w+lane*4);
  float4 bv = *(const float4*)(b+lane*4);
  st4(outp + base, ax*r*wv.x+bv.x, ay*r*wv.y+bv.y, az*r*wv.z+bv.z, aw*r*wv.w+bv.w);
}

// ---------------- weight fp32[K][N](ldw) -> bf16 Wt[N][K] ------------------
__global__ __launch_bounds__(256) void wt_k(
    const float* __restrict__ W, int ldw, int K, u16* __restrict__ Wt)
{
  __shared__ float tl[32][33];
  int k0 = blockIdx.x*32, n0 = blockIdx.y*32;
  int t = threadIdx.x; int ty=t>>5, tx=t&31;
#pragma unroll
  for (int i=0;i<4;i++){
    int k = ty + i*8;
    tl[k][tx] = W[(size_t)(k0+k)*ldw + n0+tx];
  }
  __syncthreads();
#pragma unroll
  for (int i=0;i<4;i++){
    int n = ty + i*8;
    Wt[(size_t)(n0+n)*K + k0 + tx] = f2b(tl[tx][n]);
  }
}

enum { EPI_NONE=0, EPI_SILU=1, EPI_GELU=2, EPI_SIGMUL=3, EPI_ADD=4, EPI_RELU=5, EPI_SIGMOID=6 };

// -------- MFMA GEMM: out[M,N] = epi(cat(A1,A2)[M,K] @ Wt[N,K]^T + bias) ----
// BK=32, 4 waves (2x2). WIN: gather A rows via winmap. WINST: scatter out rows.
template<int BM, int BN, int EPI, bool WIN, bool WINST, typename OT, typename CT>
__global__ __launch_bounds__(256) void mgemm_k(
    const u16* __restrict__ A1, const u16* __restrict__ A2, int K1, int K2,
    const u16* __restrict__ Wt, const float* __restrict__ bias,
    const OT* other, CT* outp, int N, int r0)
{
  constexpr int MW = BM/32;
  constexpr int NWF = BN/32;
  constexpr int LA = BM/64;
  constexpr int LB = BN/64;
  __shared__ u16 As[BM][40];
  __shared__ u16 Bs[BN][40];
  int m0 = blockIdx.y*BM, n0 = blockIdx.x*BN;
  int t = threadIdx.x;
  int lane = t&63, w = t>>6;
  int wr = w>>1, wc = w&1;
  int K = K1 + K2;
  f32x4 acc[MW][NWF];
#pragma unroll
  for (int mi=0;mi<MW;mi++)
#pragma unroll
    for (int ni=0;ni<NWF;ni++) acc[mi][ni] = (f32x4){0.f,0.f,0.f,0.f};
  int lrow = t>>2, lc8 = (t&3)*8;
  size_t aoff1[LA], aoff2[LA];
#pragma unroll
  for (int i=0;i<LA;i++){
    int gr = m0 + lrow + i*64;
    if (WIN) aoff1[i] = (size_t)winmap_tok(r0+gr)*K1;
    else { aoff1[i] = (size_t)gr*K1; aoff2[i] = (size_t)gr*K2; }
  }
  for (int k0=0; k0<K; k0+=32){
    int gk = k0 + lc8;
#pragma unroll
    for (int i=0;i<LA;i++){
      const u16* ap = (WIN || gk < K1) ? A1 + aoff1[i] + gk : A2 + aoff2[i] + (gk-K1);
      *(uint4*)&As[lrow + i*64][lc8] = *(const uint4*)ap;
    }
#pragma unroll
    for (int i=0;i<LB;i++){
      int row = lrow + i*64;
      *(uint4*)&Bs[row][lc8] = *(const uint4*)(Wt + (size_t)(n0+row)*K + gk);
    }
    __syncthreads();
    int lg = lane>>4, li = lane&15;
    s16x8 afr[MW], bfr[NWF];
#pragma unroll
    for (int mi=0;mi<MW;mi++)
      afr[mi] = *(const s16x8*)&As[wr*(BM/2)+mi*16+li][lg*8];
#pragma unroll
    for (int ni=0;ni<NWF;ni++)
      bfr[ni] = *(const s16x8*)&Bs[wc*(BN/2)+ni*16+li][lg*8];
#pragma unroll
    for (int mi=0;mi<MW;mi++)
#pragma unroll
      for (int ni=0;ni<NWF;ni++)
        acc[mi][ni] = __builtin_amdgcn_mfma_f32_16x16x32_bf16(afr[mi], bfr[ni], acc[mi][ni], 0,0,0);
    __syncthreads();
  }
  int lg = lane>>4, li = lane&15;
#pragma unroll
  for (int mi=0;mi<MW;mi++){
#pragma unroll
    for (int ni=0;ni<NWF;ni++){
      int gn = n0 + wc*(BN/2) + ni*16 + li;
      float bv = bias ? bias[gn] : 0.f;
#pragma unroll
      for (int r=0;r<4;r++){
        int gm = m0 + wr*(BM/2) + mi*16 + lg*4 + r;
        float v = acc[mi][ni][r] + bv;
        size_t orow = WINST ? (size_t)winmap_tok(r0+gm) : (size_t)gm;
        size_t off = orow*N + gn;
        if (EPI==EPI_SILU)        v = silu_(v);
        else if (EPI==EPI_GELU)   v = 0.5f*v*(1.f+erff(v*0.70710678118654752f));
        else if (EPI==EPI_SIGMUL) v = tof(other[off])*sigm_(v);
        else if (EPI==EPI_ADD)    v = v + tof(other[off]);
        else if (EPI==EPI_RELU)   v = fmaxf(v,0.f);
        else if (EPI==EPI_SIGMOID)v = sigm_(v);
        sto(outp + off, v);
      }
    }
  }
}

// -------- fp32 fallback GEMM (tiny N): out = epi(A[M,K]@W[K,N]+bias) -------
template<int EPI, typename OT, typename CT>
__global__ __launch_bounds__(256) void gemm_k(
    const u16* __restrict__ A1, const u16* __restrict__ A2, int K1, int K2,
    const float* __restrict__ W, int ldw, const float* __restrict__ bias,
    const OT* other, CT* outp, int M, int N)
{
  __shared__ float as[16][68];
  __shared__ float bs[16][64];
  int m0 = blockIdx.y*64, n0 = blockIdx.x*64;
  int t = threadIdx.x;
  int ty = t>>4, tx = t&15;
  float acc[4][4] = {{0.f}};
  int K = K1 + K2;
  int arow = t>>2, ac4 = (t&3)<<2;
  int bkr = t>>4, bnc = (t&15)<<2;
  for (int k0=0; k0<K; k0+=16){
    int gk = k0 + ac4;
    float4 av;
    if (gk < K1) av = ld4(A1 + (size_t)(m0+arow)*K1 + gk);
    else         av = ld4(A2 + (size_t)(m0+arow)*K2 + (gk-K1));
    as[ac4+0][arow]=av.x; as[ac4+1][arow]=av.y; as[ac4+2][arow]=av.z; as[ac4+3][arow]=av.w;
    int gn = n0 + bnc;
    const float* wp = W + (size_t)(k0+bkr)*ldw;
    if (gn+3 < N) {
      *(float4*)&bs[bkr][bnc] = *(const float4*)(wp + gn);
    } else {
#pragma unroll
      for (int j=0;j<4;j++) bs[bkr][bnc+j] = (gn+j<N) ? wp[gn+j] : 0.f;
    }
    __syncthreads();
#pragma unroll
    for (int kk=0; kk<16; kk++){
      float4 a4 = *(const float4*)&as[kk][ty*4];
      float4 b4 = *(const float4*)&bs[kk][tx*4];
      acc[0][0]+=a4.x*b4.x; acc[0][1]+=a4.x*b4.y; acc[0][2]+=a4.x*b4.z; acc[0][3]+=a4.x*b4.w;
      acc[1][0]+=a4.y*b4.x; acc[1][1]+=a4.y*b4.y; acc[1][2]+=a4.y*b4.z; acc[1][3]+=a4.y*b4.w;
      acc[2][0]+=a4.z*b4.x; acc[2][1]+=a4.z*b4.y; acc[2][2]+=a4.z*b4.z; acc[2][3]+=a4.z*b4.w;
      acc[3][0]+=a4.w*b4.x; acc[3][1]+=a4.w*b4.y; acc[3][2]+=a4.w*b4.z; acc[3][3]+=a4.w*b4.w;
    }
    __syncthreads();
  }
#pragma unroll
  for (int i=0;i<4;i++){
    int gm = m0 + ty*4 + i;
#pragma unroll
    for (int j=0;j<4;j++){
      int gn = n0 + tx*4 + j;
      if (gn >= N) continue;
      float v = acc[i][j] + (bias ? bias[gn] : 0.f);
      size_t off = (size_t)gm*N + gn;
      if (EPI==EPI_SILU)        v = silu_(v);
      else if (EPI==EPI_GELU)   v = 0.5f*v*(1.f+erff(v*0.70710678118654752f));
      else if (EPI==EPI_SIGMUL) v = tof(other[off])*sigm_(v);
      else if (EPI==EPI_ADD)    v = v + tof(other[off]);
      else if (EPI==EPI_RELU)   v = fmaxf(v,0.f);
      else if (EPI==EPI_SIGMOID)v = sigm_(v);
      sto(outp + off, v);
    }
  }
}

// ---- fused xBC GEMM (M=64 tile) + causal conv(4) + SiLU -> XC -------------
// grid: (N/128=5, NBtok/64). A = XNSc [tok][256]; Wt = WT_XBC [640][256].
__global__ __launch_bounds__(256) void xbcconv_k(
    const u16* __restrict__ A1, const u16* __restrict__ Wt,
    const float* __restrict__ cw, const float* __restrict__ cb,
    u16* __restrict__ XC)
{
  __shared__ u16 As[64][40];
  __shared__ u16 Ab[3][40];
  __shared__ u16 Bs[128][40];
  __shared__ float Cls[67][132];
  int m0 = blockIdx.y*64, n0 = blockIdx.x*128;
  bool first = ((m0 & 4095) == 0);
  int t = threadIdx.x;
  int lane = t&63, w = t>>6;
  int wr = w>>1, wc = w&1;
  f32x4 acc[2][4];
#pragma unroll
  for (int mi=0;mi<2;mi++)
#pragma unroll
    for (int ni=0;ni<4;ni++) acc[mi][ni] = (f32x4){0.f,0.f,0.f,0.f};
  float acc2[2] = {0.f,0.f};
  int lrow = t>>2, lc8 = (t&3)*8;
  int brow = t/64, bcol = (t%64)*2;        // boundary: threads 0..191
  for (int k0=0; k0<256; k0+=32){
    int gk = k0 + lc8;
    *(uint4*)&As[lrow][lc8] = *(const uint4*)(A1 + (size_t)(m0+lrow)*256 + gk);
    if (t < 12 && !first){
      int r3 = t>>2, seg = t&3;
      *(uint4*)&Ab[r3][seg*8] = *(const uint4*)(A1 + (size_t)(m0-3+r3)*256 + k0 + seg*8);
    }
#pragma unroll
    for (int i=0;i<2;i++){
      int row = lrow + i*64;
      *(uint4*)&Bs[row][lc8] = *(const uint4*)(Wt + (size_t)(n0+row)*256 + gk);
    }
    __syncthreads();
    int lg = lane>>4, li = lane&15;
    s16x8 afr[2], bfr[4];
#pragma unroll
    for (int mi=0;mi<2;mi++)
      afr[mi] = *(const s16x8*)&As[wr*32+mi*16+li][lg*8];
#pragma unroll
    for (int ni=0;ni<4;ni++)
      bfr[ni] = *(const s16x8*)&Bs[wc*64+ni*16+li][lg*8];
#pragma unroll
    for (int mi=0;mi<2;mi++)
#pragma unroll
      for (int ni=0;ni<4;ni++)
        acc[mi][ni] = __builtin_amdgcn_mfma_f32_16x16x32_bf16(afr[mi], bfr[ni], acc[mi][ni], 0,0,0);
    if (t < 192 && !first){
#pragma unroll
      for (int kk=0;kk<32;kk++){
        float a = b2f(Ab[brow][kk]);
        acc2[0] += a * b2f(Bs[bcol][kk]);
        acc2[1] += a * b2f(Bs[bcol+1][kk]);
      }
    }
    __syncthreads();
  }
  {
    int lg = lane>>4, li = lane&15;
#pragma unroll
    for (int mi=0;mi<2;mi++)
#pragma unroll
      for (int ni=0;ni<4;ni++){
        int col = wc*64 + ni*16 + li;
#pragma unroll
        for (int r=0;r<4;r++){
          int rl = wr*32 + mi*16 + lg*4 + r;
          Cls[3+rl][col] = acc[mi][ni][r];
        }
      }
    if (t < 192){
      Cls[brow][bcol]   = first ? 0.f : acc2[0];
      Cls[brow][bcol+1] = first ? 0.f : acc2[1];
    }
  }
  __syncthreads();
  // conv over rows, per column
  int col = t & 127, half = t >> 7;
  int ch = n0 + col;
  float w0 = cw[ch*4+0], w1 = cw[ch*4+1], w2 = cw[ch*4+2], w3 = cw[ch*4+3];
  float bias = cb[ch];
  int r0 = half*32;
  float c0 = Cls[r0+0][col], c1 = Cls[r0+1][col], c2 = Cls[r0+2][col];
#pragma unroll
  for (int rr=0; rr<32; rr++){
    float c3 = Cls[r0+rr+3][col];
    float v = bias + w0*c0 + w1*c1 + w2*c2 + w3*c3;
    XC[(size_t)(m0 + r0 + rr)*640 + ch] = f2b(silu_(v));
    c0=c1; c1=c2; c2=c3;
  }
}

// ---------------- dt: softplus(dtraw+bias); a = -dt*exp(a_log) -------------
__global__ __launch_bounds__(256) void dtk_k(
    const float* __restrict__ DTRAW, const float* __restrict__ dtb, const float* __restrict__ alog,
    float* __restrict__ DT_, float* __restrict__ AA_)
{
  int gid = blockIdx.x*256 + threadIdx.x;     // tok*8 + h
  int h = gid & 7;
  float xv = DTRAW[gid] + dtb[h];
  float sp = (xv > 20.f) ? xv : log1pf(expf(xv));
  DT_[gid] = sp;
  AA_[gid] = -sp * expf(alog[h]);
}

// ---------------- per-chunk inclusive cumsum of a (full) -------------------
__global__ __launch_bounds__(256) void acs_k(const float* __restrict__ AA_, float* __restrict__ ACS_)
{
  int wid = (blockIdx.x<<2) + (threadIdx.x>>6);   // 0..1023 = (b*8+h)*16+c
  int lane = threadIdx.x & 63;
  int c  = wid & 15;
  int bh = wid >> 4;
  int b  = bh >> 3, h = bh & 7;
  size_t tok0 = (size_t)b*4096 + c*256 + lane*4;
  float v0 = AA_[(tok0+0)*8 + h];
  float v1 = AA_[(tok0+1)*8 + h];
  float v2 = AA_[(tok0+2)*8 + h];
  float v3 = AA_[(tok0+3)*8 + h];
  v1 += v0; v2 += v1; v3 += v2;
  float tot = v3, s = tot;
#pragma unroll
  for (int o=1;o<64;o<<=1){
    float u = __shfl_up(s, o, 64);
    if (lane >= o) s += u;
  }
  float excl = s - tot;
  float* dst = ACS_ + (size_t)bh*4096 + c*256 + lane*4;
  dst[0]=excl+v0; dst[1]=excl+v1; dst[2]=excl+v2; dst[3]=excl+v3;
}

// ---------------- chunk end-states: ST[((b*16+c)*8+h)][p][n] ---------------
__global__ __launch_bounds__(256) void states_k(
    const u16* __restrict__ XC, const float* __restrict__ DTc, const float* __restrict__ ACSc,
    float* __restrict__ ST)
{
  int bid = blockIdx.x;                  // b_loc*128 + c*8 + h
  int h = bid & 7, c = (bid>>3)&15, bl = bid>>7;
  __shared__ float bsh[16][64];
  __shared__ float xsh[16][64];
  int t = threadIdx.x, ty=t>>4, tx=t&15;
  const float* acs = ACSc + ((size_t)(bl*8+h))*4096 + c*256;
  float aL = acs[255];
  size_t tok0 = (size_t)bl*4096 + c*256;
  float acc[4][4] = {{0.f}};
  int sr = t>>4, nc = (t&15)<<2;
  for (int s0=0; s0<256; s0+=16){
    size_t grow = tok0 + s0 + sr;
    float w = expf(aL - acs[s0+sr]);
    float4 bv = ld4(XC + grow*640 + 512 + nc);
    bsh[sr][nc+0]=bv.x*w; bsh[sr][nc+1]=bv.y*w; bsh[sr][nc+2]=bv.z*w; bsh[sr][nc+3]=bv.w*w;
    float dtv = DTc[grow*8 + h];
    float4 xv = ld4(XC + grow*640 + h*64 + nc);
    xsh[sr][nc+0]=xv.x*dtv; xsh[sr][nc+1]=xv.y*dtv; xsh[sr][nc+2]=xv.z*dtv; xsh[sr][nc+3]=xv.w*dtv;
    __syncthreads();
#pragma unroll
    for (int kk=0;kk<16;kk++){
      float4 p4 = *(const float4*)&xsh[kk][ty*4];
      float4 n4 = *(const float4*)&bsh[kk][tx*4];
      acc[0][0]+=p4.x*n4.x; acc[0][1]+=p4.x*n4.y; acc[0][2]+=p4.x*n4.z; acc[0][3]+=p4.x*n4.w;
      acc[1][0]+=p4.y*n4.x; acc[1][1]+=p4.y*n4.y; acc[1][2]+=p4.y*n4.z; acc[1][3]+=p4.y*n4.w;
      acc[2][0]+=p4.z*n4.x; acc[2][1]+=p4.z*n4.y; acc[2][2]+=p4.z*n4.z; acc[2][3]+=p4.z*n4.w;
      acc[3][0]+=p4.w*n4.x; acc[3][1]+=p4.w*n4.y; acc[3][2]+=p4.w*n4.z; acc[3][3]+=p4.w*n4.w;
    }
    __syncthreads();
  }
  float* dst = ST + (size_t)bid*4096;
#pragma unroll
  for (int i=0;i<4;i++)
#pragma unroll
    for (int j=0;j<4;j++)
      dst[(ty*4+i)*64 + tx*4+j] = acc[i][j];
}

// ---------------- sequential inter-chunk scan; STIN out bf16 ---------------
__global__ __launch_bounds__(256) void scan_k(
    const float* __restrict__ ST, const float* __restrict__ ACSc, u16* __restrict__ STIN)
{
  int bl = blockIdx.x>>3, h = blockIdx.x&7;
  int t = threadIdx.x;
  float hr[16];
#pragma unroll
  for (int e=0;e<16;e++) hr[e]=0.f;
  for (int c=0;c<16;c++){
    float dec = expf(ACSc[((size_t)(bl*8+h))*4096 + c*256 + 255]);
    size_t base = ((size_t)((bl*16+c)*8+h))*4096;
#pragma unroll
    for (int e=0;e<16;e++){
      size_t idx = base + e*256 + t;
      float st = ST[idx];
      STIN[idx] = f2b(hr[e]);
      hr[e] = hr[e]*dec + st;
    }
  }
}

// ---------------- Y = Yd + Yo + d_skip*xs ----------------------------------
__global__ __launch_bounds__(256) void ydy_k(
    const u16* __restrict__ XC, const float* __restrict__ DTc,
    const float* __restrict__ ACSc, const u16* __restrict__ STIN,
    const float* __restrict__ dskip, u16* __restrict__ Y)
{
  int bid = blockIdx.x;                      // bl*512 + (c*8+h)*4 + lt
  int lt = bid & 3, h = (bid>>2)&7, c = (bid>>5)&15, bl = bid>>9;
  int l0 = lt*64;
  __shared__ float smem[10624];
  float (*qT)[68]  = (float(*)[68])smem;            // [n][l]
  float (*kT)[33]  = (float(*)[33])(smem+4352);     // [n][s]
  float (*vsh)[64] = (float(*)[64])(smem+6464);     // [s][p]
  float (*ssh)[33] = (float(*)[33])(smem+8512);     // [l][s]
  float (*sT)[68]  = (float(*)[68])(smem+4352);     // [n][p] overlays
  int t = threadIdx.x, ty=t>>4, tx=t&15;
  const float* acs = ACSc + ((size_t)(bl*8+h))*4096 + c*256;
  size_t tok0 = (size_t)bl*4096 + c*256;
#pragma unroll
  for (int it=0; it<4; it++){
    int idx = t + it*256;
    int r = idx>>4, c4 = (idx&15)<<2;
    float4 v = ld4(XC + (tok0 + l0 + r)*640 + 576 + c4);
    qT[c4+0][r]=v.x; qT[c4+1][r]=v.y; qT[c4+2][r]=v.z; qT[c4+3][r]=v.w;
  }
  float acsl[4];
#pragma unroll
  for (int i=0;i<4;i++) acsl[i] = acs[l0 + ty*4 + i];
  float acc[4][4] = {{0.f}};
  for (int s0=0; s0 < l0+64; s0+=32){
#pragma unroll
    for (int it=0; it<2; it++){
      int idx = t + it*256;
      int r = idx>>4, c4 = (idx&15)<<2;
      size_t grow = tok0 + s0 + r;
      float4 bv = ld4(XC + grow*640 + 512 + c4);
      kT[c4+0][r]=bv.x; kT[c4+1][r]=bv.y; kT[c4+2][r]=bv.z; kT[c4+3][r]=bv.w;
      float dtv = DTc[grow*8 + h];
      float4 xv = ld4(XC + grow*640 + h*64 + c4);
      vsh[r][c4+0]=xv.x*dtv; vsh[r][c4+1]=xv.y*dtv; vsh[r][c4+2]=xv.z*dtv; vsh[r][c4+3]=xv.w*dtv;
    }
    __syncthreads();
    float sc[4][2] = {{0.f}};
#pragma unroll
    for (int n=0;n<64;n++){
      float4 q4 = *(const float4*)&qT[n][ty*4];
      float k0v = kT[n][tx*2+0];
      float k1v = kT[n][tx*2+1];
      sc[0][0]+=q4.x*k0v; sc[0][1]+=q4.x*k1v;
      sc[1][0]+=q4.y*k0v; sc[1][1]+=q4.y*k1v;
      sc[2][0]+=q4.z*k0v; sc[2][1]+=q4.z*k1v;
      sc[3][0]+=q4.w*k0v; sc[3][1]+=q4.w*k1v;
    }
    float acss[2];
    acss[0] = acs[s0 + tx*2+0];
    acss[1] = acs[s0 + tx*2+1];
#pragma unroll
    for (int i=0;i<4;i++){
      int li = l0 + ty*4 + i;
#pragma unroll
      for (int j=0;j<2;j++){
        int sj = s0 + tx*2 + j;
        float w = (sj <= li) ? expf(acsl[i] - acss[j]) : 0.f;
        ssh[ty*4+i][tx*2+j] = sc[i][j]*w;
      }
    }
    __syncthreads();
#pragma unroll
    for (int s=0;s<32;s++){
      float s0v=ssh[ty*4+0][s], s1v=ssh[ty*4+1][s], s2v=ssh[ty*4+2][s], s3v=ssh[ty*4+3][s];
      float4 v4 = *(const float4*)&vsh[s][tx*4];
      acc[0][0]+=s0v*v4.x; acc[0][1]+=s0v*v4.y; acc[0][2]+=s0v*v4.z; acc[0][3]+=s0v*v4.w;
      acc[1][0]+=s1v*v4.x; acc[1][1]+=s1v*v4.y; acc[1][2]+=s1v*v4.z; acc[1][3]+=s1v*v4.w;
      acc[2][0]+=s2v*v4.x; acc[2][1]+=s2v*v4.y; acc[2][2]+=s2v*v4.z; acc[2][3]+=s2v*v4.w;
      acc[3][0]+=s3v*v4.x; acc[3][1]+=s3v*v4.y; acc[3][2]+=s3v*v4.z; acc[3][3]+=s3v*v4.w;
    }
    __syncthreads();
  }
  const u16* stin = STIN + ((size_t)((bl*16+c)*8+h))*4096;
#pragma unroll
  for (int it=0; it<4; it++){
    int idx = t + it*256;
    int r = idx>>4, c4 = (idx&15)<<2;
    float4 v = ld4(stin + r*64 + c4);
    sT[c4+0][r]=v.x; sT[c4+1][r]=v.y; sT[c4+2][r]=v.z; sT[c4+3][r]=v.w;
  }
  __syncthreads();
  float osc[4][4] = {{0.f}};
#pragma unroll
  for (int n=0;n<64;n++){
    float4 q4 = *(const float4*)&qT[n][ty*4];
    float4 p4 = *(const float4*)&sT[n][tx*4];
    osc[0][0]+=q4.x*p4.x; osc[0][1]+=q4.x*p4.y; osc[0][2]+=q4.x*p4.z; osc[0][3]+=q4.x*p4.w;
    osc[1][0]+=q4.y*p4.x; osc[1][1]+=q4.y*p4.y; osc[1][2]+=q4.y*p4.z; osc[1][3]+=q4.y*p4.w;
    osc[2][0]+=q4.z*p4.x; osc[2][1]+=q4.z*p4.y; osc[2][2]+=q4.z*p4.z; osc[2][3]+=q4.z*p4.w;
    osc[3][0]+=q4.w*p4.x; osc[3][1]+=q4.w*p4.y; osc[3][2]+=q4.w*p4.z; osc[3][3]+=q4.w*p4.w;
  }
  float dsk = dskip[h];
#pragma unroll
  for (int i=0;i<4;i++){
    float el = expf(acsl[i]);
    size_t grow = tok0 + l0 + ty*4 + i;
    float4 xs = ld4(XC + grow*640 + h*64 + tx*4);
    st4(Y + grow*512 + h*64 + tx*4,
        acc[i][0] + el*osc[i][0] + dsk*xs.x,
        acc[i][1] + el*osc[i][1] + dsk*xs.y,
        acc[i][2] + el*osc[i][2] + dsk*xs.z,
        acc[i][3] + el*osc[i][3] + dsk*xs.w);
  }
}

// ---------------- u = y*silu(z); RMSNorm*w over 512 (in place) -------------
__global__ __launch_bounds__(256) void urms_k(
    u16* Y, const u16* __restrict__ Z, const float* __restrict__ nw)
{
  int tok = blockIdx.x*4 + (threadIdx.x>>6);
  int lane = threadIdx.x & 63;
  size_t base = (size_t)tok*512 + lane*8;
  float y[8], z[8], u[8];
  ld8(Y+base, y); ld8(Z+base, z);
  float ss=0.f;
#pragma unroll
  for (int e=0;e<8;e++){ u[e] = y[e]*silu_(z[e]); ss += u[e]*u[e]; }
  ss = wsum_(ss);
  float r = rsqrtf(ss*(1.f/512.f) + 1e-5f);
  float4 w0 = *(const float4*)(nw + lane*8);
  float4 w1 = *(const float4*)(nw + lane*8 + 4);
  float o[8];
  o[0]=u[0]*r*w0.x; o[1]=u[1]*r*w0.y; o[2]=u[2]*r*w0.z; o[3]=u[3]*r*w0.w;
  o[4]=u[4]*r*w1.x; o[5]=u[5]*r*w1.y; o[6]=u[6]*r*w1.z; o[7]=u[7]*r*w1.w;
  st8(Y+base, o);
}

// ---------------- window attention per (window, head) ----------------------
__global__ __launch_bounds__(256) void attn_k(
    const u16* __restrict__ QKV, const float* __restrict__ rpb, u16* __restrict__ OW)
{
  int win = blockIdx.x;      // chunk-local window
  int wid = win & 63;        // geometry window
  int head = blockIdx.y;
  __shared__ float qs[64][36], ks[64][36], vs[64][36];
  __shared__ float ssm[64][65];
  __shared__ int rid[64];
  int t = threadIdx.x;
  const float scale = 0.17677669529663687f;  // 32^-0.5
#pragma unroll
  for (int it=0; it<2; it++){
    int idx = t + it*256;
    int r = idx>>3, c4 = (idx&7)<<2;
    const u16* base = QKV + ((size_t)win*64 + r)*768 + head*32 + c4;
    float4 q4 = ld4(base);
    float4 k4 = ld4(base + 256);
    float4 v4 = ld4(base + 512);
    qs[r][c4+0]=q4.x*scale; qs[r][c4+1]=q4.y*scale; qs[r][c4+2]=q4.z*scale; qs[r][c4+3]=q4.w*scale;
    *(float4*)&ks[r][c4] = k4;
    *(float4*)&vs[r][c4] = v4;
  }
  if (t < 64){
    int h2 = ((wid>>3)<<3) + (t>>3);
    int w2 = ((wid&7)<<3) + (t&7);
    int rh = (h2<56)?0:((h2<60)?1:2);
    int rw = (w2<56)?0:((w2<60)?1:2);
    rid[t] = rh*3 + rw;
  }
  __syncthreads();
  int i = t>>2, jb = t&3;
#pragma unroll
  for (int jj=0; jj<16; jj++){
    int j = jb*16 + jj;
    float s = 0.f;
#pragma unroll
    for (int d4=0; d4<8; d4++){
      float4 q4 = *(const float4*)&qs[i][d4*4];
      float4 k4 = *(const float4*)&ks[j][d4*4];
      s += q4.x*k4.x + q4.y*k4.y + q4.z*k4.z + q4.w*k4.w;
    }
    int di = (i>>3) - (j>>3);
    int dj = (i&7) - (j&7);
    s += rpb[((di+7)*15 + (dj+7))*8 + head];
    if (rid[i] != rid[j]) s -= 100.f;
    ssm[i][j] = s;
  }
  __syncthreads();
  if (t < 64){
    float mx = -1e30f;
#pragma unroll
    for (int j=0;j<64;j++) mx = fmaxf(mx, ssm[t][j]);
    float sum = 0.f;
#pragma unroll
    for (int j=0;j<64;j++){ float e = expf(ssm[t][j]-mx); ssm[t][j]=e; sum+=e; }
    float inv = 1.f/sum;
#pragma unroll
    for (int j=0;j<64;j++) ssm[t][j] *= inv;
  }
  __syncthreads();
  int d0 = (t&3)*8;
  float o[8] = {0.f,0.f,0.f,0.f,0.f,0.f,0.f,0.f};
#pragma unroll
  for (int j=0;j<64;j++){
    float pv = ssm[i][j];
    float4 va = *(const float4*)&vs[j][d0];
    float4 vb = *(const float4*)&vs[j][d0+4];
    o[0]+=pv*va.x; o[1]+=pv*va.y; o[2]+=pv*va.z; o[3]+=pv*va.w;
    o[4]+=pv*vb.x; o[5]+=pv*vb.y; o[6]+=pv*vb.z; o[7]+=pv*vb.w;
  }
  st8(OW + ((size_t)win*64 + i)*256 + head*32 + d0, o);
}

// ---------------- xm *= gm ; xa *= ga (bf16) -------------------------------
__global__ __launch_bounds__(256) void mul2_k(
    u16* XM, const u16* __restrict__ GM, u16* XA, const u16* __restrict__ GA)
{
  size_t i = ((size_t)blockIdx.x*256 + threadIdx.x)*4;
  float4 m = ld4(XM+i), g = ld4(GM+i);
  st4(XM+i, m.x*g.x, m.y*g.y, m.z*g.z, m.w*g.w);
  float4 a = ld4(XA+i), g2 = ld4(GA+i);
  st4(XA+i, a.x*g2.x, a.y*g2.y, a.z*g2.z, a.w*g2.w);
}

// ---------------- host ------------------------------------------------------
extern "C" void kernel_launch(void* const* d_in, const int* in_sizes, int n_in,
                              void* d_out, int out_size, void* d_ws, size_t ws_size,
                              hipStream_t stream)
{
  (void)in_sizes; (void)n_in; (void)out_size;
  const size_t OFF_XN   = 0;               // bf16 32768x256 (later XA)
  const size_t OFF_XNS  = 16777216;        // bf16 32768x256 (later XM)
  const size_t OFF_SP   = 33554432;        // bf16 32768x256 (later GM)
  const size_t OFF_DTRAW= 50331648;
  const size_t OFF_DT   = 51380224;
  const size_t OFF_AA   = 52428800;
  const size_t OFF_ACS  = 53477376;
  const size_t OFF_WTS  = 54525952;        // bf16 weights (3,211,264 B used)
  const size_t ARO      = 58195968;        // chunk arena: NB*14,680,064
  // pick NB = batches per chunk
  int NB = 0;
  if      (ws_size >= ARO + 8ull*14680064) NB = 8;
  else if (ws_size >= ARO + 4ull*14680064) NB = 4;
  else if (ws_size >= ARO + 2ull*14680064) NB = 2;
  else if (ws_size >= ARO + 1ull*14680064) NB = 1;
  else return;
  int NC = 8 / NB;
  int RJ = (NB==8)?32768 : (NB==4)?16384 : (NB==2)?8192 : 4096;  // MLP slab rows

  const float* x       = (const float*)d_in[0];
  const float* ln1_w   = (const float*)d_in[1];
  const float* ln1_b   = (const float*)d_in[2];
  const float* ns_w    = (const float*)d_in[3];
  const float* ns_b    = (const float*)d_in[4];
  const float* m_win   = (const float*)d_in[5];
  const float* m_conv_w= (const float*)d_in[6];
  const float* m_conv_b= (const float*)d_in[7];
  const float* m_dt_b  = (const float*)d_in[8];
  const float* m_a_log = (const float*)d_in[9];
  const float* m_d     = (const float*)d_in[10];
  const float* m_norm_w= (const float*)d_in[11];
  const float* m_wout  = (const float*)d_in[12];
  const float* tm_w1   = (const float*)d_in[13];
  const float* tm_b1   = (const float*)d_in[14];
  const float* tm_w2   = (const float*)d_in[15];
  const float* tm_b2   = (const float*)d_in[16];
  const float* nt_w    = (const float*)d_in[17];
  const float* nt_b    = (const float*)d_in[18];
  const float* qkv_w   = (const float*)d_in[19];
  const float* qkv_b   = (const float*)d_in[20];
  const float* rpb     = (const float*)d_in[21];
  const float* gate_w  = (const float*)d_in[22];
  const float* gate_b  = (const float*)d_in[23];
  const float* proj_w  = (const float*)d_in[24];
  const float* proj_b  = (const float*)d_in[25];
  const float* cg_w1a  = (const float*)d_in[26];
  const float* cg_b1a  = (const float*)d_in[27];
  const float* cg_w2a  = (const float*)d_in[28];
  const float* cg_b2a  = (const float*)d_in[29];
  const float* cg_w1m  = (const float*)d_in[30];
  const float* cg_b1m  = (const float*)d_in[31];
  const float* cg_w2m  = (const float*)d_in[32];
  const float* cg_b2m  = (const float*)d_in[33];
  const float* cg_wf   = (const float*)d_in[34];
  const float* cg_bf   = (const float*)d_in[35];
  const float* ln2_w   = (const float*)d_in[36];
  const float* ln2_b   = (const float*)d_in[37];
  const float* mlp_w1  = (const float*)d_in[38];
  const float* mlp_b1  = (const float*)d_in[39];
  const float* mlp_w2  = (const float*)d_in[40];
  const float* mlp_b2  = (const float*)d_in[41];
  float* dout = (float*)d_out;
  char* ws = (char*)d_ws;

  u16*  XN   = (u16*)(ws + OFF_XN);
  u16*  XNS  = (u16*)(ws + OFF_XNS);
  u16*  SP   = (u16*)(ws + OFF_SP);
  float* DTRAW = (float*)(ws + OFF_DTRAW);
  float* DT  = (float*)(ws + OFF_DT);
  float* AA  = (float*)(ws + OFF_AA);
  float* ACS = (float*)(ws + OFF_ACS);
  u16*  WTS  = (u16*)(ws + OFF_WTS);
  u16* WT_XBC = WTS + 0;        // 640x256
  u16* WT_Z   = WTS + 163840;   // 512x256
  u16* WT_WOUT= WTS + 294912;   // 256x512
  u16* WT_TM1 = WTS + 425984;   // 256x512
  u16* WT_TM2 = WTS + 491520;   // 256x256
  u16* WT_QKV = WTS + 557056;   // 768x256
  u16* WT_GATE= WTS + 753664;   // 256x256
  u16* WT_PROJ= WTS + 819200;   // 256x256
  u16* WT_W2A = WTS + 884736;   // 256x64
  u16* WT_W2M = WTS + 901120;   // 256x64
  u16* WT_WF  = WTS + 917504;   // 256x512
  u16* WT_MLP1= WTS + 1048576;  // 1024x256
  u16* WT_MLP2= WTS + 1310720;  // 256x1024
  u16* WT_W1A = WTS + 1572864;  // 64x256
  u16* WT_W1M = WTS + 1589248;  // 64x256
  char* AR = ws + ARO;
  // chunk arena
  u16*  XCc   = (u16*)AR;                                    // NB*5,242,880
  u16*  Zc    = (u16*)(AR + (size_t)NB*5242880);             // NB*4,194,304
  u16*  STINc = (u16*)(AR + (size_t)NB*9437184);             // NB*1,048,576
  float* STc  = (float*)(AR + (size_t)NB*10485760);          // NB*2,097,152
  u16*  Yc    = (u16*)(AR + (size_t)NB*10485760);            // NB*4,194,304 (over ST)
  u16*  QKVc  = (u16*)AR;                                    // H: NB*6,291,456
  u16*  OWc   = (u16*)(AR + (size_t)NB*6291456);             // H: NB*2,097,152
  u16*  TBUF  = (u16*)AR;                                    // G
  u16*  XM    = XNS;
  u16*  XA    = XN;
  u16*  CGH   = (u16*)AR;                                    // I
  u16*  GA    = (u16*)(AR + 4194304);
  u16*  GM    = SP;
  u16*  LNc   = (u16*)AR;                                    // J
  u16*  MHc   = (u16*)(AR + (size_t)RJ*512);

  const size_t TB = 4096*256;
  const size_t H2 = 16384*256;

  // Phase 0: weight convert+transpose (fp32 [K][N] -> bf16 [N][K])
  wt_k<<<dim3(8,20),256,0,stream>>>(m_win+512,1160,256, WT_XBC);
  wt_k<<<dim3(8,16),256,0,stream>>>(m_win,    1160,256, WT_Z);
  wt_k<<<dim3(16,8),256,0,stream>>>(m_wout,    256,512, WT_WOUT);
  wt_k<<<dim3(16,8),256,0,stream>>>(tm_w1,     256,512, WT_TM1);
  wt_k<<<dim3(8,8), 256,0,stream>>>(tm_w2,     256,256, WT_TM2);
  wt_k<<<dim3(8,24),256,0,stream>>>(qkv_w,     768,256, WT_QKV);
  wt_k<<<dim3(8,8), 256,0,stream>>>(gate_w,    256,256, WT_GATE);
  wt_k<<<dim3(8,8), 256,0,stream>>>(proj_w,    256,256, WT_PROJ);
  wt_k<<<dim3(2,8), 256,0,stream>>>(cg_w2a,    256,64,  WT_W2A);
  wt_k<<<dim3(2,8), 256,0,stream>>>(cg_w2m,    256,64,  WT_W2M);
  wt_k<<<dim3(16,8),256,0,stream>>>(cg_wf,     256,512, WT_WF);
  wt_k<<<dim3(8,32),256,0,stream>>>(mlp_w1,   1024,256, WT_MLP1);
  wt_k<<<dim3(32,8),256,0,stream>>>(mlp_w2,    256,1024,WT_MLP2);
  wt_k<<<dim3(8,2), 256,0,stream>>>(cg_w1a,     64,256, WT_W1A);
  wt_k<<<dim3(8,2), 256,0,stream>>>(cg_w1m,     64,256, WT_W1M);

  // Phase A: xn = LN(x); xns = LN(xn); dt path (full)
  ln2x_k<<<8192,256,0,stream>>>(x, ln1_w, ln1_b, ns_w, ns_b, XN, XNS);
  gemm_k<EPI_NONE,float,float><<<dim3(1,512),256,0,stream>>>(XNS,nullptr,256,0, m_win+1152,1160, nullptr, nullptr, DTRAW, 32768,8);
  dtk_k<<<1024,256,0,stream>>>(DTRAW, m_dt_b, m_a_log, DT, AA);
  acs_k<<<256,256,0,stream>>>(AA, ACS);

  // Phases B..F per chunk of NB batches
  for (int cc=0; cc<NC; cc++){
    int cb0 = cc*NB;
    const u16* XNSc = XNS + (size_t)cb0*TB;
    const float* DTcp = DT + (size_t)cb0*32768;
    const float* ACScp = ACS + (size_t)cb0*32768;
    xbcconv_k<<<dim3(5,NB*64),256,0,stream>>>(XNSc, WT_XBC, m_conv_w, m_conv_b, XCc);
    states_k<<<NB*128,256,0,stream>>>(XCc, DTcp, ACScp, STc);
    scan_k<<<NB*8,256,0,stream>>>(STc, ACScp, STINc);
    ydy_k<<<NB*512,256,0,stream>>>(XCc, DTcp, ACScp, STINc, m_d, Yc);
    mgemm_k<64,128,EPI_NONE,false,false,float,u16><<<dim3(4,NB*64),256,0,stream>>>(XNSc,nullptr,256,0, WT_Z, nullptr, nullptr, Zc, 512, 0);
    urms_k<<<NB*1024,256,0,stream>>>(Yc, Zc, m_norm_w);
    mgemm_k<64,128,EPI_ADD,false,false,u16,u16><<<dim3(2,NB*64),256,0,stream>>>(Yc,nullptr,512,0, WT_WOUT, nullptr, XN + (size_t)cb0*TB, SP + (size_t)cb0*TB, 256, 0);
  }

  // Phase G: tmix (sequential f0 then f1)
  mgemm_k<128,128,EPI_SILU,false,false,float,u16><<<dim3(2,128),256,0,stream>>>(SP, SP+H2, 256,256, WT_TM1, tm_b1, nullptr, TBUF, 256, 0);
  mgemm_k<128,128,EPI_ADD,false,false,u16,u16><<<dim3(2,128),256,0,stream>>>(TBUF,nullptr,256,0, WT_TM2, tm_b2, SP, XM, 256, 0);
  ln_k<u16><<<4096,256,0,stream>>>(XM, nt_w, nt_b, XM);
  mgemm_k<128,128,EPI_SILU,false,false,float,u16><<<dim3(2,128),256,0,stream>>>(SP+H2, XM, 256,256, WT_TM1, tm_b1, nullptr, TBUF, 256, 0);
  mgemm_k<128,128,EPI_ADD,false,false,u16,u16><<<dim3(2,128),256,0,stream>>>(TBUF,nullptr,256,0, WT_TM2, tm_b2, SP+H2, XM+H2, 256, 0);
  ln_k<u16><<<4096,256,0,stream>>>(XM+H2, nt_w, nt_b, XM+H2);

  // Phase H: window attention on xn, per chunk (gather in A-loads, scatter in proj store)
  for (int cc=0; cc<NC; cc++){
    int r0 = cc*NB*4096;
    mgemm_k<64,128,EPI_NONE,true,false,float,u16><<<dim3(6,NB*64),256,0,stream>>>(XN,nullptr,256,0, WT_QKV, qkv_b, nullptr, QKVc, 768, r0);
    attn_k<<<dim3(NB*64,8),256,0,stream>>>(QKVc, rpb, OWc);
    mgemm_k<64,128,EPI_SIGMUL,true,false,u16,u16><<<dim3(2,NB*64),256,0,stream>>>(XN,nullptr,256,0, WT_GATE, gate_b, OWc, OWc, 256, r0);
    mgemm_k<64,128,EPI_NONE,false,true,float,u16><<<dim3(2,NB*64),256,0,stream>>>(OWc,nullptr,256,0, WT_PROJ, proj_b, nullptr, XA, 256, r0);
  }

  // Phase I: cross gates; xo = x + cat(xm*gm, xa*ga)@cg_wf + cg_bf -> d_out
  mgemm_k<128,64,EPI_RELU,false,false,float,u16><<<dim3(1,256),256,0,stream>>>(XA,nullptr,256,0, WT_W1A, cg_b1a, nullptr, CGH, 64, 0);
  mgemm_k<128,128,EPI_SIGMOID,false,false,float,u16><<<dim3(2,256),256,0,stream>>>(CGH,nullptr,64,0, WT_W2A, cg_b2a, nullptr, GM, 256, 0);
  mgemm_k<128,64,EPI_RELU,false,false,float,u16><<<dim3(1,256),256,0,stream>>>(XM,nullptr,256,0, WT_W1M, cg_b1m, nullptr, CGH, 64, 0);
  mgemm_k<128,128,EPI_SIGMOID,false,false,float,u16><<<dim3(2,256),256,0,stream>>>(CGH,nullptr,64,0, WT_W2M, cg_b2m, nullptr, GA, 256, 0);
  mul2_k<<<8192,256,0,stream>>>(XM, GM, XA, GA);
  mgemm_k<128,128,EPI_ADD,false,false,float,float><<<dim3(2,256),256,0,stream>>>(XM, XA, 256,256, WT_WF, cg_bf, x, dout, 256, 0);

  // Phase J: MLP per RJ-row slab; out = xo + gelu(ln(xo)@w1+b1)@w2+b2
  for (int q=0; q<32768/RJ; q++){
    float* XOq = dout + (size_t)q*RJ*256;
    ln_k<float><<<RJ/4,256,0,stream>>>(XOq, ln2_w, ln2_b, LNc);
    mgemm_k<128,128,EPI_GELU,false,false,float,u16><<<dim3(8,RJ/128),256,0,stream>>>(LNc,nullptr,256,0, WT_MLP1, mlp_b1, nullptr, MHc, 1024, 0);
    mgemm_k<64,128,EPI_ADD,false,false,float,float><<<dim3(2,RJ/64),256,0,stream>>>(MHc,nullptr,1024,0, WT_MLP2, mlp_b2, XOq, XOq, 256, 0);
  }
}

// Round 5
// 814.199 us; speedup vs baseline: 4.1236x; 1.3799x over previous
//
#include <hip/hip_runtime.h>
#include <math.h>

// twoB=8, L=4096 (H=W=64), C=256, d_inner=512, nh_m=8, hd=64, D_STATE=64,
// conv_dim=640, zx width=1160, CHUNK=256 (16 chunks/batch), WS=8, SS=4, NH=8, Dh=32.

#define DEVI static __device__ __forceinline__
typedef unsigned short u16;
typedef unsigned int   u32;
typedef __attribute__((ext_vector_type(8))) short s16x8;
typedef __attribute__((ext_vector_type(4))) float f32x4;

DEVI float sigm_(float x){ return 1.f/(1.f+expf(-x)); }
DEVI float silu_(float x){ return x/(1.f+expf(-x)); }
DEVI float wsum_(float v){
#pragma unroll
  for (int o=32;o>0;o>>=1) v += __shfl_xor(v,o,64);
  return v;
}

DEVI float b2f(u16 u){ union{u32 i; float f;} v; v.i = ((u32)u)<<16; return v.f; }
DEVI u16 f2b(float f){ union{float f; u32 i;} v; v.f=f; u32 r = v.i + 0x7fffu + ((v.i>>16)&1u); return (u16)(r>>16); }
DEVI float4 ld4(const float* p){ return *(const float4*)p; }
DEVI float4 ld4(const u16* p){
  uint2 r = *(const uint2*)p;
  return make_float4(b2f((u16)(r.x&0xffff)), b2f((u16)(r.x>>16)),
                     b2f((u16)(r.y&0xffff)), b2f((u16)(r.y>>16)));
}
DEVI void st4(u16* p, float a, float b, float c, float d){
  uint2 r; r.x = (u32)f2b(a) | ((u32)f2b(b)<<16); r.y = (u32)f2b(c) | ((u32)f2b(d)<<16);
  *(uint2*)p = r;
}
DEVI void ld8(const u16* p, float* f){
  uint4 r = *(const uint4*)p;
  f[0]=b2f((u16)(r.x&0xffff)); f[1]=b2f((u16)(r.x>>16));
  f[2]=b2f((u16)(r.y&0xffff)); f[3]=b2f((u16)(r.y>>16));
  f[4]=b2f((u16)(r.z&0xffff)); f[5]=b2f((u16)(r.z>>16));
  f[6]=b2f((u16)(r.w&0xffff)); f[7]=b2f((u16)(r.w>>16));
}
DEVI void st8(u16* p, const float* f){
  uint4 r;
  r.x=(u32)f2b(f[0])|((u32)f2b(f[1])<<16); r.y=(u32)f2b(f[2])|((u32)f2b(f[3])<<16);
  r.z=(u32)f2b(f[4])|((u32)f2b(f[5])<<16); r.w=(u32)f2b(f[6])|((u32)f2b(f[7])<<16);
  *(uint4*)p = r;
}
DEVI float tof(float v){ return v; }
DEVI float tof(u16 v){ return b2f(v); }
DEVI void sto(float* p, float v){ *p = v; }
DEVI void sto(u16* p, float v){ *p = f2b(v); }

// window row -> token map (roll by -4, 8x8 windows over 64x64, per batch)
DEVI int winmap_tok(int r){
  int win = r>>6, tk = r&63;
  int b = win>>6, wid = win&63;
  int h2 = ((wid>>3)<<3) + (tk>>3);
  int w2 = ((wid&7)<<3) + (tk&7);
  int hh = (h2+4)&63, wwp = (w2+4)&63;
  return b*4096 + hh*64 + wwp;
}

// ---------------- fused LN(x)->xn, LN(xn)->xns (bf16 outs) -----------------
__global__ __launch_bounds__(256) void ln2x_k(
    const float* __restrict__ x, const float* __restrict__ w1, const float* __restrict__ b1,
    const float* __restrict__ w2, const float* __restrict__ b2,
    u16* __restrict__ xn, u16* __restrict__ xns)
{
  int tok = blockIdx.x*4 + (threadIdx.x>>6);
  int lane = threadIdx.x & 63;
  size_t base = (size_t)tok*256 + lane*4;
  float4 v = *(const float4*)(x + base);
  float mu = wsum_(v.x+v.y+v.z+v.w) * (1.f/256.f);
  float ax=v.x-mu, ay=v.y-mu, az=v.z-mu, aw=v.w-mu;
  float var = wsum_(ax*ax+ay*ay+az*az+aw*aw) * (1.f/256.f);
  float r = rsqrtf(var+1e-5f);
  float4 wv = *(const float4*)(w1+lane*4);
  float4 bv = *(const float4*)(b1+lane*4);
  float ox=ax*r*wv.x+bv.x, oy=ay*r*wv.y+bv.y, oz=az*r*wv.z+bv.z, ow=aw*r*wv.w+bv.w;
  st4(xn + base, ox, oy, oz, ow);
  float mu2 = wsum_(ox+oy+oz+ow)*(1.f/256.f);
  float bx=ox-mu2, by=oy-mu2, bz=oz-mu2, bw=ow-mu2;
  float var2 = wsum_(bx*bx+by*by+bz*bz+bw*bw)*(1.f/256.f);
  float r2 = rsqrtf(var2+1e-5f);
  float4 w2v = *(const float4*)(w2+lane*4);
  float4 b2v = *(const float4*)(b2+lane*4);
  st4(xns + base, bx*r2*w2v.x+b2v.x, by*r2*w2v.y+b2v.y, bz*r2*w2v.z+b2v.z, bw*r2*w2v.w+b2v.w);
}

// ---------------- generic LayerNorm (C=256), bf16 out ----------------------
template<typename IT>
__global__ __launch_bounds__(256) void ln_k(
    const IT* __restrict__ in, const float* __restrict__ w, const float* __restrict__ b,
    u16* __restrict__ outp)
{
  int tok = blockIdx.x*4 + (threadIdx.x>>6);
  int lane = threadIdx.x & 63;
  size_t base = (size_t)tok*256 + lane*4;
  float4 v = ld4(in + base);
  float mu = wsum_(v.x+v.y+v.z+v.w) * (1.f/256.f);
  float ax=v.x-mu, ay=v.y-mu, az=v.z-mu, aw=v.w-mu;
  float var = wsum_(ax*ax+ay*ay+az*az+aw*aw) * (1.f/256.f);
  float r = rsqrtf(var+1e-5f);
  float4 wv = *(const float4*)(w+lane*4);
  float4 bv = *(const float4*)(b+lane*4);
  st4(outp + base, ax*r*wv.x+bv.x, ay*r*wv.y+bv.y, az*r*wv.z+bv.z, aw*r*wv.w+bv.w);
}

// ---------------- weight fp32[K][N](ldw) -> bf16 Wt[N][K] ------------------
__global__ __launch_bounds__(256) void wt_k(
    const float* __restrict__ W, int ldw, int K, u16* __restrict__ Wt)
{
  __shared__ float tl[32][33];
  int k0 = blockIdx.x*32, n0 = blockIdx.y*32;
  int t = threadIdx.x; int ty=t>>5, tx=t&31;
#pragma unroll
  for (int i=0;i<4;i++){
    int k = ty + i*8;
    tl[k][tx] = W[(size_t)(k0+k)*ldw + n0+tx];
  }
  __syncthreads();
#pragma unroll
  for (int i=0;i<4;i++){
    int n = ty + i*8;
    Wt[(size_t)(n0+n)*K + k0 + tx] = f2b(tl[tx][n]);
  }
}

enum { EPI_NONE=0, EPI_SILU=1, EPI_GELU=2, EPI_SIGMUL=3, EPI_ADD=4, EPI_RELU=5, EPI_SIGMOID=6 };

// -------- MFMA GEMM: out[M,N] = epi(cat(A1,A2)[M,K] @ Wt[N,K]^T + bias) ----
// BK=32, 4 waves (2x2). WIN: gather A rows via winmap. WINST: scatter out rows.
template<int BM, int BN, int EPI, bool WIN, bool WINST, typename OT, typename CT>
__global__ __launch_bounds__(256) void mgemm_k(
    const u16* __restrict__ A1, const u16* __restrict__ A2, int K1, int K2,
    const u16* __restrict__ Wt, const float* __restrict__ bias,
    const OT* other, CT* outp, int N, int r0)
{
  constexpr int MW = BM/32;
  constexpr int NWF = BN/32;
  constexpr int LA = BM/64;
  constexpr int LB = BN/64;
  __shared__ u16 As[BM][40];
  __shared__ u16 Bs[BN][40];
  int m0 = blockIdx.y*BM, n0 = blockIdx.x*BN;
  int t = threadIdx.x;
  int lane = t&63, w = t>>6;
  int wr = w>>1, wc = w&1;
  int K = K1 + K2;
  f32x4 acc[MW][NWF];
#pragma unroll
  for (int mi=0;mi<MW;mi++)
#pragma unroll
    for (int ni=0;ni<NWF;ni++) acc[mi][ni] = (f32x4){0.f,0.f,0.f,0.f};
  int lrow = t>>2, lc8 = (t&3)*8;
  size_t aoff1[LA], aoff2[LA];
#pragma unroll
  for (int i=0;i<LA;i++){
    int gr = m0 + lrow + i*64;
    if (WIN) aoff1[i] = (size_t)winmap_tok(r0+gr)*K1;
    else { aoff1[i] = (size_t)gr*K1; aoff2[i] = (size_t)gr*K2; }
  }
  for (int k0=0; k0<K; k0+=32){
    int gk = k0 + lc8;
#pragma unroll
    for (int i=0;i<LA;i++){
      const u16* ap = (WIN || gk < K1) ? A1 + aoff1[i] + gk : A2 + aoff2[i] + (gk-K1);
      *(uint4*)&As[lrow + i*64][lc8] = *(const uint4*)ap;
    }
#pragma unroll
    for (int i=0;i<LB;i++){
      int row = lrow + i*64;
      *(uint4*)&Bs[row][lc8] = *(const uint4*)(Wt + (size_t)(n0+row)*K + gk);
    }
    __syncthreads();
    int lg = lane>>4, li = lane&15;
    s16x8 afr[MW], bfr[NWF];
#pragma unroll
    for (int mi=0;mi<MW;mi++)
      afr[mi] = *(const s16x8*)&As[wr*(BM/2)+mi*16+li][lg*8];
#pragma unroll
    for (int ni=0;ni<NWF;ni++)
      bfr[ni] = *(const s16x8*)&Bs[wc*(BN/2)+ni*16+li][lg*8];
#pragma unroll
    for (int mi=0;mi<MW;mi++)
#pragma unroll
      for (int ni=0;ni<NWF;ni++)
        acc[mi][ni] = __builtin_amdgcn_mfma_f32_16x16x32_bf16(afr[mi], bfr[ni], acc[mi][ni], 0,0,0);
    __syncthreads();
  }
  int lg = lane>>4, li = lane&15;
#pragma unroll
  for (int mi=0;mi<MW;mi++){
#pragma unroll
    for (int ni=0;ni<NWF;ni++){
      int gn = n0 + wc*(BN/2) + ni*16 + li;
      float bv = bias ? bias[gn] : 0.f;
#pragma unroll
      for (int r=0;r<4;r++){
        int gm = m0 + wr*(BM/2) + mi*16 + lg*4 + r;
        float v = acc[mi][ni][r] + bv;
        size_t orow = WINST ? (size_t)winmap_tok(r0+gm) : (size_t)gm;
        size_t off = orow*N + gn;
        if (EPI==EPI_SILU)        v = silu_(v);
        else if (EPI==EPI_GELU)   v = 0.5f*v*(1.f+erff(v*0.70710678118654752f));
        else if (EPI==EPI_SIGMUL) v = tof(other[off])*sigm_(v);
        else if (EPI==EPI_ADD)    v = v + tof(other[off]);
        else if (EPI==EPI_RELU)   v = fmaxf(v,0.f);
        else if (EPI==EPI_SIGMOID)v = sigm_(v);
        sto(outp + off, v);
      }
    }
  }
}

// -------- fp32 fallback GEMM (tiny N): out = epi(A[M,K]@W[K,N]+bias) -------
template<int EPI, typename OT, typename CT>
__global__ __launch_bounds__(256) void gemm_k(
    const u16* __restrict__ A1, const u16* __restrict__ A2, int K1, int K2,
    const float* __restrict__ W, int ldw, const float* __restrict__ bias,
    const OT* other, CT* outp, int M, int N)
{
  __shared__ float as[16][68];
  __shared__ float bs[16][64];
  int m0 = blockIdx.y*64, n0 = blockIdx.x*64;
  int t = threadIdx.x;
  int ty = t>>4, tx = t&15;
  float acc[4][4] = {{0.f}};
  int K = K1 + K2;
  int arow = t>>2, ac4 = (t&3)<<2;
  int bkr = t>>4, bnc = (t&15)<<2;
  for (int k0=0; k0<K; k0+=16){
    int gk = k0 + ac4;
    float4 av;
    if (gk < K1) av = ld4(A1 + (size_t)(m0+arow)*K1 + gk);
    else         av = ld4(A2 + (size_t)(m0+arow)*K2 + (gk-K1));
    as[ac4+0][arow]=av.x; as[ac4+1][arow]=av.y; as[ac4+2][arow]=av.z; as[ac4+3][arow]=av.w;
    int gn = n0 + bnc;
    const float* wp = W + (size_t)(k0+bkr)*ldw;
    if (gn+3 < N) {
      *(float4*)&bs[bkr][bnc] = *(const float4*)(wp + gn);
    } else {
#pragma unroll
      for (int j=0;j<4;j++) bs[bkr][bnc+j] = (gn+j<N) ? wp[gn+j] : 0.f;
    }
    __syncthreads();
#pragma unroll
    for (int kk=0; kk<16; kk++){
      float4 a4 = *(const float4*)&as[kk][ty*4];
      float4 b4 = *(const float4*)&bs[kk][tx*4];
      acc[0][0]+=a4.x*b4.x; acc[0][1]+=a4.x*b4.y; acc[0][2]+=a4.x*b4.z; acc[0][3]+=a4.x*b4.w;
      acc[1][0]+=a4.y*b4.x; acc[1][1]+=a4.y*b4.y; acc[1][2]+=a4.y*b4.z; acc[1][3]+=a4.y*b4.w;
      acc[2][0]+=a4.z*b4.x; acc[2][1]+=a4.z*b4.y; acc[2][2]+=a4.z*b4.z; acc[2][3]+=a4.z*b4.w;
      acc[3][0]+=a4.w*b4.x; acc[3][1]+=a4.w*b4.y; acc[3][2]+=a4.w*b4.z; acc[3][3]+=a4.w*b4.w;
    }
    __syncthreads();
  }
#pragma unroll
  for (int i=0;i<4;i++){
    int gm = m0 + ty*4 + i;
#pragma unroll
    for (int j=0;j<4;j++){
      int gn = n0 + tx*4 + j;
      if (gn >= N) continue;
      float v = acc[i][j] + (bias ? bias[gn] : 0.f);
      size_t off = (size_t)gm*N + gn;
      if (EPI==EPI_SILU)        v = silu_(v);
      else if (EPI==EPI_GELU)   v = 0.5f*v*(1.f+erff(v*0.70710678118654752f));
      else if (EPI==EPI_SIGMUL) v = tof(other[off])*sigm_(v);
      else if (EPI==EPI_ADD)    v = v + tof(other[off]);
      else if (EPI==EPI_RELU)   v = fmaxf(v,0.f);
      else if (EPI==EPI_SIGMOID)v = sigm_(v);
      sto(outp + off, v);
    }
  }
}

// ---- fused xBC GEMM (M=64 tile) + causal conv(4) + SiLU -> XC -------------
__global__ __launch_bounds__(256) void xbcconv_k(
    const u16* __restrict__ A1, const u16* __restrict__ Wt,
    const float* __restrict__ cw, const float* __restrict__ cb,
    u16* __restrict__ XC)
{
  __shared__ u16 As[64][40];
  __shared__ u16 Ab[3][40];
  __shared__ u16 Bs[128][40];
  __shared__ float Cls[67][132];
  int m0 = blockIdx.y*64, n0 = blockIdx.x*128;
  bool first = ((m0 & 4095) == 0);
  int t = threadIdx.x;
  int lane = t&63, w = t>>6;
  int wr = w>>1, wc = w&1;
  f32x4 acc[2][4];
#pragma unroll
  for (int mi=0;mi<2;mi++)
#pragma unroll
    for (int ni=0;ni<4;ni++) acc[mi][ni] = (f32x4){0.f,0.f,0.f,0.f};
  float acc2[2] = {0.f,0.f};
  int lrow = t>>2, lc8 = (t&3)*8;
  int brow = t/64, bcol = (t%64)*2;
  for (int k0=0; k0<256; k0+=32){
    int gk = k0 + lc8;
    *(uint4*)&As[lrow][lc8] = *(const uint4*)(A1 + (size_t)(m0+lrow)*256 + gk);
    if (t < 12 && !first){
      int r3 = t>>2, seg = t&3;
      *(uint4*)&Ab[r3][seg*8] = *(const uint4*)(A1 + (size_t)(m0-3+r3)*256 + k0 + seg*8);
    }
#pragma unroll
    for (int i=0;i<2;i++){
      int row = lrow + i*64;
      *(uint4*)&Bs[row][lc8] = *(const uint4*)(Wt + (size_t)(n0+row)*256 + gk);
    }
    __syncthreads();
    int lg = lane>>4, li = lane&15;
    s16x8 afr[2], bfr[4];
#pragma unroll
    for (int mi=0;mi<2;mi++)
      afr[mi] = *(const s16x8*)&As[wr*32+mi*16+li][lg*8];
#pragma unroll
    for (int ni=0;ni<4;ni++)
      bfr[ni] = *(const s16x8*)&Bs[wc*64+ni*16+li][lg*8];
#pragma unroll
    for (int mi=0;mi<2;mi++)
#pragma unroll
      for (int ni=0;ni<4;ni++)
        acc[mi][ni] = __builtin_amdgcn_mfma_f32_16x16x32_bf16(afr[mi], bfr[ni], acc[mi][ni], 0,0,0);
    if (t < 192 && !first){
#pragma unroll
      for (int kk=0;kk<32;kk++){
        float a = b2f(Ab[brow][kk]);
        acc2[0] += a * b2f(Bs[bcol][kk]);
        acc2[1] += a * b2f(Bs[bcol+1][kk]);
      }
    }
    __syncthreads();
  }
  {
    int lg = lane>>4, li = lane&15;
#pragma unroll
    for (int mi=0;mi<2;mi++)
#pragma unroll
      for (int ni=0;ni<4;ni++){
        int col = wc*64 + ni*16 + li;
#pragma unroll
        for (int r=0;r<4;r++){
          int rl = wr*32 + mi*16 + lg*4 + r;
          Cls[3+rl][col] = acc[mi][ni][r];
        }
      }
    if (t < 192){
      Cls[brow][bcol]   = first ? 0.f : acc2[0];
      Cls[brow][bcol+1] = first ? 0.f : acc2[1];
    }
  }
  __syncthreads();
  int col = t & 127, half = t >> 7;
  int ch = n0 + col;
  float w0 = cw[ch*4+0], w1 = cw[ch*4+1], w2 = cw[ch*4+2], w3 = cw[ch*4+3];
  float bias = cb[ch];
  int r0 = half*32;
  float c0 = Cls[r0+0][col], c1 = Cls[r0+1][col], c2 = Cls[r0+2][col];
#pragma unroll
  for (int rr=0; rr<32; rr++){
    float c3 = Cls[r0+rr+3][col];
    float v = bias + w0*c0 + w1*c1 + w2*c2 + w3*c3;
    XC[(size_t)(m0 + r0 + rr)*640 + ch] = f2b(silu_(v));
    c0=c1; c1=c2; c2=c3;
  }
}

// ---------------- dt: softplus(dtraw+bias); a = -dt*exp(a_log) -------------
__global__ __launch_bounds__(256) void dtk_k(
    const float* __restrict__ DTRAW, const float* __restrict__ dtb, const float* __restrict__ alog,
    float* __restrict__ DT_, float* __restrict__ AA_)
{
  int gid = blockIdx.x*256 + threadIdx.x;
  int h = gid & 7;
  float xv = DTRAW[gid] + dtb[h];
  float sp = (xv > 20.f) ? xv : log1pf(expf(xv));
  DT_[gid] = sp;
  AA_[gid] = -sp * expf(alog[h]);
}

// ---------------- per-chunk inclusive cumsum of a (full) -------------------
__global__ __launch_bounds__(256) void acs_k(const float* __restrict__ AA_, float* __restrict__ ACS_)
{
  int wid = (blockIdx.x<<2) + (threadIdx.x>>6);
  int lane = threadIdx.x & 63;
  int c  = wid & 15;
  int bh = wid >> 4;
  int b  = bh >> 3, h = bh & 7;
  size_t tok0 = (size_t)b*4096 + c*256 + lane*4;
  float v0 = AA_[(tok0+0)*8 + h];
  float v1 = AA_[(tok0+1)*8 + h];
  float v2 = AA_[(tok0+2)*8 + h];
  float v3 = AA_[(tok0+3)*8 + h];
  v1 += v0; v2 += v1; v3 += v2;
  float tot = v3, s = tot;
#pragma unroll
  for (int o=1;o<64;o<<=1){
    float u = __shfl_up(s, o, 64);
    if (lane >= o) s += u;
  }
  float excl = s - tot;
  float* dst = ACS_ + (size_t)bh*4096 + c*256 + lane*4;
  dst[0]=excl+v0; dst[1]=excl+v1; dst[2]=excl+v2; dst[3]=excl+v3;
}

// ------- chunk end-states via MFMA: ST[((bl*16+c)*8+h)][p][n] --------------
// out[p][n] = sum_s Xdt[s][p] * Bw[s][n]; both operands transposed per s-block.
__global__ __launch_bounds__(256) void states_k(
    const u16* __restrict__ XC, const float* __restrict__ DTc, const float* __restrict__ ACSc,
    float* __restrict__ ST)
{
  int bid = blockIdx.x;                  // bl*128 + c*8 + h
  int h = bid & 7, c = (bid>>3)&15, bl = bid>>7;
  __shared__ u16 Xt[64][72];
  __shared__ u16 Bt[64][72];
  int t = threadIdx.x;
  int lane = t&63, w = t>>6;
  int wr = w>>1, wc = w&1;
  int lg = lane>>4, li = lane&15;
  const float* acs = ACSc + ((size_t)(bl*8+h))*4096 + c*256;
  float aL = acs[255];
  size_t tok0 = (size_t)bl*4096 + c*256;
  f32x4 acc[2][2];
#pragma unroll
  for (int mi=0;mi<2;mi++)
#pragma unroll
    for (int ni=0;ni<2;ni++) acc[mi][ni] = (f32x4){0.f,0.f,0.f,0.f};
  int sr = t>>2, cg = t&3;   // staging: row s = sr, 16 channels at cg*16
  for (int s0=0; s0<256; s0+=64){
    __syncthreads();
    size_t grow = tok0 + s0 + sr;
    float dtv = DTc[grow*8 + h];
    float wdec = expf(aL - acs[s0+sr]);
    const u16* xrow = XC + grow*640 + h*64 + cg*16;
    const u16* brow = XC + grow*640 + 512 + cg*16;
    uint4 xa = *(const uint4*)xrow, xb = *(const uint4*)(xrow+8);
    uint4 ba = *(const uint4*)brow, bb = *(const uint4*)(brow+8);
    const u16* xu = (const u16*)&xa;
    const u16* bu = (const u16*)&ba;
#pragma unroll
    for (int j=0;j<8;j++){
      Xt[cg*16+j][sr]   = f2b(b2f(xu[j])*dtv);
      Bt[cg*16+j][sr]   = f2b(b2f(bu[j])*wdec);
    }
    const u16* xu2 = (const u16*)&xb;
    const u16* bu2 = (const u16*)&bb;
#pragma unroll
    for (int j=0;j<8;j++){
      Xt[cg*16+8+j][sr] = f2b(b2f(xu2[j])*dtv);
      Bt[cg*16+8+j][sr] = f2b(b2f(bu2[j])*wdec);
    }
    __syncthreads();
    s16x8 afr[2][2], bfr[2][2];
#pragma unroll
    for (int kk=0;kk<2;kk++){
#pragma unroll
      for (int mi=0;mi<2;mi++)
        afr[mi][kk] = *(const s16x8*)&Xt[wr*32+mi*16+li][kk*32+lg*8];
#pragma unroll
      for (int ni=0;ni<2;ni++)
        bfr[ni][kk] = *(const s16x8*)&Bt[wc*32+ni*16+li][kk*32+lg*8];
    }
#pragma unroll
    for (int kk=0;kk<2;kk++)
#pragma unroll
      for (int mi=0;mi<2;mi++)
#pragma unroll
        for (int ni=0;ni<2;ni++)
          acc[mi][ni] = __builtin_amdgcn_mfma_f32_16x16x32_bf16(afr[mi][kk], bfr[ni][kk], acc[mi][ni], 0,0,0);
  }
  float* dst = ST + (size_t)bid*4096;
#pragma unroll
  for (int mi=0;mi<2;mi++)
#pragma unroll
    for (int ni=0;ni<2;ni++){
      int gn = wc*32 + ni*16 + li;
#pragma unroll
      for (int r=0;r<4;r++){
        int gp = wr*32 + mi*16 + lg*4 + r;
        dst[gp*64 + gn] = acc[mi][ni][r];
      }
    }
}

// ---------------- sequential inter-chunk scan; STIN out bf16 ---------------
__global__ __launch_bounds__(256) void scan_k(
    const float* __restrict__ ST, const float* __restrict__ ACSc, u16* __restrict__ STIN)
{
  int bl = blockIdx.x>>3, h = blockIdx.x&7;
  int t = threadIdx.x;
  float hr[16];
#pragma unroll
  for (int e=0;e<16;e++) hr[e]=0.f;
  for (int c=0;c<16;c++){
    float dec = expf(ACSc[((size_t)(bl*8+h))*4096 + c*256 + 255]);
    size_t base = ((size_t)((bl*16+c)*8+h))*4096;
#pragma unroll
    for (int e=0;e<16;e++){
      size_t idx = base + e*256 + t;
      float st = ST[idx];
      STIN[idx] = f2b(hr[e]);
      hr[e] = hr[e]*dec + st;
    }
  }
}

// ------------ Y = Yd + Yo + d_skip*xs via MFMA (flash-style) ---------------
// Per block: (bl,c,h,lt): 64 l-rows. S = C·B^T (mask+decay), Y += S·V; Yo = C·stin^T.
__global__ __launch_bounds__(256) void ydy_k(
    const u16* __restrict__ XC, const float* __restrict__ DTc,
    const float* __restrict__ ACSc, const u16* __restrict__ STIN,
    const float* __restrict__ dskip, u16* __restrict__ Y)
{
  int bid = blockIdx.x;                      // bl*512 + (c*8+h)*4 + lt
  int lt = bid & 3, h = (bid>>2)&7, c = (bid>>5)&15, bl = bid>>9;
  int l0 = lt*64;
  __shared__ u16 Ct[64][72];
  __shared__ u16 Sb[64][72];   // B-tile; later xs tile
  __shared__ u16 Vt[64][72];   // V^T (p,s)
  __shared__ u16 Sl[64][72];   // bf16 scores; later output staging
  int t = threadIdx.x;
  int lane = t&63, w = t>>6;
  int wr = w>>1, wc = w&1;
  int lg = lane>>4, li = lane&15;
  const float* acs = ACSc + ((size_t)(bl*8+h))*4096 + c*256;
  size_t tok0 = (size_t)bl*4096 + c*256;
  int sr = t>>2;               // staging row
  // stage C tile rows l0..l0+63 (cols 576..640)
#pragma unroll
  for (int it=0; it<2; it++){
    int seg = (t&3) + it*4;
    *(uint4*)&Ct[sr][seg*8] = *(const uint4*)(XC + (tok0+l0+sr)*640 + 576 + seg*8);
  }
  // preload acs for this thread's output rows
  float acsl[2][4];
#pragma unroll
  for (int mi=0;mi<2;mi++)
#pragma unroll
    for (int r=0;r<4;r++)
      acsl[mi][r] = acs[l0 + wr*32 + mi*16 + lg*4 + r];
  f32x4 accP[2][2], accO[2][2];
#pragma unroll
  for (int mi=0;mi<2;mi++)
#pragma unroll
    for (int ni=0;ni<2;ni++){ accP[mi][ni]=(f32x4){0,0,0,0}; accO[mi][ni]=(f32x4){0,0,0,0}; }
  __syncthreads();
  // Yo: A from Ct (k=n), B directly from STIN global ([p][n] = B-operand layout)
  const u16* stin = STIN + ((size_t)((bl*16+c)*8+h))*4096;
#pragma unroll
  for (int kk=0;kk<2;kk++){
    s16x8 bfr[2];
#pragma unroll
    for (int ni=0;ni<2;ni++){
      int p = wc*32 + ni*16 + li;
      bfr[ni] = *(const s16x8*)(stin + p*64 + kk*32 + lg*8);
    }
#pragma unroll
    for (int mi=0;mi<2;mi++){
      s16x8 afr = *(const s16x8*)&Ct[wr*32+mi*16+li][kk*32+lg*8];
#pragma unroll
      for (int ni=0;ni<2;ni++)
        accO[mi][ni] = __builtin_amdgcn_mfma_f32_16x16x32_bf16(afr, bfr[ni], accO[mi][ni], 0,0,0);
    }
  }
  // s-block loop
  for (int sb=0; sb<=lt; sb++){
    int s0 = sb*64;
    __syncthreads();   // prior PV / Yo reads done before restaging
    // stage Sb (B rows) coalesced
#pragma unroll
    for (int it=0; it<2; it++){
      int seg = (t&3) + it*4;
      *(uint4*)&Sb[sr][seg*8] = *(const uint4*)(XC + (tok0+s0+sr)*640 + 512 + seg*8);
    }
    // stage Vt transposed with dt scaling
    {
      int cg = t&3;
      size_t grow = tok0 + s0 + sr;
      float dtv = DTc[grow*8 + h];
      const u16* xrow = XC + grow*640 + h*64 + cg*16;
      uint4 xa = *(const uint4*)xrow, xb = *(const uint4*)(xrow+8);
      const u16* xu = (const u16*)&xa;
#pragma unroll
      for (int j=0;j<8;j++) Vt[cg*16+j][sr] = f2b(b2f(xu[j])*dtv);
      const u16* xu2 = (const u16*)&xb;
#pragma unroll
      for (int j=0;j<8;j++) Vt[cg*16+8+j][sr] = f2b(b2f(xu2[j])*dtv);
    }
    __syncthreads();
    // S = C·B^T for this s-block (wave quadrant: rows wr, cols wc)
    f32x4 sacc[2][2];
#pragma unroll
    for (int mi=0;mi<2;mi++)
#pragma unroll
      for (int ni=0;ni<2;ni++) sacc[mi][ni]=(f32x4){0,0,0,0};
#pragma unroll
    for (int kk=0;kk<2;kk++){
      s16x8 bfr[2];
#pragma unroll
      for (int ni=0;ni<2;ni++)
        bfr[ni] = *(const s16x8*)&Sb[wc*32+ni*16+li][kk*32+lg*8];
#pragma unroll
      for (int mi=0;mi<2;mi++){
        s16x8 afr = *(const s16x8*)&Ct[wr*32+mi*16+li][kk*32+lg*8];
#pragma unroll
        for (int ni=0;ni<2;ni++)
          sacc[mi][ni] = __builtin_amdgcn_mfma_f32_16x16x32_bf16(afr, bfr[ni], sacc[mi][ni], 0,0,0);
      }
    }
    // scale by exp(acs_l - acs_s), mask s<=l, write bf16 to Sl
#pragma unroll
    for (int ni=0;ni<2;ni++){
      int cs = wc*32 + ni*16 + li;
      int gsj = s0 + cs;
      float acss = acs[gsj];
#pragma unroll
      for (int mi=0;mi<2;mi++){
#pragma unroll
        for (int r=0;r<4;r++){
          int lrow = wr*32 + mi*16 + lg*4 + r;
          int gl = l0 + lrow;
          float wgt = (gsj <= gl) ? expf(acsl[mi][r] - acss) : 0.f;
          Sl[lrow][cs] = f2b(sacc[mi][ni][r] * wgt);
        }
      }
    }
    __syncthreads();
    // PV: accP += Sl · V  (A rows l from Sl, B cols p from Vt)
#pragma unroll
    for (int kk=0;kk<2;kk++){
      s16x8 bfr[2];
#pragma unroll
      for (int ni=0;ni<2;ni++)
        bfr[ni] = *(const s16x8*)&Vt[wc*32+ni*16+li][kk*32+lg*8];
#pragma unroll
      for (int mi=0;mi<2;mi++){
        s16x8 afr = *(const s16x8*)&Sl[wr*32+mi*16+li][kk*32+lg*8];
#pragma unroll
        for (int ni=0;ni<2;ni++)
          accP[mi][ni] = __builtin_amdgcn_mfma_f32_16x16x32_bf16(afr, bfr[ni], accP[mi][ni], 0,0,0);
      }
    }
  }
  __syncthreads();
  // stage xs tile (rows l, head slice) into Sb
#pragma unroll
  for (int it=0; it<2; it++){
    int seg = (t&3) + it*4;
    *(uint4*)&Sb[sr][seg*8] = *(const uint4*)(XC + (tok0+l0+sr)*640 + h*64 + seg*8);
  }
  __syncthreads();
  float dsk = dskip[h];
#pragma unroll
  for (int mi=0;mi<2;mi++){
#pragma unroll
    for (int ni=0;ni<2;ni++){
      int p = wc*32 + ni*16 + li;
#pragma unroll
      for (int r=0;r<4;r++){
        int lrow = wr*32 + mi*16 + lg*4 + r;
        float el = expf(acsl[mi][r]);
        float xsv = b2f(Sb[lrow][p]);
        Sl[lrow][p] = f2b(accP[mi][ni][r] + el*accO[mi][ni][r] + dsk*xsv);
      }
    }
  }
  __syncthreads();
  // coalesced store
#pragma unroll
  for (int it=0; it<2; it++){
    int seg = (t&3) + it*4;
    *(uint4*)(Y + (tok0+l0+sr)*512 + h*64 + seg*8) = *(const uint4*)&Sl[sr][seg*8];
  }
}

// ---------------- u = y*silu(z); RMSNorm*w over 512 (in place) -------------
__global__ __launch_bounds__(256) void urms_k(
    u16* Y, const u16* __restrict__ Z, const float* __restrict__ nw)
{
  int tok = blockIdx.x*4 + (threadIdx.x>>6);
  int lane = threadIdx.x & 63;
  size_t base = (size_t)tok*512 + lane*8;
  float y[8], z[8], u[8];
  ld8(Y+base, y); ld8(Z+base, z);
  float ss=0.f;
#pragma unroll
  for (int e=0;e<8;e++){ u[e] = y[e]*silu_(z[e]); ss += u[e]*u[e]; }
  ss = wsum_(ss);
  float r = rsqrtf(ss*(1.f/512.f) + 1e-5f);
  float4 w0 = *(const float4*)(nw + lane*8);
  float4 w1 = *(const float4*)(nw + lane*8 + 4);
  float o[8];
  o[0]=u[0]*r*w0.x; o[1]=u[1]*r*w0.y; o[2]=u[2]*r*w0.z; o[3]=u[3]*r*w0.w;
  o[4]=u[4]*r*w1.x; o[5]=u[5]*r*w1.y; o[6]=u[6]*r*w1.z; o[7]=u[7]*r*w1.w;
  st8(Y+base, o);
}

// ---------------- window attention per (window, head) ----------------------
__global__ __launch_bounds__(256) void attn_k(
    const u16* __restrict__ QKV, const float* __restrict__ rpb, u16* __restrict__ OW)
{
  int win = blockIdx.x;
  int wid = win & 63;
  int head = blockIdx.y;
  __shared__ float qs[64][36], ks[64][36], vs[64][36];
  __shared__ float ssm[64][65];
  __shared__ int rid[64];
  int t = threadIdx.x;
  const float scale = 0.17677669529663687f;
#pragma unroll
  for (int it=0; it<2; it++){
    int idx = t + it*256;
    int r = idx>>3, c4 = (idx&7)<<2;
    const u16* base = QKV + ((size_t)win*64 + r)*768 + head*32 + c4;
    float4 q4 = ld4(base);
    float4 k4 = ld4(base + 256);
    float4 v4 = ld4(base + 512);
    qs[r][c4+0]=q4.x*scale; qs[r][c4+1]=q4.y*scale; qs[r][c4+2]=q4.z*scale; qs[r][c4+3]=q4.w*scale;
    *(float4*)&ks[r][c4] = k4;
    *(float4*)&vs[r][c4] = v4;
  }
  if (t < 64){
    int h2 = ((wid>>3)<<3) + (t>>3);
    int w2 = ((wid&7)<<3) + (t&7);
    int rh = (h2<56)?0:((h2<60)?1:2);
    int rw = (w2<56)?0:((w2<60)?1:2);
    rid[t] = rh*3 + rw;
  }
  __syncthreads();
  int i = t>>2, jb = t&3;
#pragma unroll
  for (int jj=0; jj<16; jj++){
    int j = jb*16 + jj;
    float s = 0.f;
#pragma unroll
    for (int d4=0; d4<8; d4++){
      float4 q4 = *(const float4*)&qs[i][d4*4];
      float4 k4 = *(const float4*)&ks[j][d4*4];
      s += q4.x*k4.x + q4.y*k4.y + q4.z*k4.z + q4.w*k4.w;
    }
    int di = (i>>3) - (j>>3);
    int dj = (i&7) - (j&7);
    s += rpb[((di+7)*15 + (dj+7))*8 + head];
    if (rid[i] != rid[j]) s -= 100.f;
    ssm[i][j] = s;
  }
  __syncthreads();
  if (t < 64){
    float mx = -1e30f;
#pragma unroll
    for (int j=0;j<64;j++) mx = fmaxf(mx, ssm[t][j]);
    float sum = 0.f;
#pragma unroll
    for (int j=0;j<64;j++){ float e = expf(ssm[t][j]-mx); ssm[t][j]=e; sum+=e; }
    float inv = 1.f/sum;
#pragma unroll
    for (int j=0;j<64;j++) ssm[t][j] *= inv;
  }
  __syncthreads();
  int d0 = (t&3)*8;
  float o[8] = {0.f,0.f,0.f,0.f,0.f,0.f,0.f,0.f};
#pragma unroll
  for (int j=0;j<64;j++){
    float pv = ssm[i][j];
    float4 va = *(const float4*)&vs[j][d0];
    float4 vb = *(const float4*)&vs[j][d0+4];
    o[0]+=pv*va.x; o[1]+=pv*va.y; o[2]+=pv*va.z; o[3]+=pv*va.w;
    o[4]+=pv*vb.x; o[5]+=pv*vb.y; o[6]+=pv*vb.z; o[7]+=pv*vb.w;
  }
  st8(OW + ((size_t)win*64 + i)*256 + head*32 + d0, o);
}

// ---------------- xm *= gm ; xa *= ga (bf16) -------------------------------
__global__ __launch_bounds__(256) void mul2_k(
    u16* XM, const u16* __restrict__ GM, u16* XA, const u16* __restrict__ GA)
{
  size_t i = ((size_t)blockIdx.x*256 + threadIdx.x)*4;
  float4 m = ld4(XM+i), g = ld4(GM+i);
  st4(XM+i, m.x*g.x, m.y*g.y, m.z*g.z, m.w*g.w);
  float4 a = ld4(XA+i), g2 = ld4(GA+i);
  st4(XA+i, a.x*g2.x, a.y*g2.y, a.z*g2.z, a.w*g2.w);
}

// ---------------- host ------------------------------------------------------
extern "C" void kernel_launch(void* const* d_in, const int* in_sizes, int n_in,
                              void* d_out, int out_size, void* d_ws, size_t ws_size,
                              hipStream_t stream)
{
  (void)in_sizes; (void)n_in; (void)out_size;
  const size_t OFF_XN   = 0;
  const size_t OFF_XNS  = 16777216;
  const size_t OFF_SP   = 33554432;
  const size_t OFF_DTRAW= 50331648;
  const size_t OFF_DT   = 51380224;
  const size_t OFF_AA   = 52428800;
  const size_t OFF_ACS  = 53477376;
  const size_t OFF_WTS  = 54525952;
  const size_t ARO      = 58195968;
  int NB = 0;
  if      (ws_size >= ARO + 8ull*14680064) NB = 8;
  else if (ws_size >= ARO + 4ull*14680064) NB = 4;
  else if (ws_size >= ARO + 2ull*14680064) NB = 2;
  else if (ws_size >= ARO + 1ull*14680064) NB = 1;
  else return;
  int NC = 8 / NB;
  int RJ = (NB==8)?32768 : (NB==4)?16384 : (NB==2)?8192 : 4096;

  const float* x       = (const float*)d_in[0];
  const float* ln1_w   = (const float*)d_in[1];
  const float* ln1_b   = (const float*)d_in[2];
  const float* ns_w    = (const float*)d_in[3];
  const float* ns_b    = (const float*)d_in[4];
  const float* m_win   = (const float*)d_in[5];
  const float* m_conv_w= (const float*)d_in[6];
  const float* m_conv_b= (const float*)d_in[7];
  const float* m_dt_b  = (const float*)d_in[8];
  const float* m_a_log = (const float*)d_in[9];
  const float* m_d     = (const float*)d_in[10];
  const float* m_norm_w= (const float*)d_in[11];
  const float* m_wout  = (const float*)d_in[12];
  const float* tm_w1   = (const float*)d_in[13];
  const float* tm_b1   = (const float*)d_in[14];
  const float* tm_w2   = (const float*)d_in[15];
  const float* tm_b2   = (const float*)d_in[16];
  const float* nt_w    = (const float*)d_in[17];
  const float* nt_b    = (const float*)d_in[18];
  const float* qkv_w   = (const float*)d_in[19];
  const float* qkv_b   = (const float*)d_in[20];
  const float* rpb     = (const float*)d_in[21];
  const float* gate_w  = (const float*)d_in[22];
  const float* gate_b  = (const float*)d_in[23];
  const float* proj_w  = (const float*)d_in[24];
  const float* proj_b  = (const float*)d_in[25];
  const float* cg_w1a  = (const float*)d_in[26];
  const float* cg_b1a  = (const float*)d_in[27];
  const float* cg_w2a  = (const float*)d_in[28];
  const float* cg_b2a  = (const float*)d_in[29];
  const float* cg_w1m  = (const float*)d_in[30];
  const float* cg_b1m  = (const float*)d_in[31];
  const float* cg_w2m  = (const float*)d_in[32];
  const float* cg_b2m  = (const float*)d_in[33];
  const float* cg_wf   = (const float*)d_in[34];
  const float* cg_bf   = (const float*)d_in[35];
  const float* ln2_w   = (const float*)d_in[36];
  const float* ln2_b   = (const float*)d_in[37];
  const float* mlp_w1  = (const float*)d_in[38];
  const float* mlp_b1  = (const float*)d_in[39];
  const float* mlp_w2  = (const float*)d_in[40];
  const float* mlp_b2  = (const float*)d_in[41];
  float* dout = (float*)d_out;
  char* ws = (char*)d_ws;

  u16*  XN   = (u16*)(ws + OFF_XN);
  u16*  XNS  = (u16*)(ws + OFF_XNS);
  u16*  SP   = (u16*)(ws + OFF_SP);
  float* DTRAW = (float*)(ws + OFF_DTRAW);
  float* DT  = (float*)(ws + OFF_DT);
  float* AA  = (float*)(ws + OFF_AA);
  float* ACS = (float*)(ws + OFF_ACS);
  u16*  WTS  = (u16*)(ws + OFF_WTS);
  u16* WT_XBC = WTS + 0;
  u16* WT_Z   = WTS + 163840;
  u16* WT_WOUT= WTS + 294912;
  u16* WT_TM1 = WTS + 425984;
  u16* WT_TM2 = WTS + 491520;
  u16* WT_QKV = WTS + 557056;
  u16* WT_GATE= WTS + 753664;
  u16* WT_PROJ= WTS + 819200;
  u16* WT_W2A = WTS + 884736;
  u16* WT_W2M = WTS + 901120;
  u16* WT_WF  = WTS + 917504;
  u16* WT_MLP1= WTS + 1048576;
  u16* WT_MLP2= WTS + 1310720;
  u16* WT_W1A = WTS + 1572864;
  u16* WT_W1M = WTS + 1589248;
  char* AR = ws + ARO;
  u16*  XCc   = (u16*)AR;
  u16*  Zc    = (u16*)(AR + (size_t)NB*5242880);
  u16*  STINc = (u16*)(AR + (size_t)NB*9437184);
  float* STc  = (float*)(AR + (size_t)NB*10485760);
  u16*  Yc    = (u16*)(AR + (size_t)NB*10485760);
  u16*  QKVc  = (u16*)AR;
  u16*  OWc   = (u16*)(AR + (size_t)NB*6291456);
  u16*  TBUF  = (u16*)AR;
  u16*  XM    = XNS;
  u16*  XA    = XN;
  u16*  CGH   = (u16*)AR;
  u16*  GA    = (u16*)(AR + 4194304);
  u16*  GM    = SP;
  u16*  LNc   = (u16*)AR;
  u16*  MHc   = (u16*)(AR + (size_t)RJ*512);

  const size_t TB = 4096*256;
  const size_t H2 = 16384*256;

  // Phase 0: weight convert+transpose
  wt_k<<<dim3(8,20),256,0,stream>>>(m_win+512,1160,256, WT_XBC);
  wt_k<<<dim3(8,16),256,0,stream>>>(m_win,    1160,256, WT_Z);
  wt_k<<<dim3(16,8),256,0,stream>>>(m_wout,    256,512, WT_WOUT);
  wt_k<<<dim3(16,8),256,0,stream>>>(tm_w1,     256,512, WT_TM1);
  wt_k<<<dim3(8,8), 256,0,stream>>>(tm_w2,     256,256, WT_TM2);
  wt_k<<<dim3(8,24),256,0,stream>>>(qkv_w,     768,256, WT_QKV);
  wt_k<<<dim3(8,8), 256,0,stream>>>(gate_w,    256,256, WT_GATE);
  wt_k<<<dim3(8,8), 256,0,stream>>>(proj_w,    256,256, WT_PROJ);
  wt_k<<<dim3(2,8), 256,0,stream>>>(cg_w2a,    256,64,  WT_W2A);
  wt_k<<<dim3(2,8), 256,0,stream>>>(cg_w2m,    256,64,  WT_W2M);
  wt_k<<<dim3(16,8),256,0,stream>>>(cg_wf,     256,512, WT_WF);
  wt_k<<<dim3(8,32),256,0,stream>>>(mlp_w1,   1024,256, WT_MLP1);
  wt_k<<<dim3(32,8),256,0,stream>>>(mlp_w2,    256,1024,WT_MLP2);
  wt_k<<<dim3(8,2), 256,0,stream>>>(cg_w1a,     64,256, WT_W1A);
  wt_k<<<dim3(8,2), 256,0,stream>>>(cg_w1m,     64,256, WT_W1M);

  // Phase A
  ln2x_k<<<8192,256,0,stream>>>(x, ln1_w, ln1_b, ns_w, ns_b, XN, XNS);
  gemm_k<EPI_NONE,float,float><<<dim3(1,512),256,0,stream>>>(XNS,nullptr,256,0, m_win+1152,1160, nullptr, nullptr, DTRAW, 32768,8);
  dtk_k<<<1024,256,0,stream>>>(DTRAW, m_dt_b, m_a_log, DT, AA);
  acs_k<<<256,256,0,stream>>>(AA, ACS);

  // Phases B..F per chunk of NB batches
  for (int cc=0; cc<NC; cc++){
    int cb0 = cc*NB;
    const u16* XNSc = XNS + (size_t)cb0*TB;
    const float* DTcp = DT + (size_t)cb0*32768;
    const float* ACScp = ACS + (size_t)cb0*32768;
    xbcconv_k<<<dim3(5,NB*64),256,0,stream>>>(XNSc, WT_XBC, m_conv_w, m_conv_b, XCc);
    states_k<<<NB*128,256,0,stream>>>(XCc, DTcp, ACScp, STc);
    scan_k<<<NB*8,256,0,stream>>>(STc, ACScp, STINc);
    ydy_k<<<NB*512,256,0,stream>>>(XCc, DTcp, ACScp, STINc, m_d, Yc);
    mgemm_k<64,128,EPI_NONE,false,false,float,u16><<<dim3(4,NB*64),256,0,stream>>>(XNSc,nullptr,256,0, WT_Z, nullptr, nullptr, Zc, 512, 0);
    urms_k<<<NB*1024,256,0,stream>>>(Yc, Zc, m_norm_w);
    mgemm_k<64,128,EPI_ADD,false,false,u16,u16><<<dim3(2,NB*64),256,0,stream>>>(Yc,nullptr,512,0, WT_WOUT, nullptr, XN + (size_t)cb0*TB, SP + (size_t)cb0*TB, 256, 0);
  }

  // Phase G: tmix
  mgemm_k<128,128,EPI_SILU,false,false,float,u16><<<dim3(2,128),256,0,stream>>>(SP, SP+H2, 256,256, WT_TM1, tm_b1, nullptr, TBUF, 256, 0);
  mgemm_k<128,128,EPI_ADD,false,false,u16,u16><<<dim3(2,128),256,0,stream>>>(TBUF,nullptr,256,0, WT_TM2, tm_b2, SP, XM, 256, 0);
  ln_k<u16><<<4096,256,0,stream>>>(XM, nt_w, nt_b, XM);
  mgemm_k<128,128,EPI_SILU,false,false,float,u16><<<dim3(2,128),256,0,stream>>>(SP+H2, XM, 256,256, WT_TM1, tm_b1, nullptr, TBUF, 256, 0);
  mgemm_k<128,128,EPI_ADD,false,false,u16,u16><<<dim3(2,128),256,0,stream>>>(TBUF,nullptr,256,0, WT_TM2, tm_b2, SP+H2, XM+H2, 256, 0);
  ln_k<u16><<<4096,256,0,stream>>>(XM+H2, nt_w, nt_b, XM+H2);

  // Phase H: window attention
  for (int cc=0; cc<NC; cc++){
    int r0 = cc*NB*4096;
    mgemm_k<64,128,EPI_NONE,true,false,float,u16><<<dim3(6,NB*64),256,0,stream>>>(XN,nullptr,256,0, WT_QKV, qkv_b, nullptr, QKVc, 768, r0);
    attn_k<<<dim3(NB*64,8),256,0,stream>>>(QKVc, rpb, OWc);
    mgemm_k<64,128,EPI_SIGMUL,true,false,u16,u16><<<dim3(2,NB*64),256,0,stream>>>(XN,nullptr,256,0, WT_GATE, gate_b, OWc, OWc, 256, r0);
    mgemm_k<64,128,EPI_NONE,false,true,float,u16><<<dim3(2,NB*64),256,0,stream>>>(OWc,nullptr,256,0, WT_PROJ, proj_b, nullptr, XA, 256, r0);
  }

  // Phase I: cross gates
  mgemm_k<128,64,EPI_RELU,false,false,float,u16><<<dim3(1,256),256,0,stream>>>(XA,nullptr,256,0, WT_W1A, cg_b1a, nullptr, CGH, 64, 0);
  mgemm_k<128,128,EPI_SIGMOID,false,false,float,u16><<<dim3(2,256),256,0,stream>>>(CGH,nullptr,64,0, WT_W2A, cg_b2a, nullptr, GM, 256, 0);
  mgemm_k<128,64,EPI_RELU,false,false,float,u16><<<dim3(1,256),256,0,stream>>>(XM,nullptr,256,0, WT_W1M, cg_b1m, nullptr, CGH, 64, 0);
  mgemm_k<128,128,EPI_SIGMOID,false,false,float,u16><<<dim3(2,256),256,0,stream>>>(CGH,nullptr,64,0, WT_W2M, cg_b2m, nullptr, GA, 256, 0);
  mul2_k<<<8192,256,0,stream>>>(XM, GM, XA, GA);
  mgemm_k<128,128,EPI_ADD,false,false,float,float><<<dim3(2,256),256,0,stream>>>(XM, XA, 256,256, WT_WF, cg_bf, x, dout, 256, 0);

  // Phase J: MLP
  for (int q=0; q<32768/RJ; q++){
    float* XOq = dout + (size_t)q*RJ*256;
    ln_k<float><<<RJ/4,256,0,stream>>>(XOq, ln2_w, ln2_b, LNc);
    mgemm_k<128,128,EPI_GELU,false,false,float,u16><<<dim3(8,RJ/128),256,0,stream>>>(LNc,nullptr,256,0, WT_MLP1, mlp_b1, nullptr, MHc, 1024, 0);
    mgemm_k<64,128,EPI_ADD,false,false,float,float><<<dim3(2,RJ/64),256,0,stream>>>(MHc,nullptr,1024,0, WT_MLP2, mlp_b2, XOq, XOq, 256, 0);
  }
}

// Round 6
// 707.910 us; speedup vs baseline: 4.7428x; 1.1501x over previous
//
#include <hip/hip_runtime.h>
#include <math.h>

// twoB=8, L=4096 (H=W=64), C=256, d_inner=512, nh_m=8, hd=64, D_STATE=64,
// conv_dim=640, zx width=1160, CHUNK=256 (16 chunks/batch), WS=8, SS=4, NH=8, Dh=32.

#define DEVI static __device__ __forceinline__
typedef unsigned short u16;
typedef unsigned int   u32;
typedef __attribute__((ext_vector_type(8))) short s16x8;
typedef __attribute__((ext_vector_type(4))) float f32x4;

DEVI float sigm_(float x){ return 1.f/(1.f+expf(-x)); }
DEVI float silu_(float x){ return x/(1.f+expf(-x)); }
DEVI float wsum_(float v){
#pragma unroll
  for (int o=32;o>0;o>>=1) v += __shfl_xor(v,o,64);
  return v;
}

DEVI float b2f(u16 u){ union{u32 i; float f;} v; v.i = ((u32)u)<<16; return v.f; }
DEVI u16 f2b(float f){ union{float f; u32 i;} v; v.f=f; u32 r = v.i + 0x7fffu + ((v.i>>16)&1u); return (u16)(r>>16); }
DEVI float4 ld4(const float* p){ return *(const float4*)p; }
DEVI float4 ld4(const u16* p){
  uint2 r = *(const uint2*)p;
  return make_float4(b2f((u16)(r.x&0xffff)), b2f((u16)(r.x>>16)),
                     b2f((u16)(r.y&0xffff)), b2f((u16)(r.y>>16)));
}
DEVI void st4(u16* p, float a, float b, float c, float d){
  uint2 r; r.x = (u32)f2b(a) | ((u32)f2b(b)<<16); r.y = (u32)f2b(c) | ((u32)f2b(d)<<16);
  *(uint2*)p = r;
}
DEVI void ld8(const u16* p, float* f){
  uint4 r = *(const uint4*)p;
  f[0]=b2f((u16)(r.x&0xffff)); f[1]=b2f((u16)(r.x>>16));
  f[2]=b2f((u16)(r.y&0xffff)); f[3]=b2f((u16)(r.y>>16));
  f[4]=b2f((u16)(r.z&0xffff)); f[5]=b2f((u16)(r.z>>16));
  f[6]=b2f((u16)(r.w&0xffff)); f[7]=b2f((u16)(r.w>>16));
}
DEVI void st8(u16* p, const float* f){
  uint4 r;
  r.x=(u32)f2b(f[0])|((u32)f2b(f[1])<<16); r.y=(u32)f2b(f[2])|((u32)f2b(f[3])<<16);
  r.z=(u32)f2b(f[4])|((u32)f2b(f[5])<<16); r.w=(u32)f2b(f[6])|((u32)f2b(f[7])<<16);
  *(uint4*)p = r;
}
DEVI float tof(float v){ return v; }
DEVI float tof(u16 v){ return b2f(v); }
DEVI void sto(float* p, float v){ *p = v; }
DEVI void sto(u16* p, float v){ *p = f2b(v); }

// window row -> token map (roll by -4, 8x8 windows over 64x64, per batch)
DEVI int winmap_tok(int r){
  int win = r>>6, tk = r&63;
  int b = win>>6, wid = win&63;
  int h2 = ((wid>>3)<<3) + (tk>>3);
  int w2 = ((wid&7)<<3) + (tk&7);
  int hh = (h2+4)&63, wwp = (w2+4)&63;
  return b*4096 + hh*64 + wwp;
}

// ---------------- fused LN(x)->xn, LN(xn)->xns (bf16 outs) -----------------
__global__ __launch_bounds__(256) void ln2x_k(
    const float* __restrict__ x, const float* __restrict__ w1, const float* __restrict__ b1,
    const float* __restrict__ w2, const float* __restrict__ b2,
    u16* __restrict__ xn, u16* __restrict__ xns)
{
  int tok = blockIdx.x*4 + (threadIdx.x>>6);
  int lane = threadIdx.x & 63;
  size_t base = (size_t)tok*256 + lane*4;
  float4 v = *(const float4*)(x + base);
  float mu = wsum_(v.x+v.y+v.z+v.w) * (1.f/256.f);
  float ax=v.x-mu, ay=v.y-mu, az=v.z-mu, aw=v.w-mu;
  float var = wsum_(ax*ax+ay*ay+az*az+aw*aw) * (1.f/256.f);
  float r = rsqrtf(var+1e-5f);
  float4 wv = *(const float4*)(w1+lane*4);
  float4 bv = *(const float4*)(b1+lane*4);
  float ox=ax*r*wv.x+bv.x, oy=ay*r*wv.y+bv.y, oz=az*r*wv.z+bv.z, ow=aw*r*wv.w+bv.w;
  st4(xn + base, ox, oy, oz, ow);
  float mu2 = wsum_(ox+oy+oz+ow)*(1.f/256.f);
  float bx=ox-mu2, by=oy-mu2, bz=oz-mu2, bw=ow-mu2;
  float var2 = wsum_(bx*bx+by*by+bz*bz+bw*bw)*(1.f/256.f);
  float r2 = rsqrtf(var2+1e-5f);
  float4 w2v = *(const float4*)(w2+lane*4);
  float4 b2v = *(const float4*)(b2+lane*4);
  st4(xns + base, bx*r2*w2v.x+b2v.x, by*r2*w2v.y+b2v.y, bz*r2*w2v.z+b2v.z, bw*r2*w2v.w+b2v.w);
}

// ---------------- generic LayerNorm (C=256), bf16 out ----------------------
template<typename IT>
__global__ __launch_bounds__(256) void ln_k(
    const IT* __restrict__ in, const float* __restrict__ w, const float* __restrict__ b,
    u16* __restrict__ outp)
{
  int tok = blockIdx.x*4 + (threadIdx.x>>6);
  int lane = threadIdx.x & 63;
  size_t base = (size_t)tok*256 + lane*4;
  float4 v = ld4(in + base);
  float mu = wsum_(v.x+v.y+v.z+v.w) * (1.f/256.f);
  float ax=v.x-mu, ay=v.y-mu, az=v.z-mu, aw=v.w-mu;
  float var = wsum_(ax*ax+ay*ay+az*az+aw*aw) * (1.f/256.f);
  float r = rsqrtf(var+1e-5f);
  float4 wv = *(const float4*)(w+lane*4);
  float4 bv = *(const float4*)(b+lane*4);
  st4(outp + base, ax*r*wv.x+bv.x, ay*r*wv.y+bv.y, az*r*wv.z+bv.z, aw*r*wv.w+bv.w);
}

// ---------------- weight fp32[K][N](ldw) -> bf16 Wt[N][K] ------------------
__global__ __launch_bounds__(256) void wt_k(
    const float* __restrict__ W, int ldw, int K, u16* __restrict__ Wt)
{
  __shared__ float tl[32][33];
  int k0 = blockIdx.x*32, n0 = blockIdx.y*32;
  int t = threadIdx.x; int ty=t>>5, tx=t&31;
#pragma unroll
  for (int i=0;i<4;i++){
    int k = ty + i*8;
    tl[k][tx] = W[(size_t)(k0+k)*ldw + n0+tx];
  }
  __syncthreads();
#pragma unroll
  for (int i=0;i<4;i++){
    int n = ty + i*8;
    Wt[(size_t)(n0+n)*K + k0 + tx] = f2b(tl[tx][n]);
  }
}

enum { EPI_NONE=0, EPI_SILU=1, EPI_GELU=2, EPI_SIGMUL=3, EPI_ADD=4, EPI_RELU=5, EPI_SIGMOID=6 };

// -------- MFMA GEMM: out[M,N] = epi(cat(A1,A2)[M,K] @ Wt[N,K]^T + bias) ----
// BK=32, 4 waves (2x2). WIN: gather A rows via winmap. WINST: scatter out rows.
template<int BM, int BN, int EPI, bool WIN, bool WINST, typename OT, typename CT>
__global__ __launch_bounds__(256) void mgemm_k(
    const u16* __restrict__ A1, const u16* __restrict__ A2, int K1, int K2,
    const u16* __restrict__ Wt, const float* __restrict__ bias,
    const OT* other, CT* outp, int N, int r0)
{
  constexpr int MW = BM/32;
  constexpr int NWF = BN/32;
  constexpr int LA = BM/64;
  constexpr int LB = BN/64;
  __shared__ u16 As[BM][40];
  __shared__ u16 Bs[BN][40];
  int m0 = blockIdx.y*BM, n0 = blockIdx.x*BN;
  int t = threadIdx.x;
  int lane = t&63, w = t>>6;
  int wr = w>>1, wc = w&1;
  int K = K1 + K2;
  f32x4 acc[MW][NWF];
#pragma unroll
  for (int mi=0;mi<MW;mi++)
#pragma unroll
    for (int ni=0;ni<NWF;ni++) acc[mi][ni] = (f32x4){0.f,0.f,0.f,0.f};
  int lrow = t>>2, lc8 = (t&3)*8;
  size_t aoff1[LA], aoff2[LA];
#pragma unroll
  for (int i=0;i<LA;i++){
    int gr = m0 + lrow + i*64;
    if (WIN) aoff1[i] = (size_t)winmap_tok(r0+gr)*K1;
    else { aoff1[i] = (size_t)gr*K1; aoff2[i] = (size_t)gr*K2; }
  }
  for (int k0=0; k0<K; k0+=32){
    int gk = k0 + lc8;
#pragma unroll
    for (int i=0;i<LA;i++){
      const u16* ap = (WIN || gk < K1) ? A1 + aoff1[i] + gk : A2 + aoff2[i] + (gk-K1);
      *(uint4*)&As[lrow + i*64][lc8] = *(const uint4*)ap;
    }
#pragma unroll
    for (int i=0;i<LB;i++){
      int row = lrow + i*64;
      *(uint4*)&Bs[row][lc8] = *(const uint4*)(Wt + (size_t)(n0+row)*K + gk);
    }
    __syncthreads();
    int lg = lane>>4, li = lane&15;
    s16x8 afr[MW], bfr[NWF];
#pragma unroll
    for (int mi=0;mi<MW;mi++)
      afr[mi] = *(const s16x8*)&As[wr*(BM/2)+mi*16+li][lg*8];
#pragma unroll
    for (int ni=0;ni<NWF;ni++)
      bfr[ni] = *(const s16x8*)&Bs[wc*(BN/2)+ni*16+li][lg*8];
#pragma unroll
    for (int mi=0;mi<MW;mi++)
#pragma unroll
      for (int ni=0;ni<NWF;ni++)
        acc[mi][ni] = __builtin_amdgcn_mfma_f32_16x16x32_bf16(afr[mi], bfr[ni], acc[mi][ni], 0,0,0);
    __syncthreads();
  }
  int lg = lane>>4, li = lane&15;
#pragma unroll
  for (int mi=0;mi<MW;mi++){
#pragma unroll
    for (int ni=0;ni<NWF;ni++){
      int gn = n0 + wc*(BN/2) + ni*16 + li;
      float bv = bias ? bias[gn] : 0.f;
#pragma unroll
      for (int r=0;r<4;r++){
        int gm = m0 + wr*(BM/2) + mi*16 + lg*4 + r;
        float v = acc[mi][ni][r] + bv;
        size_t orow = WINST ? (size_t)winmap_tok(r0+gm) : (size_t)gm;
        size_t off = orow*N + gn;
        if (EPI==EPI_SILU)        v = silu_(v);
        else if (EPI==EPI_GELU)   v = 0.5f*v*(1.f+erff(v*0.70710678118654752f));
        else if (EPI==EPI_SIGMUL) v = tof(other[off])*sigm_(v);
        else if (EPI==EPI_ADD)    v = v + tof(other[off]);
        else if (EPI==EPI_RELU)   v = fmaxf(v,0.f);
        else if (EPI==EPI_SIGMOID)v = sigm_(v);
        sto(outp + off, v);
      }
    }
  }
}

// -------- fp32 fallback GEMM (tiny N): out = epi(A[M,K]@W[K,N]+bias) -------
template<int EPI, typename OT, typename CT>
__global__ __launch_bounds__(256) void gemm_k(
    const u16* __restrict__ A1, const u16* __restrict__ A2, int K1, int K2,
    const float* __restrict__ W, int ldw, const float* __restrict__ bias,
    const OT* other, CT* outp, int M, int N)
{
  __shared__ float as[16][68];
  __shared__ float bs[16][64];
  int m0 = blockIdx.y*64, n0 = blockIdx.x*64;
  int t = threadIdx.x;
  int ty = t>>4, tx = t&15;
  float acc[4][4] = {{0.f}};
  int K = K1 + K2;
  int arow = t>>2, ac4 = (t&3)<<2;
  int bkr = t>>4, bnc = (t&15)<<2;
  for (int k0=0; k0<K; k0+=16){
    int gk = k0 + ac4;
    float4 av;
    if (gk < K1) av = ld4(A1 + (size_t)(m0+arow)*K1 + gk);
    else         av = ld4(A2 + (size_t)(m0+arow)*K2 + (gk-K1));
    as[ac4+0][arow]=av.x; as[ac4+1][arow]=av.y; as[ac4+2][arow]=av.z; as[ac4+3][arow]=av.w;
    int gn = n0 + bnc;
    const float* wp = W + (size_t)(k0+bkr)*ldw;
    if (gn+3 < N) {
      *(float4*)&bs[bkr][bnc] = *(const float4*)(wp + gn);
    } else {
#pragma unroll
      for (int j=0;j<4;j++) bs[bkr][bnc+j] = (gn+j<N) ? wp[gn+j] : 0.f;
    }
    __syncthreads();
#pragma unroll
    for (int kk=0; kk<16; kk++){
      float4 a4 = *(const float4*)&as[kk][ty*4];
      float4 b4 = *(const float4*)&bs[kk][tx*4];
      acc[0][0]+=a4.x*b4.x; acc[0][1]+=a4.x*b4.y; acc[0][2]+=a4.x*b4.z; acc[0][3]+=a4.x*b4.w;
      acc[1][0]+=a4.y*b4.x; acc[1][1]+=a4.y*b4.y; acc[1][2]+=a4.y*b4.z; acc[1][3]+=a4.y*b4.w;
      acc[2][0]+=a4.z*b4.x; acc[2][1]+=a4.z*b4.y; acc[2][2]+=a4.z*b4.z; acc[2][3]+=a4.z*b4.w;
      acc[3][0]+=a4.w*b4.x; acc[3][1]+=a4.w*b4.y; acc[3][2]+=a4.w*b4.z; acc[3][3]+=a4.w*b4.w;
    }
    __syncthreads();
  }
#pragma unroll
  for (int i=0;i<4;i++){
    int gm = m0 + ty*4 + i;
#pragma unroll
    for (int j=0;j<4;j++){
      int gn = n0 + tx*4 + j;
      if (gn >= N) continue;
      float v = acc[i][j] + (bias ? bias[gn] : 0.f);
      size_t off = (size_t)gm*N + gn;
      if (EPI==EPI_SILU)        v = silu_(v);
      else if (EPI==EPI_GELU)   v = 0.5f*v*(1.f+erff(v*0.70710678118654752f));
      else if (EPI==EPI_SIGMUL) v = tof(other[off])*sigm_(v);
      else if (EPI==EPI_ADD)    v = v + tof(other[off]);
      else if (EPI==EPI_RELU)   v = fmaxf(v,0.f);
      else if (EPI==EPI_SIGMOID)v = sigm_(v);
      sto(outp + off, v);
    }
  }
}

// ---- fused xBC GEMM (M=64 tile) + causal conv(4) + SiLU -> XC -------------
__global__ __launch_bounds__(256) void xbcconv_k(
    const u16* __restrict__ A1, const u16* __restrict__ Wt,
    const float* __restrict__ cw, const float* __restrict__ cb,
    u16* __restrict__ XC)
{
  __shared__ u16 As[64][40];
  __shared__ u16 Ab[3][40];
  __shared__ u16 Bs[128][40];
  __shared__ float Cls[67][132];
  int m0 = blockIdx.y*64, n0 = blockIdx.x*128;
  bool first = ((m0 & 4095) == 0);
  int t = threadIdx.x;
  int lane = t&63, w = t>>6;
  int wr = w>>1, wc = w&1;
  f32x4 acc[2][4];
#pragma unroll
  for (int mi=0;mi<2;mi++)
#pragma unroll
    for (int ni=0;ni<4;ni++) acc[mi][ni] = (f32x4){0.f,0.f,0.f,0.f};
  float acc2[2] = {0.f,0.f};
  int lrow = t>>2, lc8 = (t&3)*8;
  int brow = t/64, bcol = (t%64)*2;
  for (int k0=0; k0<256; k0+=32){
    int gk = k0 + lc8;
    *(uint4*)&As[lrow][lc8] = *(const uint4*)(A1 + (size_t)(m0+lrow)*256 + gk);
    if (t < 12 && !first){
      int r3 = t>>2, seg = t&3;
      *(uint4*)&Ab[r3][seg*8] = *(const uint4*)(A1 + (size_t)(m0-3+r3)*256 + k0 + seg*8);
    }
#pragma unroll
    for (int i=0;i<2;i++){
      int row = lrow + i*64;
      *(uint4*)&Bs[row][lc8] = *(const uint4*)(Wt + (size_t)(n0+row)*256 + gk);
    }
    __syncthreads();
    int lg = lane>>4, li = lane&15;
    s16x8 afr[2], bfr[4];
#pragma unroll
    for (int mi=0;mi<2;mi++)
      afr[mi] = *(const s16x8*)&As[wr*32+mi*16+li][lg*8];
#pragma unroll
    for (int ni=0;ni<4;ni++)
      bfr[ni] = *(const s16x8*)&Bs[wc*64+ni*16+li][lg*8];
#pragma unroll
    for (int mi=0;mi<2;mi++)
#pragma unroll
      for (int ni=0;ni<4;ni++)
        acc[mi][ni] = __builtin_amdgcn_mfma_f32_16x16x32_bf16(afr[mi], bfr[ni], acc[mi][ni], 0,0,0);
    if (t < 192 && !first){
#pragma unroll
      for (int kk=0;kk<32;kk++){
        float a = b2f(Ab[brow][kk]);
        acc2[0] += a * b2f(Bs[bcol][kk]);
        acc2[1] += a * b2f(Bs[bcol+1][kk]);
      }
    }
    __syncthreads();
  }
  {
    int lg = lane>>4, li = lane&15;
#pragma unroll
    for (int mi=0;mi<2;mi++)
#pragma unroll
      for (int ni=0;ni<4;ni++){
        int col = wc*64 + ni*16 + li;
#pragma unroll
        for (int r=0;r<4;r++){
          int rl = wr*32 + mi*16 + lg*4 + r;
          Cls[3+rl][col] = acc[mi][ni][r];
        }
      }
    if (t < 192){
      Cls[brow][bcol]   = first ? 0.f : acc2[0];
      Cls[brow][bcol+1] = first ? 0.f : acc2[1];
    }
  }
  __syncthreads();
  int col = t & 127, half = t >> 7;
  int ch = n0 + col;
  float w0 = cw[ch*4+0], w1 = cw[ch*4+1], w2 = cw[ch*4+2], w3 = cw[ch*4+3];
  float bias = cb[ch];
  int r0 = half*32;
  float c0 = Cls[r0+0][col], c1 = Cls[r0+1][col], c2 = Cls[r0+2][col];
#pragma unroll
  for (int rr=0; rr<32; rr++){
    float c3 = Cls[r0+rr+3][col];
    float v = bias + w0*c0 + w1*c1 + w2*c2 + w3*c3;
    XC[(size_t)(m0 + r0 + rr)*640 + ch] = f2b(silu_(v));
    c0=c1; c1=c2; c2=c3;
  }
}

// ---------------- dt: softplus(dtraw+bias); a = -dt*exp(a_log) -------------
__global__ __launch_bounds__(256) void dtk_k(
    const float* __restrict__ DTRAW, const float* __restrict__ dtb, const float* __restrict__ alog,
    float* __restrict__ DT_, float* __restrict__ AA_)
{
  int gid = blockIdx.x*256 + threadIdx.x;
  int h = gid & 7;
  float xv = DTRAW[gid] + dtb[h];
  float sp = (xv > 20.f) ? xv : log1pf(expf(xv));
  DT_[gid] = sp;
  AA_[gid] = -sp * expf(alog[h]);
}

// ---------------- per-chunk inclusive cumsum of a (full) -------------------
__global__ __launch_bounds__(256) void acs_k(const float* __restrict__ AA_, float* __restrict__ ACS_)
{
  int wid = (blockIdx.x<<2) + (threadIdx.x>>6);
  int lane = threadIdx.x & 63;
  int c  = wid & 15;
  int bh = wid >> 4;
  int b  = bh >> 3, h = bh & 7;
  size_t tok0 = (size_t)b*4096 + c*256 + lane*4;
  float v0 = AA_[(tok0+0)*8 + h];
  float v1 = AA_[(tok0+1)*8 + h];
  float v2 = AA_[(tok0+2)*8 + h];
  float v3 = AA_[(tok0+3)*8 + h];
  v1 += v0; v2 += v1; v3 += v2;
  float tot = v3, s = tot;
#pragma unroll
  for (int o=1;o<64;o<<=1){
    float u = __shfl_up(s, o, 64);
    if (lane >= o) s += u;
  }
  float excl = s - tot;
  float* dst = ACS_ + (size_t)bh*4096 + c*256 + lane*4;
  dst[0]=excl+v0; dst[1]=excl+v1; dst[2]=excl+v2; dst[3]=excl+v3;
}

// ------- chunk end-states via MFMA: ST[((bl*16+c)*8+h)][p][n] --------------
__global__ __launch_bounds__(256) void states_k(
    const u16* __restrict__ XC, const float* __restrict__ DTc, const float* __restrict__ ACSc,
    float* __restrict__ ST)
{
  int bid = blockIdx.x;                  // bl*128 + c*8 + h
  int h = bid & 7, c = (bid>>3)&15, bl = bid>>7;
  __shared__ u16 Xt[64][72];
  __shared__ u16 Bt[64][72];
  int t = threadIdx.x;
  int lane = t&63, w = t>>6;
  int wr = w>>1, wc = w&1;
  int lg = lane>>4, li = lane&15;
  const float* acs = ACSc + ((size_t)(bl*8+h))*4096 + c*256;
  float aL = acs[255];
  size_t tok0 = (size_t)bl*4096 + c*256;
  f32x4 acc[2][2];
#pragma unroll
  for (int mi=0;mi<2;mi++)
#pragma unroll
    for (int ni=0;ni<2;ni++) acc[mi][ni] = (f32x4){0.f,0.f,0.f,0.f};
  int sr = t>>2, cg = t&3;
  for (int s0=0; s0<256; s0+=64){
    __syncthreads();
    size_t grow = tok0 + s0 + sr;
    float dtv = DTc[grow*8 + h];
    float wdec = expf(aL - acs[s0+sr]);
    const u16* xrow = XC + grow*640 + h*64 + cg*16;
    const u16* brow = XC + grow*640 + 512 + cg*16;
    uint4 xa = *(const uint4*)xrow, xb = *(const uint4*)(xrow+8);
    uint4 ba = *(const uint4*)brow, bb = *(const uint4*)(brow+8);
    const u16* xu = (const u16*)&xa;
    const u16* bu = (const u16*)&ba;
#pragma unroll
    for (int j=0;j<8;j++){
      Xt[cg*16+j][sr]   = f2b(b2f(xu[j])*dtv);
      Bt[cg*16+j][sr]   = f2b(b2f(bu[j])*wdec);
    }
    const u16* xu2 = (const u16*)&xb;
    const u16* bu2 = (const u16*)&bb;
#pragma unroll
    for (int j=0;j<8;j++){
      Xt[cg*16+8+j][sr] = f2b(b2f(xu2[j])*dtv);
      Bt[cg*16+8+j][sr] = f2b(b2f(bu2[j])*wdec);
    }
    __syncthreads();
    s16x8 afr[2][2], bfr[2][2];
#pragma unroll
    for (int kk=0;kk<2;kk++){
#pragma unroll
      for (int mi=0;mi<2;mi++)
        afr[mi][kk] = *(const s16x8*)&Xt[wr*32+mi*16+li][kk*32+lg*8];
#pragma unroll
      for (int ni=0;ni<2;ni++)
        bfr[ni][kk] = *(const s16x8*)&Bt[wc*32+ni*16+li][kk*32+lg*8];
    }
#pragma unroll
    for (int kk=0;kk<2;kk++)
#pragma unroll
      for (int mi=0;mi<2;mi++)
#pragma unroll
        for (int ni=0;ni<2;ni++)
          acc[mi][ni] = __builtin_amdgcn_mfma_f32_16x16x32_bf16(afr[mi][kk], bfr[ni][kk], acc[mi][ni], 0,0,0);
  }
  float* dst = ST + (size_t)bid*4096;
#pragma unroll
  for (int mi=0;mi<2;mi++)
#pragma unroll
    for (int ni=0;ni<2;ni++){
      int gn = wc*32 + ni*16 + li;
#pragma unroll
      for (int r=0;r<4;r++){
        int gp = wr*32 + mi*16 + lg*4 + r;
        dst[gp*64 + gn] = acc[mi][ni][r];
      }
    }
}

// ------- sequential inter-chunk scan; STIN out bf16; split over e ----------
__global__ __launch_bounds__(256) void scan_k(
    const float* __restrict__ ST, const float* __restrict__ ACSc, u16* __restrict__ STIN)
{
  int bid = blockIdx.x;              // (bl*8+h)*4 + eq
  int eq = bid & 3, h = (bid>>2)&7, bl = bid>>5;
  int t = threadIdx.x;
  float hr[4] = {0.f,0.f,0.f,0.f};
  for (int c=0;c<16;c++){
    float dec = expf(ACSc[((size_t)(bl*8+h))*4096 + c*256 + 255]);
    size_t base = ((size_t)((bl*16+c)*8+h))*4096 + (size_t)eq*1024;
#pragma unroll
    for (int e=0;e<4;e++){
      size_t idx = base + e*256 + t;
      float st = ST[idx];
      STIN[idx] = f2b(hr[e]);
      hr[e] = hr[e]*dec + st;
    }
  }
}

// ------------ Y = Yd + Yo + d_skip*xs via MFMA (flash-style) ---------------
__global__ __launch_bounds__(256) void ydy_k(
    const u16* __restrict__ XC, const float* __restrict__ DTc,
    const float* __restrict__ ACSc, const u16* __restrict__ STIN,
    const float* __restrict__ dskip, u16* __restrict__ Y)
{
  int bid = blockIdx.x;                      // bl*512 + (c*8+h)*4 + lt
  int lt = bid & 3, h = (bid>>2)&7, c = (bid>>5)&15, bl = bid>>9;
  int l0 = lt*64;
  __shared__ u16 Ct[64][72];
  __shared__ u16 Sb[64][72];
  __shared__ u16 Vt[64][72];
  __shared__ u16 Sl[64][72];
  int t = threadIdx.x;
  int lane = t&63, w = t>>6;
  int wr = w>>1, wc = w&1;
  int lg = lane>>4, li = lane&15;
  const float* acs = ACSc + ((size_t)(bl*8+h))*4096 + c*256;
  size_t tok0 = (size_t)bl*4096 + c*256;
  int sr = t>>2;
#pragma unroll
  for (int it=0; it<2; it++){
    int seg = (t&3) + it*4;
    *(uint4*)&Ct[sr][seg*8] = *(const uint4*)(XC + (tok0+l0+sr)*640 + 576 + seg*8);
  }
  float acsl[2][4];
#pragma unroll
  for (int mi=0;mi<2;mi++)
#pragma unroll
    for (int r=0;r<4;r++)
      acsl[mi][r] = acs[l0 + wr*32 + mi*16 + lg*4 + r];
  f32x4 accP[2][2], accO[2][2];
#pragma unroll
  for (int mi=0;mi<2;mi++)
#pragma unroll
    for (int ni=0;ni<2;ni++){ accP[mi][ni]=(f32x4){0,0,0,0}; accO[mi][ni]=(f32x4){0,0,0,0}; }
  __syncthreads();
  const u16* stin = STIN + ((size_t)((bl*16+c)*8+h))*4096;
#pragma unroll
  for (int kk=0;kk<2;kk++){
    s16x8 bfr[2];
#pragma unroll
    for (int ni=0;ni<2;ni++){
      int p = wc*32 + ni*16 + li;
      bfr[ni] = *(const s16x8*)(stin + p*64 + kk*32 + lg*8);
    }
#pragma unroll
    for (int mi=0;mi<2;mi++){
      s16x8 afr = *(const s16x8*)&Ct[wr*32+mi*16+li][kk*32+lg*8];
#pragma unroll
      for (int ni=0;ni<2;ni++)
        accO[mi][ni] = __builtin_amdgcn_mfma_f32_16x16x32_bf16(afr, bfr[ni], accO[mi][ni], 0,0,0);
    }
  }
  for (int sb=0; sb<=lt; sb++){
    int s0 = sb*64;
    __syncthreads();
#pragma unroll
    for (int it=0; it<2; it++){
      int seg = (t&3) + it*4;
      *(uint4*)&Sb[sr][seg*8] = *(const uint4*)(XC + (tok0+s0+sr)*640 + 512 + seg*8);
    }
    {
      int cg = t&3;
      size_t grow = tok0 + s0 + sr;
      float dtv = DTc[grow*8 + h];
      const u16* xrow = XC + grow*640 + h*64 + cg*16;
      uint4 xa = *(const uint4*)xrow, xb = *(const uint4*)(xrow+8);
      const u16* xu = (const u16*)&xa;
#pragma unroll
      for (int j=0;j<8;j++) Vt[cg*16+j][sr] = f2b(b2f(xu[j])*dtv);
      const u16* xu2 = (const u16*)&xb;
#pragma unroll
      for (int j=0;j<8;j++) Vt[cg*16+8+j][sr] = f2b(b2f(xu2[j])*dtv);
    }
    __syncthreads();
    f32x4 sacc[2][2];
#pragma unroll
    for (int mi=0;mi<2;mi++)
#pragma unroll
      for (int ni=0;ni<2;ni++) sacc[mi][ni]=(f32x4){0,0,0,0};
#pragma unroll
    for (int kk=0;kk<2;kk++){
      s16x8 bfr[2];
#pragma unroll
      for (int ni=0;ni<2;ni++)
        bfr[ni] = *(const s16x8*)&Sb[wc*32+ni*16+li][kk*32+lg*8];
#pragma unroll
      for (int mi=0;mi<2;mi++){
        s16x8 afr = *(const s16x8*)&Ct[wr*32+mi*16+li][kk*32+lg*8];
#pragma unroll
        for (int ni=0;ni<2;ni++)
          sacc[mi][ni] = __builtin_amdgcn_mfma_f32_16x16x32_bf16(afr, bfr[ni], sacc[mi][ni], 0,0,0);
      }
    }
#pragma unroll
    for (int ni=0;ni<2;ni++){
      int cs = wc*32 + ni*16 + li;
      int gsj = s0 + cs;
      float acss = acs[gsj];
#pragma unroll
      for (int mi=0;mi<2;mi++){
#pragma unroll
        for (int r=0;r<4;r++){
          int lrow = wr*32 + mi*16 + lg*4 + r;
          int gl = l0 + lrow;
          float wgt = (gsj <= gl) ? expf(acsl[mi][r] - acss) : 0.f;
          Sl[lrow][cs] = f2b(sacc[mi][ni][r] * wgt);
        }
      }
    }
    __syncthreads();
#pragma unroll
    for (int kk=0;kk<2;kk++){
      s16x8 bfr[2];
#pragma unroll
      for (int ni=0;ni<2;ni++)
        bfr[ni] = *(const s16x8*)&Vt[wc*32+ni*16+li][kk*32+lg*8];
#pragma unroll
      for (int mi=0;mi<2;mi++){
        s16x8 afr = *(const s16x8*)&Sl[wr*32+mi*16+li][kk*32+lg*8];
#pragma unroll
        for (int ni=0;ni<2;ni++)
          accP[mi][ni] = __builtin_amdgcn_mfma_f32_16x16x32_bf16(afr, bfr[ni], accP[mi][ni], 0,0,0);
      }
    }
  }
  __syncthreads();
#pragma unroll
  for (int it=0; it<2; it++){
    int seg = (t&3) + it*4;
    *(uint4*)&Sb[sr][seg*8] = *(const uint4*)(XC + (tok0+l0+sr)*640 + h*64 + seg*8);
  }
  __syncthreads();
  float dsk = dskip[h];
#pragma unroll
  for (int mi=0;mi<2;mi++){
#pragma unroll
    for (int ni=0;ni<2;ni++){
      int p = wc*32 + ni*16 + li;
#pragma unroll
      for (int r=0;r<4;r++){
        int lrow = wr*32 + mi*16 + lg*4 + r;
        float el = expf(acsl[mi][r]);
        float xsv = b2f(Sb[lrow][p]);
        Sl[lrow][p] = f2b(accP[mi][ni][r] + el*accO[mi][ni][r] + dsk*xsv);
      }
    }
  }
  __syncthreads();
#pragma unroll
  for (int it=0; it<2; it++){
    int seg = (t&3) + it*4;
    *(uint4*)(Y + (tok0+l0+sr)*512 + h*64 + seg*8) = *(const uint4*)&Sl[sr][seg*8];
  }
}

// ---------------- u = y*silu(z); RMSNorm*w over 512 (in place) -------------
__global__ __launch_bounds__(256) void urms_k(
    u16* Y, const u16* __restrict__ Z, const float* __restrict__ nw)
{
  int tok = blockIdx.x*4 + (threadIdx.x>>6);
  int lane = threadIdx.x & 63;
  size_t base = (size_t)tok*512 + lane*8;
  float y[8], z[8], u[8];
  ld8(Y+base, y); ld8(Z+base, z);
  float ss=0.f;
#pragma unroll
  for (int e=0;e<8;e++){ u[e] = y[e]*silu_(z[e]); ss += u[e]*u[e]; }
  ss = wsum_(ss);
  float r = rsqrtf(ss*(1.f/512.f) + 1e-5f);
  float4 w0 = *(const float4*)(nw + lane*8);
  float4 w1 = *(const float4*)(nw + lane*8 + 4);
  float o[8];
  o[0]=u[0]*r*w0.x; o[1]=u[1]*r*w0.y; o[2]=u[2]*r*w0.z; o[3]=u[3]*r*w0.w;
  o[4]=u[4]*r*w1.x; o[5]=u[5]*r*w1.y; o[6]=u[6]*r*w1.z; o[7]=u[7]*r*w1.w;
  st8(Y+base, o);
}

// ------------ window attention via MFMA, block per (window, head) ----------
// 4 waves; wave w owns score/output rows w*16..w*16+15. In-register softmax.
__global__ __launch_bounds__(256) void attn_k(
    const u16* __restrict__ QKV, const float* __restrict__ rpb, u16* __restrict__ OW)
{
  int win = blockIdx.x;      // chunk-local window
  int wid = win & 63;        // geometry window
  int head = blockIdx.y;
  __shared__ u16 Qs[64][40];
  __shared__ u16 Ks[64][40];
  __shared__ u16 Vt[32][72];
  __shared__ u16 Pl[64][72];
  __shared__ float rl[225];
  __shared__ int rid[64];
  int t = threadIdx.x;
  int lane = t&63, w = t>>6;
  int lg = lane>>4, li = lane&15;
  const float scale = 0.17677669529663687f;  // 32^-0.5
  // stage Q (scaled), K, V^T
  {
    int row = t>>2, seg = t&3;
    const u16* base = QKV + ((size_t)win*64 + row)*768 + head*32 + seg*8;
    uint4 q = *(const uint4*)base;
    const u16* qe = (const u16*)&q;
    u16 qs8[8];
#pragma unroll
    for (int j=0;j<8;j++) qs8[j] = f2b(b2f(qe[j])*scale);
    *(uint4*)&Qs[row][seg*8] = *(const uint4*)qs8;
    *(uint4*)&Ks[row][seg*8] = *(const uint4*)(base + 256);
    uint4 v = *(const uint4*)(base + 512);
    const u16* ve = (const u16*)&v;
#pragma unroll
    for (int j=0;j<8;j++) Vt[seg*8+j][row] = ve[j];
  }
  if (t < 225) rl[t] = rpb[t*8 + head];
  if (t < 64){
    int h2 = ((wid>>3)<<3) + (t>>3);
    int w2 = ((wid&7)<<3) + (t&7);
    int rh = (h2<56)?0:((h2<60)?1:2);
    int rw = (w2<56)?0:((w2<60)?1:2);
    rid[t] = rh*3 + rw;
  }
  __syncthreads();
  // S = Q·K^T (rows w*16.., K=32 in one step)
  f32x4 sc[4];
  {
    s16x8 qf = *(const s16x8*)&Qs[w*16+li][lg*8];
#pragma unroll
    for (int ni=0;ni<4;ni++){
      s16x8 kf = *(const s16x8*)&Ks[ni*16+li][lg*8];
      sc[ni] = __builtin_amdgcn_mfma_f32_16x16x32_bf16(qf, kf, (f32x4){0,0,0,0}, 0,0,0);
    }
  }
  // softmax in-register: row = w*16+lg*4+r lives across li lanes x 4 ni regs
  float inv[4];
#pragma unroll
  for (int r=0;r<4;r++){
    int i = w*16 + lg*4 + r;
    int ridi = rid[i];
    float vv[4];
    float m = -1e30f;
#pragma unroll
    for (int ni=0;ni<4;ni++){
      int j = ni*16 + li;
      float s = sc[ni][r] + rl[((i>>3)-(j>>3)+7)*15 + ((i&7)-(j&7)+7)];
      if (ridi != rid[j]) s -= 100.f;
      vv[ni] = s;
      m = fmaxf(m, s);
    }
#pragma unroll
    for (int o=1;o<16;o<<=1) m = fmaxf(m, __shfl_xor(m, o, 64));
    float sum = 0.f;
#pragma unroll
    for (int ni=0;ni<4;ni++){ vv[ni] = expf(vv[ni]-m); sum += vv[ni]; }
#pragma unroll
    for (int o=1;o<16;o<<=1) sum += __shfl_xor(sum, o, 64);
    inv[r] = 1.f/sum;
#pragma unroll
    for (int ni=0;ni<4;ni++) Pl[i][ni*16+li] = f2b(vv[ni]);
  }
  __syncthreads();
  // O = P·V, rows w*16.. ; cols 0..31
  f32x4 oacc[2];
  oacc[0]=(f32x4){0,0,0,0}; oacc[1]=(f32x4){0,0,0,0};
#pragma unroll
  for (int kk=0;kk<2;kk++){
    s16x8 pf = *(const s16x8*)&Pl[w*16+li][kk*32+lg*8];
#pragma unroll
    for (int ni=0;ni<2;ni++){
      s16x8 vf = *(const s16x8*)&Vt[ni*16+li][kk*32+lg*8];
      oacc[ni] = __builtin_amdgcn_mfma_f32_16x16x32_bf16(pf, vf, oacc[ni], 0,0,0);
    }
  }
  // write scaled output into Pl[row][0..31] (wave-local rows)
#pragma unroll
  for (int ni=0;ni<2;ni++)
#pragma unroll
    for (int r=0;r<4;r++)
      Pl[w*16+lg*4+r][ni*16+li] = f2b(oacc[ni][r]*inv[r]);
  __syncthreads();
  // coalesced store: 64 rows x 32 cols
  {
    int row = t>>2, seg = t&3;
    *(uint4*)(OW + ((size_t)win*64 + row)*256 + head*32 + seg*8) = *(const uint4*)&Pl[row][seg*8];
  }
}

// ---------------- xm *= gm ; xa *= ga (bf16) -------------------------------
__global__ __launch_bounds__(256) void mul2_k(
    u16* XM, const u16* __restrict__ GM, u16* XA, const u16* __restrict__ GA)
{
  size_t i = ((size_t)blockIdx.x*256 + threadIdx.x)*4;
  float4 m = ld4(XM+i), g = ld4(GM+i);
  st4(XM+i, m.x*g.x, m.y*g.y, m.z*g.z, m.w*g.w);
  float4 a = ld4(XA+i), g2 = ld4(GA+i);
  st4(XA+i, a.x*g2.x, a.y*g2.y, a.z*g2.z, a.w*g2.w);
}

// ---------------- host ------------------------------------------------------
extern "C" void kernel_launch(void* const* d_in, const int* in_sizes, int n_in,
                              void* d_out, int out_size, void* d_ws, size_t ws_size,
                              hipStream_t stream)
{
  (void)in_sizes; (void)n_in; (void)out_size;
  const size_t OFF_XN   = 0;
  const size_t OFF_XNS  = 16777216;
  const size_t OFF_SP   = 33554432;
  const size_t OFF_DTRAW= 50331648;
  const size_t OFF_DT   = 51380224;
  const size_t OFF_AA   = 52428800;
  const size_t OFF_ACS  = 53477376;
  const size_t OFF_WTS  = 54525952;
  const size_t ARO      = 58195968;
  int NB = 0;
  if      (ws_size >= ARO + 8ull*14680064) NB = 8;
  else if (ws_size >= ARO + 4ull*14680064) NB = 4;
  else if (ws_size >= ARO + 2ull*14680064) NB = 2;
  else if (ws_size >= ARO + 1ull*14680064) NB = 1;
  else return;
  int NC = 8 / NB;
  int RJ = (NB==8)?32768 : (NB==4)?16384 : (NB==2)?8192 : 4096;

  const float* x       = (const float*)d_in[0];
  const float* ln1_w   = (const float*)d_in[1];
  const float* ln1_b   = (const float*)d_in[2];
  const float* ns_w    = (const float*)d_in[3];
  const float* ns_b    = (const float*)d_in[4];
  const float* m_win   = (const float*)d_in[5];
  const float* m_conv_w= (const float*)d_in[6];
  const float* m_conv_b= (const float*)d_in[7];
  const float* m_dt_b  = (const float*)d_in[8];
  const float* m_a_log = (const float*)d_in[9];
  const float* m_d     = (const float*)d_in[10];
  const float* m_norm_w= (const float*)d_in[11];
  const float* m_wout  = (const float*)d_in[12];
  const float* tm_w1   = (const float*)d_in[13];
  const float* tm_b1   = (const float*)d_in[14];
  const float* tm_w2   = (const float*)d_in[15];
  const float* tm_b2   = (const float*)d_in[16];
  const float* nt_w    = (const float*)d_in[17];
  const float* nt_b    = (const float*)d_in[18];
  const float* qkv_w   = (const float*)d_in[19];
  const float* qkv_b   = (const float*)d_in[20];
  const float* rpb     = (const float*)d_in[21];
  const float* gate_w  = (const float*)d_in[22];
  const float* gate_b  = (const float*)d_in[23];
  const float* proj_w  = (const float*)d_in[24];
  const float* proj_b  = (const float*)d_in[25];
  const float* cg_w1a  = (const float*)d_in[26];
  const float* cg_b1a  = (const float*)d_in[27];
  const float* cg_w2a  = (const float*)d_in[28];
  const float* cg_b2a  = (const float*)d_in[29];
  const float* cg_w1m  = (const float*)d_in[30];
  const float* cg_b1m  = (const float*)d_in[31];
  const float* cg_w2m  = (const float*)d_in[32];
  const float* cg_b2m  = (const float*)d_in[33];
  const float* cg_wf   = (const float*)d_in[34];
  const float* cg_bf   = (const float*)d_in[35];
  const float* ln2_w   = (const float*)d_in[36];
  const float* ln2_b   = (const float*)d_in[37];
  const float* mlp_w1  = (const float*)d_in[38];
  const float* mlp_b1  = (const float*)d_in[39];
  const float* mlp_w2  = (const float*)d_in[40];
  const float* mlp_b2  = (const float*)d_in[41];
  float* dout = (float*)d_out;
  char* ws = (char*)d_ws;

  u16*  XN   = (u16*)(ws + OFF_XN);
  u16*  XNS  = (u16*)(ws + OFF_XNS);
  u16*  SP   = (u16*)(ws + OFF_SP);
  float* DTRAW = (float*)(ws + OFF_DTRAW);
  float* DT  = (float*)(ws + OFF_DT);
  float* AA  = (float*)(ws + OFF_AA);
  float* ACS = (float*)(ws + OFF_ACS);
  u16*  WTS  = (u16*)(ws + OFF_WTS);
  u16* WT_XBC = WTS + 0;
  u16* WT_Z   = WTS + 163840;
  u16* WT_WOUT= WTS + 294912;
  u16* WT_TM1 = WTS + 425984;
  u16* WT_TM2 = WTS + 491520;
  u16* WT_QKV = WTS + 557056;
  u16* WT_GATE= WTS + 753664;
  u16* WT_PROJ= WTS + 819200;
  u16* WT_W2A = WTS + 884736;
  u16* WT_W2M = WTS + 901120;
  u16* WT_WF  = WTS + 917504;
  u16* WT_MLP1= WTS + 1048576;
  u16* WT_MLP2= WTS + 1310720;
  u16* WT_W1A = WTS + 1572864;
  u16* WT_W1M = WTS + 1589248;
  char* AR = ws + ARO;
  u16*  XCc   = (u16*)AR;
  u16*  Zc    = (u16*)(AR + (size_t)NB*5242880);
  u16*  STINc = (u16*)(AR + (size_t)NB*9437184);
  float* STc  = (float*)(AR + (size_t)NB*10485760);
  u16*  Yc    = (u16*)(AR + (size_t)NB*10485760);
  u16*  QKVc  = (u16*)AR;
  u16*  OWc   = (u16*)(AR + (size_t)NB*6291456);
  u16*  TBUF  = (u16*)AR;
  u16*  XM    = XNS;
  u16*  XA    = XN;
  u16*  CGH   = (u16*)AR;
  u16*  GA    = (u16*)(AR + 4194304);
  u16*  GM    = SP;
  u16*  LNc   = (u16*)AR;
  u16*  MHc   = (u16*)(AR + (size_t)RJ*512);

  const size_t TB = 4096*256;
  const size_t H2 = 16384*256;

  // Phase 0: weight convert+transpose
  wt_k<<<dim3(8,20),256,0,stream>>>(m_win+512,1160,256, WT_XBC);
  wt_k<<<dim3(8,16),256,0,stream>>>(m_win,    1160,256, WT_Z);
  wt_k<<<dim3(16,8),256,0,stream>>>(m_wout,    256,512, WT_WOUT);
  wt_k<<<dim3(16,8),256,0,stream>>>(tm_w1,     256,512, WT_TM1);
  wt_k<<<dim3(8,8), 256,0,stream>>>(tm_w2,     256,256, WT_TM2);
  wt_k<<<dim3(8,24),256,0,stream>>>(qkv_w,     768,256, WT_QKV);
  wt_k<<<dim3(8,8), 256,0,stream>>>(gate_w,    256,256, WT_GATE);
  wt_k<<<dim3(8,8), 256,0,stream>>>(proj_w,    256,256, WT_PROJ);
  wt_k<<<dim3(2,8), 256,0,stream>>>(cg_w2a,    256,64,  WT_W2A);
  wt_k<<<dim3(2,8), 256,0,stream>>>(cg_w2m,    256,64,  WT_W2M);
  wt_k<<<dim3(16,8),256,0,stream>>>(cg_wf,     256,512, WT_WF);
  wt_k<<<dim3(8,32),256,0,stream>>>(mlp_w1,   1024,256, WT_MLP1);
  wt_k<<<dim3(32,8),256,0,stream>>>(mlp_w2,    256,1024,WT_MLP2);
  wt_k<<<dim3(8,2), 256,0,stream>>>(cg_w1a,     64,256, WT_W1A);
  wt_k<<<dim3(8,2), 256,0,stream>>>(cg_w1m,     64,256, WT_W1M);

  // Phase A
  ln2x_k<<<8192,256,0,stream>>>(x, ln1_w, ln1_b, ns_w, ns_b, XN, XNS);
  gemm_k<EPI_NONE,float,float><<<dim3(1,512),256,0,stream>>>(XNS,nullptr,256,0, m_win+1152,1160, nullptr, nullptr, DTRAW, 32768,8);
  dtk_k<<<1024,256,0,stream>>>(DTRAW, m_dt_b, m_a_log, DT, AA);
  acs_k<<<256,256,0,stream>>>(AA, ACS);

  // Phases B..F per chunk of NB batches
  for (int cc=0; cc<NC; cc++){
    int cb0 = cc*NB;
    const u16* XNSc = XNS + (size_t)cb0*TB;
    const float* DTcp = DT + (size_t)cb0*32768;
    const float* ACScp = ACS + (size_t)cb0*32768;
    xbcconv_k<<<dim3(5,NB*64),256,0,stream>>>(XNSc, WT_XBC, m_conv_w, m_conv_b, XCc);
    states_k<<<NB*128,256,0,stream>>>(XCc, DTcp, ACScp, STc);
    scan_k<<<NB*32,256,0,stream>>>(STc, ACScp, STINc);
    ydy_k<<<NB*512,256,0,stream>>>(XCc, DTcp, ACScp, STINc, m_d, Yc);
    mgemm_k<64,128,EPI_NONE,false,false,float,u16><<<dim3(4,NB*64),256,0,stream>>>(XNSc,nullptr,256,0, WT_Z, nullptr, nullptr, Zc, 512, 0);
    urms_k<<<NB*1024,256,0,stream>>>(Yc, Zc, m_norm_w);
    mgemm_k<64,128,EPI_ADD,false,false,u16,u16><<<dim3(2,NB*64),256,0,stream>>>(Yc,nullptr,512,0, WT_WOUT, nullptr, XN + (size_t)cb0*TB, SP + (size_t)cb0*TB, 256, 0);
  }

  // Phase G: tmix
  mgemm_k<128,128,EPI_SILU,false,false,float,u16><<<dim3(2,128),256,0,stream>>>(SP, SP+H2, 256,256, WT_TM1, tm_b1, nullptr, TBUF, 256, 0);
  mgemm_k<128,128,EPI_ADD,false,false,u16,u16><<<dim3(2,128),256,0,stream>>>(TBUF,nullptr,256,0, WT_TM2, tm_b2, SP, XM, 256, 0);
  ln_k<u16><<<4096,256,0,stream>>>(XM, nt_w, nt_b, XM);
  mgemm_k<128,128,EPI_SILU,false,false,float,u16><<<dim3(2,128),256,0,stream>>>(SP+H2, XM, 256,256, WT_TM1, tm_b1, nullptr, TBUF, 256, 0);
  mgemm_k<128,128,EPI_ADD,false,false,u16,u16><<<dim3(2,128),256,0,stream>>>(TBUF,nullptr,256,0, WT_TM2, tm_b2, SP+H2, XM+H2, 256, 0);
  ln_k<u16><<<4096,256,0,stream>>>(XM+H2, nt_w, nt_b, XM+H2);

  // Phase H: window attention
  for (int cc=0; cc<NC; cc++){
    int r0 = cc*NB*4096;
    mgemm_k<64,128,EPI_NONE,true,false,float,u16><<<dim3(6,NB*64),256,0,stream>>>(XN,nullptr,256,0, WT_QKV, qkv_b, nullptr, QKVc, 768, r0);
    attn_k<<<dim3(NB*64,8),256,0,stream>>>(QKVc, rpb, OWc);
    mgemm_k<64,128,EPI_SIGMUL,true,false,u16,u16><<<dim3(2,NB*64),256,0,stream>>>(XN,nullptr,256,0, WT_GATE, gate_b, OWc, OWc, 256, r0);
    mgemm_k<64,128,EPI_NONE,false,true,float,u16><<<dim3(2,NB*64),256,0,stream>>>(OWc,nullptr,256,0, WT_PROJ, proj_b, nullptr, XA, 256, r0);
  }

  // Phase I: cross gates
  mgemm_k<128,64,EPI_RELU,false,false,float,u16><<<dim3(1,256),256,0,stream>>>(XA,nullptr,256,0, WT_W1A, cg_b1a, nullptr, CGH, 64, 0);
  mgemm_k<128,128,EPI_SIGMOID,false,false,float,u16><<<dim3(2,256),256,0,stream>>>(CGH,nullptr,64,0, WT_W2A, cg_b2a, nullptr, GM, 256, 0);
  mgemm_k<128,64,EPI_RELU,false,false,float,u16><<<dim3(1,256),256,0,stream>>>(XM,nullptr,256,0, WT_W1M, cg_b1m, nullptr, CGH, 64, 0);
  mgemm_k<128,128,EPI_SIGMOID,false,false,float,u16><<<dim3(2,256),256,0,stream>>>(CGH,nullptr,64,0, WT_W2M, cg_b2m, nullptr, GA, 256, 0);
  mul2_k<<<8192,256,0,stream>>>(XM, GM, XA, GA);
  mgemm_k<128,128,EPI_ADD,false,false,float,float><<<dim3(2,256),256,0,stream>>>(XM, XA, 256,256, WT_WF, cg_bf, x, dout, 256, 0);

  // Phase J: MLP
  for (int q=0; q<32768/RJ; q++){
    float* XOq = dout + (size_t)q*RJ*256;
    ln_k<float><<<RJ/4,256,0,stream>>>(XOq, ln2_w, ln2_b, LNc);
    mgemm_k<128,128,EPI_GELU,false,false,float,u16><<<dim3(8,RJ/128),256,0,stream>>>(LNc,nullptr,256,0, WT_MLP1, mlp_b1, nullptr, MHc, 1024, 0);
    mgemm_k<64,128,EPI_ADD,false,false,float,float><<<dim3(2,RJ/64),256,0,stream>>>(MHc,nullptr,1024,0, WT_MLP2, mlp_b2, XOq, XOq, 256, 0);
  }
}

// Round 7
// 706.808 us; speedup vs baseline: 4.7501x; 1.0016x over previous
//
#include <hip/hip_runtime.h>
#include <math.h>

// twoB=8, L=4096 (H=W=64), C=256, d_inner=512, nh_m=8, hd=64, D_STATE=64,
// conv_dim=640, zx width=1160, CHUNK=256 (16 chunks/batch), WS=8, SS=4, NH=8, Dh=32.

#define DEVI static __device__ __forceinline__
typedef unsigned short u16;
typedef unsigned int   u32;
typedef __attribute__((ext_vector_type(8))) short s16x8;
typedef __attribute__((ext_vector_type(4))) float f32x4;

DEVI float sigm_(float x){ return 1.f/(1.f+__expf(-x)); }
DEVI float silu_(float x){ return x/(1.f+__expf(-x)); }
DEVI float wsum_(float v){
#pragma unroll
  for (int o=32;o>0;o>>=1) v += __shfl_xor(v,o,64);
  return v;
}

DEVI float b2f(u16 u){ union{u32 i; float f;} v; v.i = ((u32)u)<<16; return v.f; }
DEVI u16 f2b(float f){ union{float f; u32 i;} v; v.f=f; u32 r = v.i + 0x7fffu + ((v.i>>16)&1u); return (u16)(r>>16); }
DEVI float4 ld4(const float* p){ return *(const float4*)p; }
DEVI float4 ld4(const u16* p){
  uint2 r = *(const uint2*)p;
  return make_float4(b2f((u16)(r.x&0xffff)), b2f((u16)(r.x>>16)),
                     b2f((u16)(r.y&0xffff)), b2f((u16)(r.y>>16)));
}
DEVI void st4(u16* p, float a, float b, float c, float d){
  uint2 r; r.x = (u32)f2b(a) | ((u32)f2b(b)<<16); r.y = (u32)f2b(c) | ((u32)f2b(d)<<16);
  *(uint2*)p = r;
}
DEVI void ld8(const u16* p, float* f){
  uint4 r = *(const uint4*)p;
  f[0]=b2f((u16)(r.x&0xffff)); f[1]=b2f((u16)(r.x>>16));
  f[2]=b2f((u16)(r.y&0xffff)); f[3]=b2f((u16)(r.y>>16));
  f[4]=b2f((u16)(r.z&0xffff)); f[5]=b2f((u16)(r.z>>16));
  f[6]=b2f((u16)(r.w&0xffff)); f[7]=b2f((u16)(r.w>>16));
}
DEVI void st8(u16* p, const float* f){
  uint4 r;
  r.x=(u32)f2b(f[0])|((u32)f2b(f[1])<<16); r.y=(u32)f2b(f[2])|((u32)f2b(f[3])<<16);
  r.z=(u32)f2b(f[4])|((u32)f2b(f[5])<<16); r.w=(u32)f2b(f[6])|((u32)f2b(f[7])<<16);
  *(uint4*)p = r;
}
DEVI float tof(float v){ return v; }
DEVI float tof(u16 v){ return b2f(v); }
DEVI void sto(float* p, float v){ *p = v; }
DEVI void sto(u16* p, float v){ *p = f2b(v); }

// window row -> token map (roll by -4, 8x8 windows over 64x64, per batch)
DEVI int winmap_tok(int r){
  int win = r>>6, tk = r&63;
  int b = win>>6, wid = win&63;
  int h2 = ((wid>>3)<<3) + (tk>>3);
  int w2 = ((wid&7)<<3) + (tk&7);
  int hh = (h2+4)&63, wwp = (w2+4)&63;
  return b*4096 + hh*64 + wwp;
}

// ---------------- fused LN(x)->xn, LN(xn)->xns (bf16 outs) -----------------
__global__ __launch_bounds__(256) void ln2x_k(
    const float* __restrict__ x, const float* __restrict__ w1, const float* __restrict__ b1,
    const float* __restrict__ w2, const float* __restrict__ b2,
    u16* __restrict__ xn, u16* __restrict__ xns)
{
  int tok = blockIdx.x*4 + (threadIdx.x>>6);
  int lane = threadIdx.x & 63;
  size_t base = (size_t)tok*256 + lane*4;
  float4 v = *(const float4*)(x + base);
  float mu = wsum_(v.x+v.y+v.z+v.w) * (1.f/256.f);
  float ax=v.x-mu, ay=v.y-mu, az=v.z-mu, aw=v.w-mu;
  float var = wsum_(ax*ax+ay*ay+az*az+aw*aw) * (1.f/256.f);
  float r = rsqrtf(var+1e-5f);
  float4 wv = *(const float4*)(w1+lane*4);
  float4 bv = *(const float4*)(b1+lane*4);
  float ox=ax*r*wv.x+bv.x, oy=ay*r*wv.y+bv.y, oz=az*r*wv.z+bv.z, ow=aw*r*wv.w+bv.w;
  st4(xn + base, ox, oy, oz, ow);
  float mu2 = wsum_(ox+oy+oz+ow)*(1.f/256.f);
  float bx=ox-mu2, by=oy-mu2, bz=oz-mu2, bw=ow-mu2;
  float var2 = wsum_(bx*bx+by*by+bz*bz+bw*bw)*(1.f/256.f);
  float r2 = rsqrtf(var2+1e-5f);
  float4 w2v = *(const float4*)(w2+lane*4);
  float4 b2v = *(const float4*)(b2+lane*4);
  st4(xns + base, bx*r2*w2v.x+b2v.x, by*r2*w2v.y+b2v.y, bz*r2*w2v.z+b2v.z, bw*r2*w2v.w+b2v.w);
}

// ---------------- generic LayerNorm (C=256), bf16 out ----------------------
template<typename IT>
__global__ __launch_bounds__(256) void ln_k(
    const IT* __restrict__ in, const float* __restrict__ w, const float* __restrict__ b,
    u16* __restrict__ outp)
{
  int tok = blockIdx.x*4 + (threadIdx.x>>6);
  int lane = threadIdx.x & 63;
  size_t base = (size_t)tok*256 + lane*4;
  float4 v = ld4(in + base);
  float mu = wsum_(v.x+v.y+v.z+v.w) * (1.f/256.f);
  float ax=v.x-mu, ay=v.y-mu, az=v.z-mu, aw=v.w-mu;
  float var = wsum_(ax*ax+ay*ay+az*az+aw*aw) * (1.f/256.f);
  float r = rsqrtf(var+1e-5f);
  float4 wv = *(const float4*)(w+lane*4);
  float4 bv = *(const float4*)(b+lane*4);
  st4(outp + base, ax*r*wv.x+bv.x, ay*r*wv.y+bv.y, az*r*wv.z+bv.z, aw*r*wv.w+bv.w);
}

// ---------------- weight fp32[K][N](ldw) -> bf16 Wt[N][K] ------------------
__global__ __launch_bounds__(256) void wt_k(
    const float* __restrict__ W, int ldw, int K, u16* __restrict__ Wt)
{
  __shared__ float tl[32][33];
  int k0 = blockIdx.x*32, n0 = blockIdx.y*32;
  int t = threadIdx.x; int ty=t>>5, tx=t&31;
#pragma unroll
  for (int i=0;i<4;i++){
    int k = ty + i*8;
    tl[k][tx] = W[(size_t)(k0+k)*ldw + n0+tx];
  }
  __syncthreads();
#pragma unroll
  for (int i=0;i<4;i++){
    int n = ty + i*8;
    Wt[(size_t)(n0+n)*K + k0 + tx] = f2b(tl[tx][n]);
  }
}

enum { EPI_NONE=0, EPI_SILU=1, EPI_GELU=2, EPI_SIGMUL=3, EPI_ADD=4, EPI_RELU=5, EPI_SIGMOID=6 };

// -------- MFMA GEMM: out[M,N] = epi(cat(A1,A2)[M,K] @ Wt[N,K]^T + bias) ----
// BK=32, 4 waves (2x2). WIN: gather A rows via winmap. WINST: scatter out rows.
template<int BM, int BN, int EPI, bool WIN, bool WINST, typename OT, typename CT>
__global__ __launch_bounds__(256) void mgemm_k(
    const u16* __restrict__ A1, const u16* __restrict__ A2, int K1, int K2,
    const u16* __restrict__ Wt, const float* __restrict__ bias,
    const OT* other, CT* outp, int N, int r0)
{
  constexpr int MW = BM/32;
  constexpr int NWF = BN/32;
  constexpr int LA = BM/64;
  constexpr int LB = BN/64;
  __shared__ u16 As[BM][40];
  __shared__ u16 Bs[BN][40];
  int m0 = blockIdx.y*BM, n0 = blockIdx.x*BN;
  int t = threadIdx.x;
  int lane = t&63, w = t>>6;
  int wr = w>>1, wc = w&1;
  int K = K1 + K2;
  f32x4 acc[MW][NWF];
#pragma unroll
  for (int mi=0;mi<MW;mi++)
#pragma unroll
    for (int ni=0;ni<NWF;ni++) acc[mi][ni] = (f32x4){0.f,0.f,0.f,0.f};
  int lrow = t>>2, lc8 = (t&3)*8;
  size_t aoff1[LA], aoff2[LA];
#pragma unroll
  for (int i=0;i<LA;i++){
    int gr = m0 + lrow + i*64;
    if (WIN) aoff1[i] = (size_t)winmap_tok(r0+gr)*K1;
    else { aoff1[i] = (size_t)gr*K1; aoff2[i] = (size_t)gr*K2; }
  }
  for (int k0=0; k0<K; k0+=32){
    int gk = k0 + lc8;
#pragma unroll
    for (int i=0;i<LA;i++){
      const u16* ap = (WIN || gk < K1) ? A1 + aoff1[i] + gk : A2 + aoff2[i] + (gk-K1);
      *(uint4*)&As[lrow + i*64][lc8] = *(const uint4*)ap;
    }
#pragma unroll
    for (int i=0;i<LB;i++){
      int row = lrow + i*64;
      *(uint4*)&Bs[row][lc8] = *(const uint4*)(Wt + (size_t)(n0+row)*K + gk);
    }
    __syncthreads();
    int lg = lane>>4, li = lane&15;
    s16x8 afr[MW], bfr[NWF];
#pragma unroll
    for (int mi=0;mi<MW;mi++)
      afr[mi] = *(const s16x8*)&As[wr*(BM/2)+mi*16+li][lg*8];
#pragma unroll
    for (int ni=0;ni<NWF;ni++)
      bfr[ni] = *(const s16x8*)&Bs[wc*(BN/2)+ni*16+li][lg*8];
#pragma unroll
    for (int mi=0;mi<MW;mi++)
#pragma unroll
      for (int ni=0;ni<NWF;ni++)
        acc[mi][ni] = __builtin_amdgcn_mfma_f32_16x16x32_bf16(afr[mi], bfr[ni], acc[mi][ni], 0,0,0);
    __syncthreads();
  }
  int lg = lane>>4, li = lane&15;
#pragma unroll
  for (int mi=0;mi<MW;mi++){
#pragma unroll
    for (int ni=0;ni<NWF;ni++){
      int gn = n0 + wc*(BN/2) + ni*16 + li;
      float bv = bias ? bias[gn] : 0.f;
#pragma unroll
      for (int r=0;r<4;r++){
        int gm = m0 + wr*(BM/2) + mi*16 + lg*4 + r;
        float v = acc[mi][ni][r] + bv;
        size_t orow = WINST ? (size_t)winmap_tok(r0+gm) : (size_t)gm;
        size_t off = orow*N + gn;
        if (EPI==EPI_SILU)        v = silu_(v);
        else if (EPI==EPI_GELU)   v = 0.5f*v*(1.f+erff(v*0.70710678118654752f));
        else if (EPI==EPI_SIGMUL) v = tof(other[off])*sigm_(v);
        else if (EPI==EPI_ADD)    v = v + tof(other[off]);
        else if (EPI==EPI_RELU)   v = fmaxf(v,0.f);
        else if (EPI==EPI_SIGMOID)v = sigm_(v);
        sto(outp + off, v);
      }
    }
  }
}

// -------- fp32 fallback GEMM (tiny N): out = epi(A[M,K]@W[K,N]+bias) -------
template<int EPI, typename OT, typename CT>
__global__ __launch_bounds__(256) void gemm_k(
    const u16* __restrict__ A1, const u16* __restrict__ A2, int K1, int K2,
    const float* __restrict__ W, int ldw, const float* __restrict__ bias,
    const OT* other, CT* outp, int M, int N)
{
  __shared__ float as[16][68];
  __shared__ float bs[16][64];
  int m0 = blockIdx.y*64, n0 = blockIdx.x*64;
  int t = threadIdx.x;
  int ty = t>>4, tx = t&15;
  float acc[4][4] = {{0.f}};
  int K = K1 + K2;
  int arow = t>>2, ac4 = (t&3)<<2;
  int bkr = t>>4, bnc = (t&15)<<2;
  for (int k0=0; k0<K; k0+=16){
    int gk = k0 + ac4;
    float4 av;
    if (gk < K1) av = ld4(A1 + (size_t)(m0+arow)*K1 + gk);
    else         av = ld4(A2 + (size_t)(m0+arow)*K2 + (gk-K1));
    as[ac4+0][arow]=av.x; as[ac4+1][arow]=av.y; as[ac4+2][arow]=av.z; as[ac4+3][arow]=av.w;
    int gn = n0 + bnc;
    const float* wp = W + (size_t)(k0+bkr)*ldw;
    if (gn+3 < N) {
      *(float4*)&bs[bkr][bnc] = *(const float4*)(wp + gn);
    } else {
#pragma unroll
      for (int j=0;j<4;j++) bs[bkr][bnc+j] = (gn+j<N) ? wp[gn+j] : 0.f;
    }
    __syncthreads();
#pragma unroll
    for (int kk=0; kk<16; kk++){
      float4 a4 = *(const float4*)&as[kk][ty*4];
      float4 b4 = *(const float4*)&bs[kk][tx*4];
      acc[0][0]+=a4.x*b4.x; acc[0][1]+=a4.x*b4.y; acc[0][2]+=a4.x*b4.z; acc[0][3]+=a4.x*b4.w;
      acc[1][0]+=a4.y*b4.x; acc[1][1]+=a4.y*b4.y; acc[1][2]+=a4.y*b4.z; acc[1][3]+=a4.y*b4.w;
      acc[2][0]+=a4.z*b4.x; acc[2][1]+=a4.z*b4.y; acc[2][2]+=a4.z*b4.z; acc[2][3]+=a4.z*b4.w;
      acc[3][0]+=a4.w*b4.x; acc[3][1]+=a4.w*b4.y; acc[3][2]+=a4.w*b4.z; acc[3][3]+=a4.w*b4.w;
    }
    __syncthreads();
  }
#pragma unroll
  for (int i=0;i<4;i++){
    int gm = m0 + ty*4 + i;
#pragma unroll
    for (int j=0;j<4;j++){
      int gn = n0 + tx*4 + j;
      if (gn >= N) continue;
      float v = acc[i][j] + (bias ? bias[gn] : 0.f);
      size_t off = (size_t)gm*N + gn;
      if (EPI==EPI_SILU)        v = silu_(v);
      else if (EPI==EPI_GELU)   v = 0.5f*v*(1.f+erff(v*0.70710678118654752f));
      else if (EPI==EPI_SIGMUL) v = tof(other[off])*sigm_(v);
      else if (EPI==EPI_ADD)    v = v + tof(other[off]);
      else if (EPI==EPI_RELU)   v = fmaxf(v,0.f);
      else if (EPI==EPI_SIGMOID)v = sigm_(v);
      sto(outp + off, v);
    }
  }
}

// ---- fused xBC GEMM (M=64 tile) + causal conv(4) + SiLU -> XC -------------
__global__ __launch_bounds__(256) void xbcconv_k(
    const u16* __restrict__ A1, const u16* __restrict__ Wt,
    const float* __restrict__ cw, const float* __restrict__ cb,
    u16* __restrict__ XC)
{
  __shared__ u16 As[64][40];
  __shared__ u16 Ab[3][40];
  __shared__ u16 Bs[128][40];
  __shared__ float Cls[67][132];
  int m0 = blockIdx.y*64, n0 = blockIdx.x*128;
  bool first = ((m0 & 4095) == 0);
  int t = threadIdx.x;
  int lane = t&63, w = t>>6;
  int wr = w>>1, wc = w&1;
  f32x4 acc[2][4];
#pragma unroll
  for (int mi=0;mi<2;mi++)
#pragma unroll
    for (int ni=0;ni<4;ni++) acc[mi][ni] = (f32x4){0.f,0.f,0.f,0.f};
  float acc2[2] = {0.f,0.f};
  int lrow = t>>2, lc8 = (t&3)*8;
  int brow = t/64, bcol = (t%64)*2;
  for (int k0=0; k0<256; k0+=32){
    int gk = k0 + lc8;
    *(uint4*)&As[lrow][lc8] = *(const uint4*)(A1 + (size_t)(m0+lrow)*256 + gk);
    if (t < 12 && !first){
      int r3 = t>>2, seg = t&3;
      *(uint4*)&Ab[r3][seg*8] = *(const uint4*)(A1 + (size_t)(m0-3+r3)*256 + k0 + seg*8);
    }
#pragma unroll
    for (int i=0;i<2;i++){
      int row = lrow + i*64;
      *(uint4*)&Bs[row][lc8] = *(const uint4*)(Wt + (size_t)(n0+row)*256 + gk);
    }
    __syncthreads();
    int lg = lane>>4, li = lane&15;
    s16x8 afr[2], bfr[4];
#pragma unroll
    for (int mi=0;mi<2;mi++)
      afr[mi] = *(const s16x8*)&As[wr*32+mi*16+li][lg*8];
#pragma unroll
    for (int ni=0;ni<4;ni++)
      bfr[ni] = *(const s16x8*)&Bs[wc*64+ni*16+li][lg*8];
#pragma unroll
    for (int mi=0;mi<2;mi++)
#pragma unroll
      for (int ni=0;ni<4;ni++)
        acc[mi][ni] = __builtin_amdgcn_mfma_f32_16x16x32_bf16(afr[mi], bfr[ni], acc[mi][ni], 0,0,0);
    if (t < 192 && !first){
#pragma unroll
      for (int kk=0;kk<32;kk++){
        float a = b2f(Ab[brow][kk]);
        acc2[0] += a * b2f(Bs[bcol][kk]);
        acc2[1] += a * b2f(Bs[bcol+1][kk]);
      }
    }
    __syncthreads();
  }
  {
    int lg = lane>>4, li = lane&15;
#pragma unroll
    for (int mi=0;mi<2;mi++)
#pragma unroll
      for (int ni=0;ni<4;ni++){
        int col = wc*64 + ni*16 + li;
#pragma unroll
        for (int r=0;r<4;r++){
          int rl = wr*32 + mi*16 + lg*4 + r;
          Cls[3+rl][col] = acc[mi][ni][r];
        }
      }
    if (t < 192){
      Cls[brow][bcol]   = first ? 0.f : acc2[0];
      Cls[brow][bcol+1] = first ? 0.f : acc2[1];
    }
  }
  __syncthreads();
  int col = t & 127, half = t >> 7;
  int ch = n0 + col;
  float w0 = cw[ch*4+0], w1 = cw[ch*4+1], w2 = cw[ch*4+2], w3 = cw[ch*4+3];
  float bias = cb[ch];
  int r0 = half*32;
  float c0 = Cls[r0+0][col], c1 = Cls[r0+1][col], c2 = Cls[r0+2][col];
#pragma unroll
  for (int rr=0; rr<32; rr++){
    float c3 = Cls[r0+rr+3][col];
    float v = bias + w0*c0 + w1*c1 + w2*c2 + w3*c3;
    XC[(size_t)(m0 + r0 + rr)*640 + ch] = f2b(silu_(v));
    c0=c1; c1=c2; c2=c3;
  }
}

// ---------------- dt: softplus(dtraw+bias); a = -dt*exp(a_log) -------------
__global__ __launch_bounds__(256) void dtk_k(
    const float* __restrict__ DTRAW, const float* __restrict__ dtb, const float* __restrict__ alog,
    float* __restrict__ DT_, float* __restrict__ AA_)
{
  int gid = blockIdx.x*256 + threadIdx.x;
  int h = gid & 7;
  float xv = DTRAW[gid] + dtb[h];
  float sp = (xv > 20.f) ? xv : log1pf(__expf(xv));
  DT_[gid] = sp;
  AA_[gid] = -sp * __expf(alog[h]);
}

// ---------------- per-chunk inclusive cumsum of a (full) -------------------
__global__ __launch_bounds__(256) void acs_k(const float* __restrict__ AA_, float* __restrict__ ACS_)
{
  int wid = (blockIdx.x<<2) + (threadIdx.x>>6);
  int lane = threadIdx.x & 63;
  int c  = wid & 15;
  int bh = wid >> 4;
  int b  = bh >> 3, h = bh & 7;
  size_t tok0 = (size_t)b*4096 + c*256 + lane*4;
  float v0 = AA_[(tok0+0)*8 + h];
  float v1 = AA_[(tok0+1)*8 + h];
  float v2 = AA_[(tok0+2)*8 + h];
  float v3 = AA_[(tok0+3)*8 + h];
  v1 += v0; v2 += v1; v3 += v2;
  float tot = v3, s = tot;
#pragma unroll
  for (int o=1;o<64;o<<=1){
    float u = __shfl_up(s, o, 64);
    if (lane >= o) s += u;
  }
  float excl = s - tot;
  float* dst = ACS_ + (size_t)bh*4096 + c*256 + lane*4;
  dst[0]=excl+v0; dst[1]=excl+v1; dst[2]=excl+v2; dst[3]=excl+v3;
}

// ------- chunk end-states via MFMA: ST[((bl*16+c)*8+h)][p][n] --------------
__global__ __launch_bounds__(256) void states_k(
    const u16* __restrict__ XC, const float* __restrict__ DTc, const float* __restrict__ ACSc,
    float* __restrict__ ST)
{
  int bid = blockIdx.x;                  // bl*128 + c*8 + h
  int h = bid & 7, c = (bid>>3)&15, bl = bid>>7;
  __shared__ u16 Xt[64][72];
  __shared__ u16 Bt[64][72];
  int t = threadIdx.x;
  int lane = t&63, w = t>>6;
  int wr = w>>1, wc = w&1;
  int lg = lane>>4, li = lane&15;
  const float* acs = ACSc + ((size_t)(bl*8+h))*4096 + c*256;
  float aL = acs[255];
  size_t tok0 = (size_t)bl*4096 + c*256;
  f32x4 acc[2][2];
#pragma unroll
  for (int mi=0;mi<2;mi++)
#pragma unroll
    for (int ni=0;ni<2;ni++) acc[mi][ni] = (f32x4){0.f,0.f,0.f,0.f};
  int sr = t>>2, cg = t&3;
  for (int s0=0; s0<256; s0+=64){
    __syncthreads();
    size_t grow = tok0 + s0 + sr;
    float dtv = DTc[grow*8 + h];
    float wdec = __expf(aL - acs[s0+sr]);
    const u16* xrow = XC + grow*640 + h*64 + cg*16;
    const u16* brow = XC + grow*640 + 512 + cg*16;
    uint4 xa = *(const uint4*)xrow, xb = *(const uint4*)(xrow+8);
    uint4 ba = *(const uint4*)brow, bb = *(const uint4*)(brow+8);
    const u16* xu = (const u16*)&xa;
    const u16* bu = (const u16*)&ba;
#pragma unroll
    for (int j=0;j<8;j++){
      Xt[cg*16+j][sr]   = f2b(b2f(xu[j])*dtv);
      Bt[cg*16+j][sr]   = f2b(b2f(bu[j])*wdec);
    }
    const u16* xu2 = (const u16*)&xb;
    const u16* bu2 = (const u16*)&bb;
#pragma unroll
    for (int j=0;j<8;j++){
      Xt[cg*16+8+j][sr] = f2b(b2f(xu2[j])*dtv);
      Bt[cg*16+8+j][sr] = f2b(b2f(bu2[j])*wdec);
    }
    __syncthreads();
    s16x8 afr[2][2], bfr[2][2];
#pragma unroll
    for (int kk=0;kk<2;kk++){
#pragma unroll
      for (int mi=0;mi<2;mi++)
        afr[mi][kk] = *(const s16x8*)&Xt[wr*32+mi*16+li][kk*32+lg*8];
#pragma unroll
      for (int ni=0;ni<2;ni++)
        bfr[ni][kk] = *(const s16x8*)&Bt[wc*32+ni*16+li][kk*32+lg*8];
    }
#pragma unroll
    for (int kk=0;kk<2;kk++)
#pragma unroll
      for (int mi=0;mi<2;mi++)
#pragma unroll
        for (int ni=0;ni<2;ni++)
          acc[mi][ni] = __builtin_amdgcn_mfma_f32_16x16x32_bf16(afr[mi][kk], bfr[ni][kk], acc[mi][ni], 0,0,0);
  }
  float* dst = ST + (size_t)bid*4096;
#pragma unroll
  for (int mi=0;mi<2;mi++)
#pragma unroll
    for (int ni=0;ni<2;ni++){
      int gn = wc*32 + ni*16 + li;
#pragma unroll
      for (int r=0;r<4;r++){
        int gp = wr*32 + mi*16 + lg*4 + r;
        dst[gp*64 + gn] = acc[mi][ni][r];
      }
    }
}

// ------- sequential inter-chunk scan; STIN out bf16; split over e ----------
__global__ __launch_bounds__(256) void scan_k(
    const float* __restrict__ ST, const float* __restrict__ ACSc, u16* __restrict__ STIN)
{
  int bid = blockIdx.x;              // (bl*8+h)*4 + eq
  int eq = bid & 3, h = (bid>>2)&7, bl = bid>>5;
  int t = threadIdx.x;
  float hr[4] = {0.f,0.f,0.f,0.f};
  for (int c=0;c<16;c++){
    float dec = __expf(ACSc[((size_t)(bl*8+h))*4096 + c*256 + 255]);
    size_t base = ((size_t)((bl*16+c)*8+h))*4096 + (size_t)eq*1024;
#pragma unroll
    for (int e=0;e<4;e++){
      size_t idx = base + e*256 + t;
      float st = ST[idx];
      STIN[idx] = f2b(hr[e]);
      hr[e] = hr[e]*dec + st;
    }
  }
}

// ------------ Y = Yd + Yo + d_skip*xs via MFMA (flash-style) ---------------
// V staged as pure transpose; dt folded into score weight; xs from Vt tile.
__global__ __launch_bounds__(256) void ydy_k(
    const u16* __restrict__ XC, const float* __restrict__ DTc,
    const float* __restrict__ ACSc, const u16* __restrict__ STIN,
    const float* __restrict__ dskip, u16* __restrict__ Y)
{
  int bid = blockIdx.x;                      // bl*512 + (c*8+h)*4 + lt
  int lt = bid & 3, h = (bid>>2)&7, c = (bid>>5)&15, bl = bid>>9;
  int l0 = lt*64;
  __shared__ u16 Ct[64][72];
  __shared__ u16 Sb[64][72];
  __shared__ u16 Vt[64][72];
  __shared__ u16 Sl[64][72];
  int t = threadIdx.x;
  int lane = t&63, w = t>>6;
  int wr = w>>1, wc = w&1;
  int lg = lane>>4, li = lane&15;
  const float* acs = ACSc + ((size_t)(bl*8+h))*4096 + c*256;
  size_t tok0 = (size_t)bl*4096 + c*256;
  int sr = t>>2;
#pragma unroll
  for (int it=0; it<2; it++){
    int seg = (t&3) + it*4;
    *(uint4*)&Ct[sr][seg*8] = *(const uint4*)(XC + (tok0+l0+sr)*640 + 576 + seg*8);
  }
  float acsl[2][4];
#pragma unroll
  for (int mi=0;mi<2;mi++)
#pragma unroll
    for (int r=0;r<4;r++)
      acsl[mi][r] = acs[l0 + wr*32 + mi*16 + lg*4 + r];
  f32x4 accP[2][2], accO[2][2];
#pragma unroll
  for (int mi=0;mi<2;mi++)
#pragma unroll
    for (int ni=0;ni<2;ni++){ accP[mi][ni]=(f32x4){0,0,0,0}; accO[mi][ni]=(f32x4){0,0,0,0}; }
  __syncthreads();
  // Yo: A from Ct (k=n), B directly from STIN global ([p][n] = B-operand layout)
  const u16* stin = STIN + ((size_t)((bl*16+c)*8+h))*4096;
#pragma unroll
  for (int kk=0;kk<2;kk++){
    s16x8 bfr[2];
#pragma unroll
    for (int ni=0;ni<2;ni++){
      int p = wc*32 + ni*16 + li;
      bfr[ni] = *(const s16x8*)(stin + p*64 + kk*32 + lg*8);
    }
#pragma unroll
    for (int mi=0;mi<2;mi++){
      s16x8 afr = *(const s16x8*)&Ct[wr*32+mi*16+li][kk*32+lg*8];
#pragma unroll
      for (int ni=0;ni<2;ni++)
        accO[mi][ni] = __builtin_amdgcn_mfma_f32_16x16x32_bf16(afr, bfr[ni], accO[mi][ni], 0,0,0);
    }
  }
  for (int sb=0; sb<=lt; sb++){
    int s0 = sb*64;
    __syncthreads();
#pragma unroll
    for (int it=0; it<2; it++){
      int seg = (t&3) + it*4;
      *(uint4*)&Sb[sr][seg*8] = *(const uint4*)(XC + (tok0+s0+sr)*640 + 512 + seg*8);
    }
    {  // stage V^T (pure u16 transpose, no scaling)
      int cg = t&3;
      size_t grow = tok0 + s0 + sr;
      const u16* xrow = XC + grow*640 + h*64 + cg*16;
      uint4 xa = *(const uint4*)xrow, xb = *(const uint4*)(xrow+8);
      const u16* xu = (const u16*)&xa;
#pragma unroll
      for (int j=0;j<8;j++) Vt[cg*16+j][sr] = xu[j];
      const u16* xu2 = (const u16*)&xb;
#pragma unroll
      for (int j=0;j<8;j++) Vt[cg*16+8+j][sr] = xu2[j];
    }
    __syncthreads();
    f32x4 sacc[2][2];
#pragma unroll
    for (int mi=0;mi<2;mi++)
#pragma unroll
      for (int ni=0;ni<2;ni++) sacc[mi][ni]=(f32x4){0,0,0,0};
#pragma unroll
    for (int kk=0;kk<2;kk++){
      s16x8 bfr[2];
#pragma unroll
      for (int ni=0;ni<2;ni++)
        bfr[ni] = *(const s16x8*)&Sb[wc*32+ni*16+li][kk*32+lg*8];
#pragma unroll
      for (int mi=0;mi<2;mi++){
        s16x8 afr = *(const s16x8*)&Ct[wr*32+mi*16+li][kk*32+lg*8];
#pragma unroll
        for (int ni=0;ni<2;ni++)
          sacc[mi][ni] = __builtin_amdgcn_mfma_f32_16x16x32_bf16(afr, bfr[ni], sacc[mi][ni], 0,0,0);
      }
    }
#pragma unroll
    for (int ni=0;ni<2;ni++){
      int cs = wc*32 + ni*16 + li;
      int gsj = s0 + cs;
      float acss = acs[gsj];
      float dts = DTc[(tok0+gsj)*8 + h];    // dt folded into weight
#pragma unroll
      for (int mi=0;mi<2;mi++){
#pragma unroll
        for (int r=0;r<4;r++){
          int lrow = wr*32 + mi*16 + lg*4 + r;
          int gl = l0 + lrow;
          float wgt = (gsj <= gl) ? __expf(acsl[mi][r] - acss)*dts : 0.f;
          Sl[lrow][cs] = f2b(sacc[mi][ni][r] * wgt);
        }
      }
    }
    __syncthreads();
#pragma unroll
    for (int kk=0;kk<2;kk++){
      s16x8 bfr[2];
#pragma unroll
      for (int ni=0;ni<2;ni++)
        bfr[ni] = *(const s16x8*)&Vt[wc*32+ni*16+li][kk*32+lg*8];
#pragma unroll
      for (int mi=0;mi<2;mi++){
        s16x8 afr = *(const s16x8*)&Sl[wr*32+mi*16+li][kk*32+lg*8];
#pragma unroll
        for (int ni=0;ni<2;ni++)
          accP[mi][ni] = __builtin_amdgcn_mfma_f32_16x16x32_bf16(afr, bfr[ni], accP[mi][ni], 0,0,0);
      }
    }
  }
  __syncthreads();
  // epilogue: xs read straight from Vt (last staged s-block == l-block lt)
  float dsk = dskip[h];
#pragma unroll
  for (int mi=0;mi<2;mi++){
#pragma unroll
    for (int ni=0;ni<2;ni++){
      int p = wc*32 + ni*16 + li;
#pragma unroll
      for (int r=0;r<4;r++){
        int lrow = wr*32 + mi*16 + lg*4 + r;
        float el = __expf(acsl[mi][r]);
        float xsv = b2f(Vt[p][lrow]);
        Sl[lrow][p] = f2b(accP[mi][ni][r] + el*accO[mi][ni][r] + dsk*xsv);
      }
    }
  }
  __syncthreads();
#pragma unroll
  for (int it=0; it<2; it++){
    int seg = (t&3) + it*4;
    *(uint4*)(Y + (tok0+l0+sr)*512 + h*64 + seg*8) = *(const uint4*)&Sl[sr][seg*8];
  }
}

// ---------------- u = y*silu(z); RMSNorm*w over 512 (in place) -------------
__global__ __launch_bounds__(256) void urms_k(
    u16* Y, const u16* __restrict__ Z, const float* __restrict__ nw)
{
  int tok = blockIdx.x*4 + (threadIdx.x>>6);
  int lane = threadIdx.x & 63;
  size_t base = (size_t)tok*512 + lane*8;
  float y[8], z[8], u[8];
  ld8(Y+base, y); ld8(Z+base, z);
  float ss=0.f;
#pragma unroll
  for (int e=0;e<8;e++){ u[e] = y[e]*silu_(z[e]); ss += u[e]*u[e]; }
  ss = wsum_(ss);
  float r = rsqrtf(ss*(1.f/512.f) + 1e-5f);
  float4 w0 = *(const float4*)(nw + lane*8);
  float4 w1 = *(const float4*)(nw + lane*8 + 4);
  float o[8];
  o[0]=u[0]*r*w0.x; o[1]=u[1]*r*w0.y; o[2]=u[2]*r*w0.z; o[3]=u[3]*r*w0.w;
  o[4]=u[4]*r*w1.x; o[5]=u[5]*r*w1.y; o[6]=u[6]*r*w1.z; o[7]=u[7]*r*w1.w;
  st8(Y+base, o);
}

// ------------ window attention via MFMA, block per (window, head) ----------
__global__ __launch_bounds__(256) void attn_k(
    const u16* __restrict__ QKV, const float* __restrict__ rpb, u16* __restrict__ OW)
{
  int win = blockIdx.x;
  int wid = win & 63;
  int head = blockIdx.y;
  __shared__ u16 Qs[64][40];
  __shared__ u16 Ks[64][40];
  __shared__ u16 Vt[32][72];
  __shared__ u16 Pl[64][72];
  __shared__ float rl[225];
  __shared__ int rid[64];
  int t = threadIdx.x;
  int lane = t&63, w = t>>6;
  int lg = lane>>4, li = lane&15;
  const float scale = 0.17677669529663687f;
  {
    int row = t>>2, seg = t&3;
    const u16* base = QKV + ((size_t)win*64 + row)*768 + head*32 + seg*8;
    uint4 q = *(const uint4*)base;
    const u16* qe = (const u16*)&q;
    u16 qs8[8];
#pragma unroll
    for (int j=0;j<8;j++) qs8[j] = f2b(b2f(qe[j])*scale);
    *(uint4*)&Qs[row][seg*8] = *(const uint4*)qs8;
    *(uint4*)&Ks[row][seg*8] = *(const uint4*)(base + 256);
    uint4 v = *(const uint4*)(base + 512);
    const u16* ve = (const u16*)&v;
#pragma unroll
    for (int j=0;j<8;j++) Vt[seg*8+j][row] = ve[j];
  }
  if (t < 225) rl[t] = rpb[t*8 + head];
  if (t < 64){
    int h2 = ((wid>>3)<<3) + (t>>3);
    int w2 = ((wid&7)<<3) + (t&7);
    int rh = (h2<56)?0:((h2<60)?1:2);
    int rw = (w2<56)?0:((w2<60)?1:2);
    rid[t] = rh*3 + rw;
  }
  __syncthreads();
  f32x4 sc[4];
  {
    s16x8 qf = *(const s16x8*)&Qs[w*16+li][lg*8];
#pragma unroll
    for (int ni=0;ni<4;ni++){
      s16x8 kf = *(const s16x8*)&Ks[ni*16+li][lg*8];
      sc[ni] = __builtin_amdgcn_mfma_f32_16x16x32_bf16(qf, kf, (f32x4){0,0,0,0}, 0,0,0);
    }
  }
  float inv[4];
#pragma unroll
  for (int r=0;r<4;r++){
    int i = w*16 + lg*4 + r;
    int ridi = rid[i];
    float vv[4];
    float m = -1e30f;
#pragma unroll
    for (int ni=0;ni<4;ni++){
      int j = ni*16 + li;
      float s = sc[ni][r] + rl[((i>>3)-(j>>3)+7)*15 + ((i&7)-(j&7)+7)];
      if (ridi != rid[j]) s -= 100.f;
      vv[ni] = s;
      m = fmaxf(m, s);
    }
#pragma unroll
    for (int o=1;o<16;o<<=1) m = fmaxf(m, __shfl_xor(m, o, 64));
    float sum = 0.f;
#pragma unroll
    for (int ni=0;ni<4;ni++){ vv[ni] = __expf(vv[ni]-m); sum += vv[ni]; }
#pragma unroll
    for (int o=1;o<16;o<<=1) sum += __shfl_xor(sum, o, 64);
    inv[r] = 1.f/sum;
#pragma unroll
    for (int ni=0;ni<4;ni++) Pl[i][ni*16+li] = f2b(vv[ni]);
  }
  __syncthreads();
  f32x4 oacc[2];
  oacc[0]=(f32x4){0,0,0,0}; oacc[1]=(f32x4){0,0,0,0};
#pragma unroll
  for (int kk=0;kk<2;kk++){
    s16x8 pf = *(const s16x8*)&Pl[w*16+li][kk*32+lg*8];
#pragma unroll
    for (int ni=0;ni<2;ni++){
      s16x8 vf = *(const s16x8*)&Vt[ni*16+li][kk*32+lg*8];
      oacc[ni] = __builtin_amdgcn_mfma_f32_16x16x32_bf16(pf, vf, oacc[ni], 0,0,0);
    }
  }
#pragma unroll
  for (int ni=0;ni<2;ni++)
#pragma unroll
    for (int r=0;r<4;r++)
      Pl[w*16+lg*4+r][ni*16+li] = f2b(oacc[ni][r]*inv[r]);
  __syncthreads();
  {
    int row = t>>2, seg = t&3;
    *(uint4*)(OW + ((size_t)win*64 + row)*256 + head*32 + seg*8) = *(const uint4*)&Pl[row][seg*8];
  }
}

// ---------------- xm *= gm ; xa *= ga (bf16) -------------------------------
__global__ __launch_bounds__(256) void mul2_k(
    u16* XM, const u16* __restrict__ GM, u16* XA, const u16* __restrict__ GA)
{
  size_t i = ((size_t)blockIdx.x*256 + threadIdx.x)*4;
  float4 m = ld4(XM+i), g = ld4(GM+i);
  st4(XM+i, m.x*g.x, m.y*g.y, m.z*g.z, m.w*g.w);
  float4 a = ld4(XA+i), g2 = ld4(GA+i);
  st4(XA+i, a.x*g2.x, a.y*g2.y, a.z*g2.z, a.w*g2.w);
}

// ---------------- host ------------------------------------------------------
extern "C" void kernel_launch(void* const* d_in, const int* in_sizes, int n_in,
                              void* d_out, int out_size, void* d_ws, size_t ws_size,
                              hipStream_t stream)
{
  (void)in_sizes; (void)n_in; (void)out_size;
  const size_t OFF_XN   = 0;
  const size_t OFF_XNS  = 16777216;
  const size_t OFF_SP   = 33554432;
  const size_t OFF_DTRAW= 50331648;
  const size_t OFF_DT   = 51380224;
  const size_t OFF_AA   = 52428800;
  const size_t OFF_ACS  = 53477376;
  const size_t OFF_WTS  = 54525952;
  const size_t ARO      = 58195968;
  int NB = 0;
  if      (ws_size >= ARO + 8ull*14680064) NB = 8;
  else if (ws_size >= ARO + 4ull*14680064) NB = 4;
  else if (ws_size >= ARO + 2ull*14680064) NB = 2;
  else if (ws_size >= ARO + 1ull*14680064) NB = 1;
  else return;
  int NC = 8 / NB;
  int RJ = (NB==8)?32768 : (NB==4)?16384 : (NB==2)?8192 : 4096;

  const float* x       = (const float*)d_in[0];
  const float* ln1_w   = (const float*)d_in[1];
  const float* ln1_b   = (const float*)d_in[2];
  const float* ns_w    = (const float*)d_in[3];
  const float* ns_b    = (const float*)d_in[4];
  const float* m_win   = (const float*)d_in[5];
  const float* m_conv_w= (const float*)d_in[6];
  const float* m_conv_b= (const float*)d_in[7];
  const float* m_dt_b  = (const float*)d_in[8];
  const float* m_a_log = (const float*)d_in[9];
  const float* m_d     = (const float*)d_in[10];
  const float* m_norm_w= (const float*)d_in[11];
  const float* m_wout  = (const float*)d_in[12];
  const float* tm_w1   = (const float*)d_in[13];
  const float* tm_b1   = (const float*)d_in[14];
  const float* tm_w2   = (const float*)d_in[15];
  const float* tm_b2   = (const float*)d_in[16];
  const float* nt_w    = (const float*)d_in[17];
  const float* nt_b    = (const float*)d_in[18];
  const float* qkv_w   = (const float*)d_in[19];
  const float* qkv_b   = (const float*)d_in[20];
  const float* rpb     = (const float*)d_in[21];
  const float* gate_w  = (const float*)d_in[22];
  const float* gate_b  = (const float*)d_in[23];
  const float* proj_w  = (const float*)d_in[24];
  const float* proj_b  = (const float*)d_in[25];
  const float* cg_w1a  = (const float*)d_in[26];
  const float* cg_b1a  = (const float*)d_in[27];
  const float* cg_w2a  = (const float*)d_in[28];
  const float* cg_b2a  = (const float*)d_in[29];
  const float* cg_w1m  = (const float*)d_in[30];
  const float* cg_b1m  = (const float*)d_in[31];
  const float* cg_w2m  = (const float*)d_in[32];
  const float* cg_b2m  = (const float*)d_in[33];
  const float* cg_wf   = (const float*)d_in[34];
  const float* cg_bf   = (const float*)d_in[35];
  const float* ln2_w   = (const float*)d_in[36];
  const float* ln2_b   = (const float*)d_in[37];
  const float* mlp_w1  = (const float*)d_in[38];
  const float* mlp_b1  = (const float*)d_in[39];
  const float* mlp_w2  = (const float*)d_in[40];
  const float* mlp_b2  = (const float*)d_in[41];
  float* dout = (float*)d_out;
  char* ws = (char*)d_ws;

  u16*  XN   = (u16*)(ws + OFF_XN);
  u16*  XNS  = (u16*)(ws + OFF_XNS);
  u16*  SP   = (u16*)(ws + OFF_SP);
  float* DTRAW = (float*)(ws + OFF_DTRAW);
  float* DT  = (float*)(ws + OFF_DT);
  float* AA  = (float*)(ws + OFF_AA);
  float* ACS = (float*)(ws + OFF_ACS);
  u16*  WTS  = (u16*)(ws + OFF_WTS);
  u16* WT_XBC = WTS + 0;
  u16* WT_Z   = WTS + 163840;
  u16* WT_WOUT= WTS + 294912;
  u16* WT_TM1 = WTS + 425984;
  u16* WT_TM2 = WTS + 491520;
  u16* WT_QKV = WTS + 557056;
  u16* WT_GATE= WTS + 753664;
  u16* WT_PROJ= WTS + 819200;
  u16* WT_W2A = WTS + 884736;
  u16* WT_W2M = WTS + 901120;
  u16* WT_WF  = WTS + 917504;
  u16* WT_MLP1= WTS + 1048576;
  u16* WT_MLP2= WTS + 1310720;
  u16* WT_W1A = WTS + 1572864;
  u16* WT_W1M = WTS + 1589248;
  char* AR = ws + ARO;
  u16*  XCc   = (u16*)AR;
  u16*  Zc    = (u16*)(AR + (size_t)NB*5242880);
  u16*  STINc = (u16*)(AR + (size_t)NB*9437184);
  float* STc  = (float*)(AR + (size_t)NB*10485760);
  u16*  Yc    = (u16*)(AR + (size_t)NB*10485760);
  u16*  QKVc  = (u16*)AR;
  u16*  OWc   = (u16*)(AR + (size_t)NB*6291456);
  u16*  TBUF  = (u16*)AR;
  u16*  XM    = XNS;
  u16*  XA    = XN;
  u16*  CGH   = (u16*)AR;
  u16*  GA    = (u16*)(AR + 4194304);
  u16*  GM    = SP;
  u16*  LNc   = (u16*)AR;
  u16*  MHc   = (u16*)(AR + (size_t)RJ*512);

  const size_t TB = 4096*256;
  const size_t H2 = 16384*256;

  // Phase 0: weight convert+transpose
  wt_k<<<dim3(8,20),256,0,stream>>>(m_win+512,1160,256, WT_XBC);
  wt_k<<<dim3(8,16),256,0,stream>>>(m_win,    1160,256, WT_Z);
  wt_k<<<dim3(16,8),256,0,stream>>>(m_wout,    256,512, WT_WOUT);
  wt_k<<<dim3(16,8),256,0,stream>>>(tm_w1,     256,512, WT_TM1);
  wt_k<<<dim3(8,8), 256,0,stream>>>(tm_w2,     256,256, WT_TM2);
  wt_k<<<dim3(8,24),256,0,stream>>>(qkv_w,     768,256, WT_QKV);
  wt_k<<<dim3(8,8), 256,0,stream>>>(gate_w,    256,256, WT_GATE);
  wt_k<<<dim3(8,8), 256,0,stream>>>(proj_w,    256,256, WT_PROJ);
  wt_k<<<dim3(2,8), 256,0,stream>>>(cg_w2a,    256,64,  WT_W2A);
  wt_k<<<dim3(2,8), 256,0,stream>>>(cg_w2m,    256,64,  WT_W2M);
  wt_k<<<dim3(16,8),256,0,stream>>>(cg_wf,     256,512, WT_WF);
  wt_k<<<dim3(8,32),256,0,stream>>>(mlp_w1,   1024,256, WT_MLP1);
  wt_k<<<dim3(32,8),256,0,stream>>>(mlp_w2,    256,1024,WT_MLP2);
  wt_k<<<dim3(8,2), 256,0,stream>>>(cg_w1a,     64,256, WT_W1A);
  wt_k<<<dim3(8,2), 256,0,stream>>>(cg_w1m,     64,256, WT_W1M);

  // Phase A
  ln2x_k<<<8192,256,0,stream>>>(x, ln1_w, ln1_b, ns_w, ns_b, XN, XNS);
  gemm_k<EPI_NONE,float,float><<<dim3(1,512),256,0,stream>>>(XNS,nullptr,256,0, m_win+1152,1160, nullptr, nullptr, DTRAW, 32768,8);
  dtk_k<<<1024,256,0,stream>>>(DTRAW, m_dt_b, m_a_log, DT, AA);
  acs_k<<<256,256,0,stream>>>(AA, ACS);

  // Phases B..F per chunk of NB batches
  for (int cc=0; cc<NC; cc++){
    int cb0 = cc*NB;
    const u16* XNSc = XNS + (size_t)cb0*TB;
    const float* DTcp = DT + (size_t)cb0*32768;
    const float* ACScp = ACS + (size_t)cb0*32768;
    xbcconv_k<<<dim3(5,NB*64),256,0,stream>>>(XNSc, WT_XBC, m_conv_w, m_conv_b, XCc);
    states_k<<<NB*128,256,0,stream>>>(XCc, DTcp, ACScp, STc);
    scan_k<<<NB*32,256,0,stream>>>(STc, ACScp, STINc);
    ydy_k<<<NB*512,256,0,stream>>>(XCc, DTcp, ACScp, STINc, m_d, Yc);
    mgemm_k<128,128,EPI_NONE,false,false,float,u16><<<dim3(4,NB*32),256,0,stream>>>(XNSc,nullptr,256,0, WT_Z, nullptr, nullptr, Zc, 512, 0);
    urms_k<<<NB*1024,256,0,stream>>>(Yc, Zc, m_norm_w);
    mgemm_k<128,128,EPI_ADD,false,false,u16,u16><<<dim3(2,NB*32),256,0,stream>>>(Yc,nullptr,512,0, WT_WOUT, nullptr, XN + (size_t)cb0*TB, SP + (size_t)cb0*TB, 256, 0);
  }

  // Phase G: tmix
  mgemm_k<128,128,EPI_SILU,false,false,float,u16><<<dim3(2,128),256,0,stream>>>(SP, SP+H2, 256,256, WT_TM1, tm_b1, nullptr, TBUF, 256, 0);
  mgemm_k<128,128,EPI_ADD,false,false,u16,u16><<<dim3(2,128),256,0,stream>>>(TBUF,nullptr,256,0, WT_TM2, tm_b2, SP, XM, 256, 0);
  ln_k<u16><<<4096,256,0,stream>>>(XM, nt_w, nt_b, XM);
  mgemm_k<128,128,EPI_SILU,false,false,float,u16><<<dim3(2,128),256,0,stream>>>(SP+H2, XM, 256,256, WT_TM1, tm_b1, nullptr, TBUF, 256, 0);
  mgemm_k<128,128,EPI_ADD,false,false,u16,u16><<<dim3(2,128),256,0,stream>>>(TBUF,nullptr,256,0, WT_TM2, tm_b2, SP+H2, XM+H2, 256, 0);
  ln_k<u16><<<4096,256,0,stream>>>(XM+H2, nt_w, nt_b, XM+H2);

  // Phase H: window attention
  for (int cc=0; cc<NC; cc++){
    int r0 = cc*NB*4096;
    mgemm_k<128,128,EPI_NONE,true,false,float,u16><<<dim3(6,NB*32),256,0,stream>>>(XN,nullptr,256,0, WT_QKV, qkv_b, nullptr, QKVc, 768, r0);
    attn_k<<<dim3(NB*64,8),256,0,stream>>>(QKVc, rpb, OWc);
    mgemm_k<128,128,EPI_SIGMUL,true,false,u16,u16><<<dim3(2,NB*32),256,0,stream>>>(XN,nullptr,256,0, WT_GATE, gate_b, OWc, OWc, 256, r0);
    mgemm_k<128,128,EPI_NONE,false,true,float,u16><<<dim3(2,NB*32),256,0,stream>>>(OWc,nullptr,256,0, WT_PROJ, proj_b, nullptr, XA, 256, r0);
  }

  // Phase I: cross gates
  mgemm_k<128,64,EPI_RELU,false,false,float,u16><<<dim3(1,256),256,0,stream>>>(XA,nullptr,256,0, WT_W1A, cg_b1a, nullptr, CGH, 64, 0);
  mgemm_k<128,128,EPI_SIGMOID,false,false,float,u16><<<dim3(2,256),256,0,stream>>>(CGH,nullptr,64,0, WT_W2A, cg_b2a, nullptr, GM, 256, 0);
  mgemm_k<128,64,EPI_RELU,false,false,float,u16><<<dim3(1,256),256,0,stream>>>(XM,nullptr,256,0, WT_W1M, cg_b1m, nullptr, CGH, 64, 0);
  mgemm_k<128,128,EPI_SIGMOID,false,false,float,u16><<<dim3(2,256),256,0,stream>>>(CGH,nullptr,64,0, WT_W2M, cg_b2m, nullptr, GA, 256, 0);
  mul2_k<<<8192,256,0,stream>>>(XM, GM, XA, GA);
  mgemm_k<128,128,EPI_ADD,false,false,float,float><<<dim3(2,256),256,0,stream>>>(XM, XA, 256,256, WT_WF, cg_bf, x, dout, 256, 0);

  // Phase J: MLP
  for (int q=0; q<32768/RJ; q++){
    float* XOq = dout + (size_t)q*RJ*256;
    ln_k<float><<<RJ/4,256,0,stream>>>(XOq, ln2_w, ln2_b, LNc);
    mgemm_k<128,128,EPI_GELU,false,false,float,u16><<<dim3(8,RJ/128),256,0,stream>>>(LNc,nullptr,256,0, WT_MLP1, mlp_b1, nullptr, MHc, 1024, 0);
    mgemm_k<128,128,EPI_ADD,false,false,float,float><<<dim3(2,RJ/128),256,0,stream>>>(MHc,nullptr,1024,0, WT_MLP2, mlp_b2, XOq, XOq, 256, 0);
  }
}